// Round 14
// 3228.330 us; speedup vs baseline: 3.8830x; 1.1111x over previous
//
#include <hip/hip_runtime.h>
#include <math.h>

#define S_LEN 1024
#define NB 8
#define CDIM 512
#define KCB 4096
#define DH 64
#define NLAYER 6
#define NTOK (S_LEN*NB)
#define TOKC ((long)NTOK*CDIM)

typedef __attribute__((ext_vector_type(8))) _Float16 f16x8;
typedef __attribute__((ext_vector_type(4))) _Float16 f16x4;
typedef __attribute__((ext_vector_type(2))) _Float16 f16x2;
typedef __attribute__((ext_vector_type(4))) float f32x4;

// ---------------------------------------------------------------------------
// MFMA GEMM: C[M,N] = A[M,K] @ W[N,K]^T (+bias/res/relu).
// TM in {64,128}; N-tile 128. BK=64, mfma_f32_16x16x32_f16, XOR-swizzled LDS.
// SPLIT=1: hi/lo split-fp16, 3 MFMAs/pair (~fp32 accuracy).
// F16IN: 0 = A,W fp32 (convert in-kernel); 1 = A,W fp16; 2 = A,W split fp16
// hi/lo (Avl/Wvl, SPLIT=1); 3 = A fp16, W fp32-converted (SPLIT=0).
// E16: epilogue writes fp16 hi (Ch16) (+lo Cl16 if SPLIT); also fp32 C if C!=0.
// OREMAP: output row (s*NB+b) -> (b*S_LEN+s).
// NOTE: A and C must NOT alias (blocks of one dispatch race).
// ---------------------------------------------------------------------------
template<int TM, int SPLIT, int F16IN, bool BIAS, bool RES, bool RELU, bool OREMAP, bool E16>
__global__ __launch_bounds__(256)
void hgemm_k(const void* __restrict__ Av, const void* __restrict__ Wv,
             const float* __restrict__ bias, const float* __restrict__ Rsrc, int ldr,
             float* __restrict__ C, int ldc, int M, int N, int K,
             _Float16* __restrict__ Ch16, _Float16* __restrict__ Cl16,
             const void* __restrict__ Avl, const void* __restrict__ Wvl)
{
  constexpr int MI = TM / 32;
  constexpr int ATPR = 256 / TM;
  constexpr int ACOL = 64 / ATPR;
  constexpr bool AF16 = (F16IN >= 1);
  constexpr bool WF16 = (F16IN == 1 || F16IN == 2);
  __shared__ __align__(16) _Float16 Ah[TM*64];
  __shared__ __align__(16) _Float16 Bh[128*64];
  __shared__ __align__(16) _Float16 Al[SPLIT ? TM*64 : 8];
  __shared__ __align__(16) _Float16 Bl[SPLIT ? 128*64 : 8];
  const int t = threadIdx.x;
  const int m0 = blockIdx.y * TM, n0 = blockIdx.x * 128;

  const int arow = t / ATPR, apart = t % ATPR;
  const int brow = t >> 1, bpart = t & 1;

  const float*    Af  = (const float*)Av;
  const _Float16* Axh = (const _Float16*)Av;
  const _Float16* Axl = (const _Float16*)Avl;
  const float*    Wf  = (const float*)Wv;
  const _Float16* Wxh = (const _Float16*)Wv;
  const _Float16* Wxl = (const _Float16*)Wvl;
  const long aoff = (long)(m0 + arow) * K + apart * ACOL;
  const long boff = (long)(n0 + brow) * K + bpart * 32;

  const int lane = t & 63, wave = t >> 6;
  const int wm = wave >> 1, wn = wave & 1;
  const int lr = lane & 15, lk = lane >> 4;

  f32x4 acc[MI][4];
#pragma unroll
  for (int mi = 0; mi < MI; ++mi)
#pragma unroll
    for (int ni = 0; ni < 4; ++ni)
#pragma unroll
      for (int e = 0; e < 4; ++e) acc[mi][ni][e] = 0.f;

  float4 a4[ACOL/4], b4[8];
  f16x8  a16[ACOL/8], b16[4];
  f16x8  a16l[F16IN==2 ? ACOL/8 : 1], b16l[F16IN==2 ? 4 : 1];
  if (AF16) {
#pragma unroll
    for (int g = 0; g < ACOL/8; ++g) a16[g] = *(const f16x8*)(Axh + aoff + g*8);
    if (F16IN == 2) {
#pragma unroll
      for (int g = 0; g < ACOL/8; ++g) a16l[g] = *(const f16x8*)(Axl + aoff + g*8);
    }
  } else {
#pragma unroll
    for (int j = 0; j < ACOL/4; ++j) a4[j] = *(const float4*)(Af + aoff + j*4);
  }
  if (WF16) {
#pragma unroll
    for (int g = 0; g < 4; ++g) b16[g] = *(const f16x8*)(Wxh + boff + g*8);
    if (F16IN == 2) {
#pragma unroll
      for (int g = 0; g < 4; ++g) b16l[g] = *(const f16x8*)(Wxl + boff + g*8);
    }
  } else {
#pragma unroll
    for (int j = 0; j < 8; ++j) b4[j] = *(const float4*)(Wf + boff + j*4);
  }

  for (int k0 = 0; k0 < K; k0 += 64) {
    __syncthreads();
    if (AF16) {
#pragma unroll
      for (int g = 0; g < ACOL/8; ++g) {
        const int sw = (apart*ACOL*2 + g*16) ^ ((arow & 7) << 4);
        *(f16x8*)((char*)Ah + arow*128 + sw) = a16[g];
        if (F16IN == 2) *(f16x8*)((char*)Al + arow*128 + sw) = a16l[g];
      }
    } else {
      const float* af = (const float*)a4;
#pragma unroll
      for (int g = 0; g < ACOL/8; ++g) {
        f16x8 h, l;
#pragma unroll
        for (int j = 0; j < 8; ++j) {
          float xv = af[g*8+j];
          _Float16 hh = (_Float16)xv;
          h[j] = hh;
          if (SPLIT) l[j] = (_Float16)(xv - (float)hh);
        }
        const int sw = (apart*ACOL*2 + g*16) ^ ((arow & 7) << 4);
        *(f16x8*)((char*)Ah + arow*128 + sw) = h;
        if (SPLIT) *(f16x8*)((char*)Al + arow*128 + sw) = l;
      }
    }
    if (WF16) {
#pragma unroll
      for (int g = 0; g < 4; ++g) {
        const int sw = (bpart*64 + g*16) ^ ((brow & 7) << 4);
        *(f16x8*)((char*)Bh + brow*128 + sw) = b16[g];
        if (F16IN == 2) *(f16x8*)((char*)Bl + brow*128 + sw) = b16l[g];
      }
    } else {
      const float* bf = (const float*)b4;
#pragma unroll
      for (int g = 0; g < 4; ++g) {
        f16x8 h, l;
#pragma unroll
        for (int j = 0; j < 8; ++j) {
          float xv = bf[g*8+j];
          _Float16 hh = (_Float16)xv;
          h[j] = hh;
          if (SPLIT) l[j] = (_Float16)(xv - (float)hh);
        }
        const int sw = (bpart*64 + g*16) ^ ((brow & 7) << 4);
        *(f16x8*)((char*)Bh + brow*128 + sw) = h;
        if (SPLIT) *(f16x8*)((char*)Bl + brow*128 + sw) = l;
      }
    }
    __syncthreads();
    if (k0 + 64 < K) {
      if (AF16) {
#pragma unroll
        for (int g = 0; g < ACOL/8; ++g) a16[g] = *(const f16x8*)(Axh + aoff + k0 + 64 + g*8);
        if (F16IN == 2) {
#pragma unroll
          for (int g = 0; g < ACOL/8; ++g) a16l[g] = *(const f16x8*)(Axl + aoff + k0 + 64 + g*8);
        }
      } else {
#pragma unroll
        for (int j = 0; j < ACOL/4; ++j) a4[j] = *(const float4*)(Af + aoff + k0 + 64 + j*4);
      }
      if (WF16) {
#pragma unroll
        for (int g = 0; g < 4; ++g) b16[g] = *(const f16x8*)(Wxh + boff + k0 + 64 + g*8);
        if (F16IN == 2) {
#pragma unroll
          for (int g = 0; g < 4; ++g) b16l[g] = *(const f16x8*)(Wxl + boff + k0 + 64 + g*8);
        }
      } else {
#pragma unroll
        for (int j = 0; j < 8; ++j) b4[j] = *(const float4*)(Wf + boff + k0 + 64 + j*4);
      }
    }
#pragma unroll
    for (int kk = 0; kk < 2; ++kk) {
      f16x8 afh[MI], bfh[4], afl[MI], bfl[4];
#pragma unroll
      for (int mi = 0; mi < MI; ++mi) {
        const int r = wm*(TM/2) + mi*16 + lr;
        const int bo = (lk*16 + kk*64) ^ ((r & 7) << 4);
        afh[mi] = *(const f16x8*)((const char*)Ah + r*128 + bo);
        if (SPLIT) afl[mi] = *(const f16x8*)((const char*)Al + r*128 + bo);
      }
#pragma unroll
      for (int ni = 0; ni < 4; ++ni) {
        const int r = wn*64 + ni*16 + lr;
        const int bo = (lk*16 + kk*64) ^ ((r & 7) << 4);
        bfh[ni] = *(const f16x8*)((const char*)Bh + r*128 + bo);
        if (SPLIT) bfl[ni] = *(const f16x8*)((const char*)Bl + r*128 + bo);
      }
#pragma unroll
      for (int mi = 0; mi < MI; ++mi)
#pragma unroll
        for (int ni = 0; ni < 4; ++ni) {
          acc[mi][ni] = __builtin_amdgcn_mfma_f32_16x16x32_f16(afh[mi], bfh[ni], acc[mi][ni], 0, 0, 0);
          if (SPLIT) {
            acc[mi][ni] = __builtin_amdgcn_mfma_f32_16x16x32_f16(afh[mi], bfl[ni], acc[mi][ni], 0, 0, 0);
            acc[mi][ni] = __builtin_amdgcn_mfma_f32_16x16x32_f16(afl[mi], bfh[ni], acc[mi][ni], 0, 0, 0);
          }
        }
    }
  }

  float bvv[4];
  if (BIAS) {
#pragma unroll
    for (int ni = 0; ni < 4; ++ni) bvv[ni] = bias[n0 + wn*64 + ni*16 + lr];
  }
#pragma unroll
  for (int mi = 0; mi < MI; ++mi)
#pragma unroll
  for (int i = 0; i < 4; ++i) {
    const int rm = m0 + wm*(TM/2) + mi*16 + lk*4 + i;
    long orow = rm;
    if (OREMAP) orow = (long)(rm & (NB-1)) * S_LEN + (rm >> 3);
#pragma unroll
    for (int ni = 0; ni < 4; ++ni) {
      const int col = n0 + wn*64 + ni*16 + lr;
      float v = acc[mi][ni][i];
      if (BIAS) v += bvv[ni];
      if (RES)  v += Rsrc[(long)rm*ldr + col];
      if (RELU) v = fmaxf(v, 0.f);
      if (E16) {
        _Float16 hv = (_Float16)v;
        Ch16[(long)rm*ldc + col] = hv;
        if (SPLIT) Cl16[(long)rm*ldc + col] = (_Float16)(v - (float)hv);
        if (C != nullptr) C[orow*(long)ldc + col] = v;
      } else {
        C[orow*(long)ldc + col] = v;
      }
    }
  }
}

// ---------------------------------------------------------------------------
// Swapped-operand flash attention (validated structure, round 12/13).
// S^T = mfma(K,Q): lane owns q = qb*16+lr with 16 key-scores local; softmax is
// local ops + 2 shfl; P converts in-register to the B-fragment of
// mfma_f32_16x16x16_f16 -> NO P LDS round-trip. PV: O^T[d][q], A = V^T (b64
// LDS reads). SPLIT=1 (encoder): hi/lo split operands, 3 MFMAs/pair, split
// hi/lo output. SPLIT=0 (decoder): plain fp16, hi-only output.
// Grid: (bh, s0-tile) — same-KV blocks share an XCD.
// ---------------------------------------------------------------------------
template<int SPLIT>
__global__ __launch_bounds__(256)
void sattn_k(const _Float16* __restrict__ Qh, const _Float16* __restrict__ Ql, int ldq,
             const _Float16* __restrict__ Kh, const _Float16* __restrict__ Kl, int ldk,
             const _Float16* __restrict__ Vh, const _Float16* __restrict__ Vl, int ldv,
             _Float16* __restrict__ Oh, _Float16* __restrict__ Ol, int ldo)
{
  __shared__ __align__(16) char Kb[8192];
  __shared__ __align__(16) char Vb[8192];
  __shared__ __align__(16) char Klo[SPLIT ? 8192 : 16];
  __shared__ __align__(16) char Vlo[SPLIT ? 8192 : 16];

  const int t = threadIdx.x;
  const int b = blockIdx.x >> 3, hd = blockIdx.x & 7;
  const int s0 = blockIdx.y * 128;
  const int qoff = hd * DH;
  const int wave = t >> 6, lane = t & 63;
  const int lr = lane & 15, lk = lane >> 4;
  const int krow = t >> 2, kqd = t & 3;
  const int vtp = t & 31, vdc = t >> 5;

  // Q fragments (B-side of swapped QK), pre-scaled by 1/8 (exact)
  f16x8 qa[2][2], qal[2][2];
#pragma unroll
  for (int qb = 0; qb < 2; ++qb)
#pragma unroll
    for (int kk = 0; kk < 2; ++kk) {
      const int q = s0 + wave*32 + qb*16 + lr;
      const long base = ((long)q*NB + b)*ldq + qoff + kk*32 + lk*8;
      f16x8 v = *(const f16x8*)(Qh + base);
#pragma unroll
      for (int e = 0; e < 8; ++e) v[e] = v[e] * (_Float16)0.125f;
      qa[qb][kk] = v;
      if (SPLIT) {
        f16x8 w = *(const f16x8*)(Ql + base);
#pragma unroll
        for (int e = 0; e < 8; ++e) w[e] = w[e] * (_Float16)0.125f;
        qal[qb][kk] = w;
      }
    }

  float m_run[2] = {-INFINITY, -INFINITY};
  float l_run[2] = {0.f, 0.f};
  f32x4 oaccT[4][2];
#pragma unroll
  for (int nd = 0; nd < 4; ++nd)
#pragma unroll
    for (int qb = 0; qb < 2; ++qb)
#pragma unroll
      for (int e = 0; e < 4; ++e) oaccT[nd][qb][e] = 0.f;

  f16x8 kr0, kr1, krl0, krl1, vr0, vr1, vrl0, vrl1;
  {
    const long kb = ((long)krow*NB + b)*ldk + qoff + kqd*16;
    kr0 = *(const f16x8*)(Kh + kb);
    kr1 = *(const f16x8*)(Kh + kb + 8);
    if (SPLIT) { krl0 = *(const f16x8*)(Kl + kb); krl1 = *(const f16x8*)(Kl + kb + 8); }
    const long vb = ((long)(2*vtp)*NB + b)*ldv + qoff + vdc*8;
    vr0 = *(const f16x8*)(Vh + vb);
    vr1 = *(const f16x8*)(Vh + vb + (long)NB*ldv);
    if (SPLIT) { vrl0 = *(const f16x8*)(Vl + vb); vrl1 = *(const f16x8*)(Vl + vb + (long)NB*ldv); }
  }

  for (int t0 = 0; t0 < S_LEN; t0 += 64) {
    __syncthreads();
    {
      const int sw0 = (kqd*32) ^ ((krow & 7) << 4);
      const int sw1 = (kqd*32 + 16) ^ ((krow & 7) << 4);
      *(f16x8*)(Kb + krow*128 + sw0) = kr0;
      *(f16x8*)(Kb + krow*128 + sw1) = kr1;
      if (SPLIT) {
        *(f16x8*)(Klo + krow*128 + sw0) = krl0;
        *(f16x8*)(Klo + krow*128 + sw1) = krl1;
      }
#pragma unroll
      for (int j = 0; j < 8; ++j) {
        const int dd = vdc*8 + j;
        const int off = dd*128 + ((vtp*4) ^ ((dd & 7) << 4));
        f16x2 hv = {vr0[j], vr1[j]};
        *(f16x2*)(Vb + off) = hv;
        if (SPLIT) {
          f16x2 lv = {vrl0[j], vrl1[j]};
          *(f16x2*)(Vlo + off) = lv;
        }
      }
    }
    if (t0 + 64 < S_LEN) {
      const long kb = ((long)(t0 + 64 + krow)*NB + b)*ldk + qoff + kqd*16;
      kr0 = *(const f16x8*)(Kh + kb);
      kr1 = *(const f16x8*)(Kh + kb + 8);
      if (SPLIT) { krl0 = *(const f16x8*)(Kl + kb); krl1 = *(const f16x8*)(Kl + kb + 8); }
      const long vb = ((long)(t0 + 64 + 2*vtp)*NB + b)*ldv + qoff + vdc*8;
      vr0 = *(const f16x8*)(Vh + vb);
      vr1 = *(const f16x8*)(Vh + vb + (long)NB*ldv);
      if (SPLIT) { vrl0 = *(const f16x8*)(Vl + vb); vrl1 = *(const f16x8*)(Vl + vb + (long)NB*ldv); }
    }
    __syncthreads();

    // ---- S^T[key][q] = mfma(K, Q) (+ split cross terms) ----
    f32x4 st[4][2];
#pragma unroll
    for (int ki = 0; ki < 4; ++ki)
#pragma unroll
      for (int qb = 0; qb < 2; ++qb)
#pragma unroll
        for (int e = 0; e < 4; ++e) st[ki][qb][e] = 0.f;
#pragma unroll
    for (int kk = 0; kk < 2; ++kk) {
      f16x8 kb[4], kbl[4];
#pragma unroll
      for (int ki = 0; ki < 4; ++ki) {
        const int r = ki*16 + lr;
        const int bo = (lk*16 + kk*64) ^ ((r & 7) << 4);
        kb[ki] = *(const f16x8*)(Kb + r*128 + bo);
        if (SPLIT) kbl[ki] = *(const f16x8*)(Klo + r*128 + bo);
      }
#pragma unroll
      for (int ki = 0; ki < 4; ++ki)
#pragma unroll
        for (int qb = 0; qb < 2; ++qb) {
          st[ki][qb] = __builtin_amdgcn_mfma_f32_16x16x32_f16(kb[ki], qa[qb][kk], st[ki][qb], 0, 0, 0);
          if (SPLIT) {
            st[ki][qb] = __builtin_amdgcn_mfma_f32_16x16x32_f16(kb[ki], qal[qb][kk], st[ki][qb], 0, 0, 0);
            st[ki][qb] = __builtin_amdgcn_mfma_f32_16x16x32_f16(kbl[ki], qa[qb][kk], st[ki][qb], 0, 0, 0);
          }
        }
    }

    // ---- online softmax: lane owns q = qb*16+lr; 16 keys local + 2 shfl ----
    f16x4 pbh[4][2], pbl[4][2];
#pragma unroll
    for (int qb = 0; qb < 2; ++qb) {
      float rm = st[0][qb][0];
#pragma unroll
      for (int ki = 0; ki < 4; ++ki)
#pragma unroll
        for (int e = 0; e < 4; ++e) rm = fmaxf(rm, st[ki][qb][e]);
      rm = fmaxf(rm, __shfl_xor(rm, 16));
      rm = fmaxf(rm, __shfl_xor(rm, 32));
      const float mnew = fmaxf(m_run[qb], rm);
      const float corr = __expf(m_run[qb] - mnew);
      m_run[qb] = mnew;
      float ls = 0.f;
#pragma unroll
      for (int ki = 0; ki < 4; ++ki) {
        f16x4 ph, pl;
#pragma unroll
        for (int e = 0; e < 4; ++e) {
          float p = __expf(st[ki][qb][e] - mnew);
          ls += p;
          _Float16 h = (_Float16)p;
          ph[e] = h;
          if (SPLIT) pl[e] = (_Float16)(p - (float)h);
        }
        pbh[ki][qb] = ph;
        if (SPLIT) pbl[ki][qb] = pl;
      }
      ls += __shfl_xor(ls, 16);
      ls += __shfl_xor(ls, 32);
      l_run[qb] = l_run[qb]*corr + ls;
#pragma unroll
      for (int nd = 0; nd < 4; ++nd)
#pragma unroll
        for (int e = 0; e < 4; ++e) oaccT[nd][qb][e] *= corr;
    }

    // ---- O^T[d][q] += mfma16(V^T, P^T) — P never touches LDS ----
#pragma unroll
    for (int ki = 0; ki < 4; ++ki) {
      f16x4 avh[4], avl[4];
#pragma unroll
      for (int nd = 0; nd < 4; ++nd) {
        const int row = nd*16 + lr;
        const int bo = (ki*32 + lk*8) ^ ((row & 7) << 4);
        avh[nd] = *(const f16x4*)(Vb + row*128 + bo);
        if (SPLIT) avl[nd] = *(const f16x4*)(Vlo + row*128 + bo);
      }
#pragma unroll
      for (int nd = 0; nd < 4; ++nd)
#pragma unroll
        for (int qb = 0; qb < 2; ++qb) {
          oaccT[nd][qb] = __builtin_amdgcn_mfma_f32_16x16x16f16(avh[nd], pbh[ki][qb], oaccT[nd][qb], 0, 0, 0);
          if (SPLIT) {
            oaccT[nd][qb] = __builtin_amdgcn_mfma_f32_16x16x16f16(avh[nd], pbl[ki][qb], oaccT[nd][qb], 0, 0, 0);
            oaccT[nd][qb] = __builtin_amdgcn_mfma_f32_16x16x16f16(avl[nd], pbh[ki][qb], oaccT[nd][qb], 0, 0, 0);
          }
        }
    }
  }

  // ---- epilogue: O[q][d], packed b64 stores; SPLIT also writes lo ----
#pragma unroll
  for (int qb = 0; qb < 2; ++qb) {
    const float inv = 1.0f / l_run[qb];
    const int q = s0 + wave*32 + qb*16 + lr;
    const long base = ((long)q * NB + b) * ldo + qoff;
#pragma unroll
    for (int nd = 0; nd < 4; ++nd) {
      f16x4 o, ol;
#pragma unroll
      for (int e = 0; e < 4; ++e) {
        float v = oaccT[nd][qb][e] * inv;
        _Float16 h = (_Float16)v;
        o[e] = h;
        if (SPLIT) ol[e] = (_Float16)(v - (float)h);
      }
      *(f16x4*)(Oh + base + nd*16 + lk*4) = o;
      if (SPLIT) *(f16x4*)(Ol + base + nd*16 + lk*4) = ol;
    }
  }
}

// ---------------------------------------------------------------------------
// LayerNorm over c=512, one wave per row.
// ES: 0 = fp32 only; 1 = fp32 + split fp16 hi/lo; 2 = fp32 + fp16 hi.
// ---------------------------------------------------------------------------
template<int ES>
__global__ __launch_bounds__(256)
void ln_k(const float* __restrict__ X, const float* __restrict__ g,
          const float* __restrict__ bb, float* __restrict__ Y,
          _Float16* __restrict__ Yh, _Float16* __restrict__ Yl)
{
  const int t = threadIdx.x;
  const int lane = t & 63;
  const long row = (long)blockIdx.x * 4 + (t >> 6);
  const float* xr = X + row * CDIM;
  float4 v0 = *(const float4*)(xr + lane*4);
  float4 v1 = *(const float4*)(xr + 256 + lane*4);
  float s = v0.x+v0.y+v0.z+v0.w + v1.x+v1.y+v1.z+v1.w;
#pragma unroll
  for (int off = 1; off < 64; off <<= 1) s += __shfl_xor(s, off);
  const float mean = s * (1.0f/512.0f);
  float d[8] = {v0.x-mean, v0.y-mean, v0.z-mean, v0.w-mean,
                v1.x-mean, v1.y-mean, v1.z-mean, v1.w-mean};
  float sq = d[0]*d[0]+d[1]*d[1]+d[2]*d[2]+d[3]*d[3]
           + d[4]*d[4]+d[5]*d[5]+d[6]*d[6]+d[7]*d[7];
#pragma unroll
  for (int off = 1; off < 64; off <<= 1) sq += __shfl_xor(sq, off);
  const float inv = 1.0f / sqrtf(sq * (1.0f/512.0f) + 1e-5f);
  float4 g0 = *(const float4*)(g + lane*4);
  float4 g1 = *(const float4*)(g + 256 + lane*4);
  float4 b0 = *(const float4*)(bb + lane*4);
  float4 b1 = *(const float4*)(bb + 256 + lane*4);
  float o[8];
  o[0] = d[0]*inv*g0.x + b0.x; o[1] = d[1]*inv*g0.y + b0.y;
  o[2] = d[2]*inv*g0.z + b0.z; o[3] = d[3]*inv*g0.w + b0.w;
  o[4] = d[4]*inv*g1.x + b1.x; o[5] = d[5]*inv*g1.y + b1.y;
  o[6] = d[6]*inv*g1.z + b1.z; o[7] = d[7]*inv*g1.w + b1.w;
  *(float4*)(Y + row*CDIM + lane*4) = *(float4*)&o[0];
  *(float4*)(Y + row*CDIM + 256 + lane*4) = *(float4*)&o[4];
  if (ES) {
    f16x4 h0, h1, l0, l1;
#pragma unroll
    for (int j = 0; j < 4; ++j) {
      _Float16 h = (_Float16)o[j];     h0[j] = h;
      _Float16 k = (_Float16)o[4+j];   h1[j] = k;
      if (ES == 1) { l0[j] = (_Float16)(o[j] - (float)h); l1[j] = (_Float16)(o[4+j] - (float)k); }
    }
    *(f16x4*)(Yh + row*CDIM + lane*4) = h0;
    *(f16x4*)(Yh + row*CDIM + 256 + lane*4) = h1;
    if (ES == 1) {
      *(f16x4*)(Yl + row*CDIM + lane*4) = l0;
      *(f16x4*)(Yl + row*CDIM + 256 + lane*4) = l1;
    }
  }
}

// ---------------------------------------------------------------------------
// Pack x (N,C,H,W) -> enc_flat (S,n,c); posisted fp32 + split fp16 hi/lo.
// ---------------------------------------------------------------------------
__global__ void pack_pe_k(const float* __restrict__ x, float* __restrict__ encf,
                          float* __restrict__ posd,
                          _Float16* __restrict__ posh, _Float16* __restrict__ posl)
{
  __shared__ float tl[32][33];
  const int b = blockIdx.z;
  const int s0 = blockIdx.x*32, c0 = blockIdx.y*32;
#pragma unroll
  for (int i = 0; i < 4; ++i) {
    int ci = threadIdx.y + i*8;
    tl[ci][threadIdx.x] = x[((long)b*CDIM + c0+ci)*S_LEN + s0 + threadIdx.x];
  }
  __syncthreads();
#pragma unroll
  for (int i = 0; i < 4; ++i) {
    int si = threadIdx.y + i*8;
    int s = s0 + si;
    int ch = c0 + threadIdx.x;
    float val = tl[threadIdx.x][si];
    long o = ((long)s*NB + b)*CDIM + ch;
    encf[o] = val;
    int pos = (ch < 256) ? (s & 31) : (s >> 5);
    int j = (ch & 255) >> 1;
    float dv = expf((float)(2*j) * (-9.210340371976184f / 256.0f));
    float ang = (float)pos * dv;
    float pe = (ch & 1) ? cosf(ang) : sinf(ang);
    float pv = val + pe;
    posd[o] = pv;
    _Float16 h = (_Float16)pv;
    posh[o] = h;
    posl[o] = (_Float16)(pv - (float)h);
  }
}

// (S,n,c) token-major -> (n,c,S) output layout
__global__ void tpose_k(const float* __restrict__ in, float* __restrict__ out)
{
  __shared__ float tl[32][33];
  const int b = blockIdx.z;
  const int s0 = blockIdx.x*32, c0 = blockIdx.y*32;
#pragma unroll
  for (int i = 0; i < 4; ++i) {
    int si = threadIdx.y + i*8;
    tl[si][threadIdx.x] = in[((long)(s0+si)*NB + b)*CDIM + c0 + threadIdx.x];
  }
  __syncthreads();
#pragma unroll
  for (int i = 0; i < 4; ++i) {
    int ci = threadIdx.y + i*8;
    out[((long)b*CDIM + c0+ci)*S_LEN + s0 + threadIdx.x] = tl[threadIdx.x][ci];
  }
}

// cb_w (c,K) -> transposed split-fp16 codebook [K][c] hi/lo
__global__ void cbt16_k(const float* __restrict__ cb,
                        _Float16* __restrict__ outh, _Float16* __restrict__ outl)
{
  __shared__ float tl[32][33];
  const int k0 = blockIdx.x*32, c0 = blockIdx.y*32;
#pragma unroll
  for (int i = 0; i < 4; ++i) {
    int ci = threadIdx.y + i*8;
    tl[ci][threadIdx.x] = cb[(long)(c0+ci)*KCB + k0 + threadIdx.x];
  }
  __syncthreads();
#pragma unroll
  for (int i = 0; i < 4; ++i) {
    int ki = threadIdx.y + i*8;
    float v = tl[threadIdx.x][ki];
    _Float16 h = (_Float16)v;
    outh[(long)(k0+ki)*CDIM + c0 + threadIdx.x] = h;
    outl[(long)(k0+ki)*CDIM + c0 + threadIdx.x] = (_Float16)(v - (float)h);
  }
}

// fp32 -> fp16 elementwise, 8 per thread
__global__ __launch_bounds__(256)
void conv16_k(const float* __restrict__ in, _Float16* __restrict__ out)
{
  const long i = ((long)blockIdx.x * 256 + threadIdx.x) * 8;
  float4 v0 = *(const float4*)(in + i);
  float4 v1 = *(const float4*)(in + i + 4);
  f16x8 h;
  h[0]=(_Float16)v0.x; h[1]=(_Float16)v0.y; h[2]=(_Float16)v0.z; h[3]=(_Float16)v0.w;
  h[4]=(_Float16)v1.x; h[5]=(_Float16)v1.y; h[6]=(_Float16)v1.z; h[7]=(_Float16)v1.w;
  *(f16x8*)(out + i) = h;
}

// fp32 -> split fp16 hi/lo, 8 per thread
__global__ __launch_bounds__(256)
void convsplit_k(const float* __restrict__ in, _Float16* __restrict__ oh,
                 _Float16* __restrict__ ol)
{
  const long i = ((long)blockIdx.x * 256 + threadIdx.x) * 8;
  float4 v0 = *(const float4*)(in + i);
  float4 v1 = *(const float4*)(in + i + 4);
  float vv[8] = {v0.x,v0.y,v0.z,v0.w,v1.x,v1.y,v1.z,v1.w};
  f16x8 h, l;
#pragma unroll
  for (int j = 0; j < 8; ++j) {
    _Float16 hh = (_Float16)vv[j];
    h[j] = hh;
    l[j] = (_Float16)(vv[j] - (float)hh);
  }
  *(f16x8*)(oh + i) = h;
  *(f16x8*)(ol + i) = l;
}

// Per-token row of logits: argmax (np first-occurrence) + write P (fp16)
__global__ __launch_bounds__(256)
void simstats_k(const float* __restrict__ logits, _Float16* __restrict__ Pbuf,
                int* __restrict__ codes_tok, float* __restrict__ codes_out)
{
  const long phys = blockIdx.x;
  const float* rowp = logits + phys * KCB;
  const int t = threadIdx.x;
  float vals[16];
#pragma unroll
  for (int rep = 0; rep < 4; ++rep) {
    float4 v = *(const float4*)(rowp + rep*1024 + t*4);
    vals[rep*4+0]=v.x; vals[rep*4+1]=v.y; vals[rep*4+2]=v.z; vals[rep*4+3]=v.w;
  }
  float mv = -INFINITY; int mi = 0;
#pragma unroll
  for (int rep = 0; rep < 4; ++rep)
#pragma unroll
    for (int j = 0; j < 4; ++j) {
      float xv = vals[rep*4+j];
      int ix = rep*1024 + t*4 + j;
      if (xv > mv) { mv = xv; mi = ix; }
    }
  const int lane = t & 63, wid = t >> 6;
#pragma unroll
  for (int off = 1; off < 64; off <<= 1) {
    float ov = __shfl_xor(mv, off);
    int   oi = __shfl_xor(mi, off);
    if (ov > mv || (ov == mv && oi < mi)) { mv = ov; mi = oi; }
  }
  __shared__ float smax[4]; __shared__ int sidx[4]; __shared__ float ssum[4];
  __shared__ float fm; __shared__ int fi; __shared__ float sinv;
  if (lane == 0) { smax[wid] = mv; sidx[wid] = mi; }
  __syncthreads();
  if (t == 0) {
    float bm = smax[0]; int bi = sidx[0];
    for (int wq = 1; wq < 4; ++wq)
      if (smax[wq] > bm || (smax[wq] == bm && sidx[wq] < bi)) { bm = smax[wq]; bi = sidx[wq]; }
    fm = bm; fi = bi;
  }
  __syncthreads();
  const float Mx = fm;
  float se = 0.f;
#pragma unroll
  for (int q = 0; q < 16; ++q) se += __expf(vals[q] - Mx);
#pragma unroll
  for (int off = 1; off < 64; off <<= 1) se += __shfl_xor(se, off);
  if (lane == 0) ssum[wid] = se;
  __syncthreads();
  const int b = (int)(phys >> 10), s = (int)(phys & 1023);
  if (t == 0) {
    float tot = ssum[0]+ssum[1]+ssum[2]+ssum[3];
    sinv = 1.0f / tot;
    codes_tok[s*NB + b] = fi;
    codes_out[phys] = (float)fi;
  }
  __syncthreads();
  const float inv = sinv;
  _Float16* prow = Pbuf + ((long)s*NB + b) * KCB;
#pragma unroll
  for (int rep = 0; rep < 4; ++rep) {
    f16x4 pv;
#pragma unroll
    for (int j = 0; j < 4; ++j) pv[j] = (_Float16)(__expf(vals[rep*4+j] - Mx) * inv);
    *(f16x4*)(prow + rep*1024 + t*4) = pv;
  }
}

// quant = (hard - soft) + soft; emit hard fp32 and quant fp32 + fp16-hi.
__global__ __launch_bounds__(128)
void quant_k(const float* __restrict__ soft, const int* __restrict__ codes_tok,
             const _Float16* __restrict__ cbh, const _Float16* __restrict__ cbl,
             float* __restrict__ quant, float* __restrict__ hardb,
             _Float16* __restrict__ qh16)
{
  const int r = blockIdx.x;
  const int code = codes_tok[r];
  const int c = threadIdx.x * 4;
  f16x4 hh = *(const f16x4*)(cbh + (long)code*CDIM + c);
  f16x4 hl = *(const f16x4*)(cbl + (long)code*CDIM + c);
  float4 sf = *(const float4*)(soft + (long)r*CDIM + c);
  float4 h, q;
  h.x = (float)hh[0] + (float)hl[0]; h.y = (float)hh[1] + (float)hl[1];
  h.z = (float)hh[2] + (float)hl[2]; h.w = (float)hh[3] + (float)hl[3];
  q.x = (h.x - sf.x) + sf.x; q.y = (h.y - sf.y) + sf.y;
  q.z = (h.z - sf.z) + sf.z; q.w = (h.w - sf.w) + sf.w;
  *(float4*)(quant + (long)r*CDIM + c) = q;
  *(float4*)(hardb + (long)r*CDIM + c) = h;
  f16x4 qh = {(_Float16)q.x, (_Float16)q.y, (_Float16)q.z, (_Float16)q.w};
  *(f16x4*)(qh16 + (long)r*CDIM + c) = qh;
}

// Detect the storage format of the bool mask buffer.
__global__ void maskdetect_k(const void* __restrict__ mask, int* __restrict__ flag)
{
  const unsigned int* wds = (const unsigned int*)mask;
  int t = threadIdx.x;
  int okI = 1, okF = 1, okL = 1;
  for (int i = t; i < 2048; i += 256) {
    unsigned int u = wds[i];
    if (u > 1u) okI = 0;
    if (u != 0u && u != 0x3F800000u) okF = 0;
    if ((i & 1) ? (u != 0u) : (u > 1u)) okL = 0;
  }
  __shared__ int sI, sF, sL;
  if (t == 0) { sI = 1; sF = 1; sL = 1; }
  __syncthreads();
  if (!okI) atomicAnd(&sI, 0);
  if (!okF) atomicAnd(&sF, 0);
  if (!okL) atomicAnd(&sL, 0);
  __syncthreads();
  if (t == 0) {
    int f;
    if (sI && sL) f = 3;
    else if (sI)  f = 1;
    else if (sF)  f = 2;
    else          f = 0;
    *flag = f;
  }
}

// mixed = mask ? enc_flat : post; fp32 + fp16-hi outputs
__global__ __launch_bounds__(256)
void mixed_k(const float* __restrict__ encf, const float* __restrict__ post,
             const void* __restrict__ mask, const int* __restrict__ flag,
             float* __restrict__ outx, _Float16* __restrict__ outh)
{
  long gid = (long)blockIdx.x * blockDim.x + threadIdx.x;
  int r = (int)(gid >> 7);
  int c = (int)(gid & 127) * 4;
  int f = *flag;
  bool mv;
  if (f == 0)      mv = ((const unsigned char*)mask)[r] != 0;
  else if (f == 1) mv = ((const int*)mask)[r] != 0;
  else if (f == 3) mv = ((const long long*)mask)[r] != 0;
  else             mv = ((const float*)mask)[r] != 0.0f;
  const float* src = mv ? encf : post;
  float4 v = *(const float4*)(src + (long)r*CDIM + c);
  *(float4*)(outx + (long)r*CDIM + c) = v;
  f16x4 h = {(_Float16)v.x, (_Float16)v.y, (_Float16)v.z, (_Float16)v.w};
  *(f16x4*)(outh + (long)r*CDIM + c) = h;
}

extern "C" void kernel_launch(void* const* d_in, const int* in_sizes, int n_in,
                              void* d_out, int out_size, void* d_ws, size_t ws_size,
                              hipStream_t stream)
{
  const float* x       = (const float*)d_in[0];
  const float* pre_w   = (const float*)d_in[1];
  const float* pre_b   = (const float*)d_in[2];
  const float* post_w  = (const float*)d_in[3];
  const float* post_b  = (const float*)d_in[4];
  const float* cb_w    = (const float*)d_in[5];
  const float* e_qkv_w = (const float*)d_in[6];
  const float* e_qkv_b = (const float*)d_in[7];
  const float* e_o_w   = (const float*)d_in[8];
  const float* e_o_b   = (const float*)d_in[9];
  const float* e_ln1_w = (const float*)d_in[10];
  const float* e_ln1_b = (const float*)d_in[11];
  const float* e_ln2_w = (const float*)d_in[12];
  const float* e_ln2_b = (const float*)d_in[13];
  const float* e_f1_w  = (const float*)d_in[14];
  const float* e_f1_b  = (const float*)d_in[15];
  const float* e_f2_w  = (const float*)d_in[16];
  const float* e_f2_b  = (const float*)d_in[17];
  const float* d_sqkv_w= (const float*)d_in[18];
  const float* d_sqkv_b= (const float*)d_in[19];
  const float* d_so_w  = (const float*)d_in[20];
  const float* d_so_b  = (const float*)d_in[21];
  const float* d_cqkv_w= (const float*)d_in[22];
  const float* d_cqkv_b= (const float*)d_in[23];
  const float* d_co_w  = (const float*)d_in[24];
  const float* d_co_b  = (const float*)d_in[25];
  const float* d_ln1w  = (const float*)d_in[26];
  const float* d_ln1b  = (const float*)d_in[27];
  const float* d_ln2w  = (const float*)d_in[28];
  const float* d_ln2b  = (const float*)d_in[29];
  const float* d_ln3w  = (const float*)d_in[30];
  const float* d_ln3b  = (const float*)d_in[31];
  const float* d_f1w   = (const float*)d_in[32];
  const float* d_f1b   = (const float*)d_in[33];
  const float* d_f2w   = (const float*)d_in[34];
  const float* d_f2b   = (const float*)d_in[35];
  const void*  mask    = d_in[36];

  float* out = (float*)d_out;
  float* o_quant  = out;
  float* o_high   = out + 4194304;
  float* o_softs  = out + 8388608;
  float* o_hards  = out + 12582912;
  float* o_codes  = out + 16777216;
  float* o_logits = out + 16785408;

  float* ws    = (float*)d_ws;
  float* ENC   = ws;
  float* Xb    = ws + TOKC;
  float* T1    = ws + 2*TOKC;
  float* T2    = ws + 3*TOKC;
  float* QKV   = ws + 4*TOKC;
  float* MEMB  = ws + 7*TOKC;
  float* CBREG = ws + 8*TOKC;
  int*   CODES = (int*)(CBREG + (long)KCB*CDIM);
  int*   FLAG  = CODES + NTOK;
  float* HARDB = QKV;
  float* QUANT = QKV + TOKC;
  _Float16* PBUF = (_Float16*)QKV;
  _Float16* CBH  = (_Float16*)T1;
  _Float16* QKVh = (_Float16*)QKV;
  _Float16* QKVl = QKVh + (long)NTOK*3*CDIM;
  _Float16* CQh  = (_Float16*)QKV;
  _Float16* KVh  = (_Float16*)(QKV + TOKC);
  _Float16* CBT16h = (_Float16*)CBREG;
  _Float16* CBT16l = CBT16h + (long)KCB*CDIM;
  _Float16* PREH = (_Float16*)T2;
  _Float16* PREL = PREH + TOKC;
  _Float16* AH16   = (_Float16*)ENC;
  _Float16* FH16   = AH16 + TOKC;
  _Float16* XH16   = ((_Float16*)QKV) + 4*TOKC;
  _Float16* MEMBH16= XH16 + TOKC;
  _Float16* QH16   = ((_Float16*)T1) + TOKC;

  const long WQSZ = (long)6*3*CDIM*CDIM;
  const long WSSZ = (long)6*CDIM*CDIM;
  _Float16* SCR  = (_Float16*)o_logits;
  _Float16* WQH = SCR;            _Float16* WQL = WQH + WQSZ;
  _Float16* WOH = WQL + WQSZ;     _Float16* WOL = WOH + WSSZ;
  _Float16* WF1H= WOL + WSSZ;     _Float16* WF1L= WF1H + WSSZ;
  _Float16* WF2H= WF1L + WSSZ;    _Float16* WF2L= WF2H + WSSZ;
  _Float16* WPH = WF2L + WSSZ;    _Float16* WPL = WPH + (long)CDIM*CDIM;
  _Float16* XH  = WPL + (long)CDIM*CDIM;  _Float16* XL  = XH + TOKC;
  _Float16* AH  = XL + TOKC;      _Float16* AL  = AH + TOKC;
  _Float16* L1H = AL + TOKC;      _Float16* L1L = L1H + TOKC;
  _Float16* H1H = L1L + TOKC;     _Float16* H1L = H1H + TOKC;

  const size_t NEED = (size_t)(8*TOKC + (long)KCB*CDIM + 2*NTOK + NTOK + 16) * 4;
  if (ws_size < NEED) return;

  const int M = NTOK;
  dim3 tgrid(S_LEN/32, CDIM/32, NB), tblk(32, 8);
  dim3 agrid(NB*8, S_LEN/128);

  pack_pe_k<<<tgrid, tblk, 0, stream>>>(x, ENC, Xb, XH, XL);
  cbt16_k<<<dim3(KCB/32, CDIM/32), tblk, 0, stream>>>(cb_w, CBT16h, CBT16l);
  maskdetect_k<<<1, 256, 0, stream>>>(mask, FLAG);
  convsplit_k<<<(int)(WQSZ/2048), 256, 0, stream>>>(e_qkv_w, WQH, WQL);
  convsplit_k<<<(int)(WSSZ/2048), 256, 0, stream>>>(e_o_w,  WOH,  WOL);
  convsplit_k<<<(int)(WSSZ/2048), 256, 0, stream>>>(e_f1_w, WF1H, WF1L);
  convsplit_k<<<(int)(WSSZ/2048), 256, 0, stream>>>(e_f2_w, WF2H, WF2L);
  convsplit_k<<<(int)(((long)CDIM*CDIM)/2048), 256, 0, stream>>>(pre_w, WPH, WPL);

  // -------- encoder (split-fp16 MFMA, swapped-operand attention) --------
  for (int i = 0; i < NLAYER; ++i) {
    hgemm_k<128,1,2,true,false,false,false,true><<<dim3(3*CDIM/128, M/128), 256, 0, stream>>>(
        XH, WQH + (long)i*3*CDIM*CDIM, e_qkv_b + i*3*CDIM, nullptr, 0,
        nullptr, 3*CDIM, M, 3*CDIM, CDIM, QKVh, QKVl, XL, WQL + (long)i*3*CDIM*CDIM);
    sattn_k<1><<<agrid, 256, 0, stream>>>(QKVh, QKVl, 3*CDIM,
        QKVh+CDIM, QKVl+CDIM, 3*CDIM, QKVh+2*CDIM, QKVl+2*CDIM, 3*CDIM,
        AH, AL, CDIM);
    hgemm_k<64,1,2,true,true,false,false,false><<<dim3(CDIM/128, M/64), 256, 0, stream>>>(
        AH, WOH + (long)i*CDIM*CDIM, e_o_b + i*CDIM, Xb, CDIM,
        T2, CDIM, M, CDIM, CDIM, nullptr, nullptr, AL, WOL + (long)i*CDIM*CDIM);
    ln_k<1><<<M/4, 256, 0, stream>>>(T2, e_ln1_w + i*CDIM, e_ln1_b + i*CDIM, T1, L1H, L1L);
    hgemm_k<64,1,2,true,false,true,false,true><<<dim3(CDIM/128, M/64), 256, 0, stream>>>(
        L1H, WF1H + (long)i*CDIM*CDIM, e_f1_b + i*CDIM, nullptr, 0,
        nullptr, CDIM, M, CDIM, CDIM, H1H, H1L, L1L, WF1L + (long)i*CDIM*CDIM);
    hgemm_k<64,1,2,true,true,false,false,false><<<dim3(CDIM/128, M/64), 256, 0, stream>>>(
        H1H, WF2H + (long)i*CDIM*CDIM, e_f2_b + i*CDIM, T1, CDIM,
        T2, CDIM, M, CDIM, CDIM, nullptr, nullptr, H1L, WF2L + (long)i*CDIM*CDIM);
    ln_k<1><<<M/4, 256, 0, stream>>>(T2, e_ln2_w + i*CDIM, e_ln2_b + i*CDIM, Xb, XH, XL);
  }

  // -------- codebook / quantizer --------
  hgemm_k<64,1,2,true,false,false,false,true><<<dim3(CDIM/128, M/64), 256, 0, stream>>>(
      XH, WPH, pre_b, nullptr, 0, T1, CDIM, M, CDIM, CDIM, PREH, PREL, XL, WPL);
  tpose_k<<<tgrid, tblk, 0, stream>>>(T1, o_high);
  hgemm_k<128,1,2,false,false,false,true,false><<<dim3(KCB/128, M/128), 256, 0, stream>>>(
      PREH, CBT16h, nullptr, nullptr, 0, o_logits, KCB, M, KCB, CDIM,
      nullptr, nullptr, PREL, CBT16l);
  conv16_k<<<(CDIM*(long)KCB)/(256*8), 256, 0, stream>>>(cb_w, CBH);
  simstats_k<<<NTOK, 256, 0, stream>>>(o_logits, PBUF, CODES, o_codes);
  hgemm_k<64,0,1,false,false,false,false,false><<<dim3(CDIM/128, M/64), 256, 0, stream>>>(
      PBUF, CBH, nullptr, nullptr, 0, T2, CDIM, M, CDIM, KCB,
      nullptr, nullptr, nullptr, nullptr);
  tpose_k<<<tgrid, tblk, 0, stream>>>(T2, o_softs);
  quant_k<<<NTOK, 128, 0, stream>>>(T2, CODES, CBT16h, CBT16l, QUANT, HARDB, QH16);
  tpose_k<<<tgrid, tblk, 0, stream>>>(HARDB, o_hards);
  hgemm_k<64,0,3,true,false,false,false,false><<<dim3(CDIM/128, M/64), 256, 0, stream>>>(
      QH16, post_w, post_b, nullptr, 0, MEMB, CDIM, M, CDIM, CDIM,
      nullptr, nullptr, nullptr, nullptr);
  mixed_k<<<4096, 256, 0, stream>>>(ENC, MEMB, mask, FLAG, Xb, XH16);
  conv16_k<<<(int)(TOKC/2048), 256, 0, stream>>>(MEMB, MEMBH16);

  // -------- decoder (f16 MFMA, swapped-operand attention) --------
  for (int i = 0; i < NLAYER; ++i) {
    hgemm_k<128,0,3,true,false,false,false,true><<<dim3(3*CDIM/128, M/128), 256, 0, stream>>>(
        XH16, d_sqkv_w + (long)i*3*CDIM*CDIM, d_sqkv_b + i*3*CDIM, nullptr, 0,
        nullptr, 3*CDIM, M, 3*CDIM, CDIM, QKVh, nullptr, nullptr, nullptr);
    sattn_k<0><<<agrid, 256, 0, stream>>>(QKVh, nullptr, 3*CDIM,
        QKVh+CDIM, nullptr, 3*CDIM, QKVh+2*CDIM, nullptr, 3*CDIM,
        AH16, nullptr, CDIM);
    hgemm_k<64,0,3,true,true,false,false,false><<<dim3(CDIM/128, M/64), 256, 0, stream>>>(
        AH16, d_so_w + (long)i*CDIM*CDIM, d_so_b + i*CDIM, Xb, CDIM,
        T2, CDIM, M, CDIM, CDIM, nullptr, nullptr, nullptr, nullptr);
    ln_k<2><<<M/4, 256, 0, stream>>>(T2, d_ln1w + i*CDIM, d_ln1b + i*CDIM, Xb, XH16, nullptr);
    hgemm_k<64,0,3,true,false,false,false,true><<<dim3(CDIM/128, M/64), 256, 0, stream>>>(
        XH16, d_cqkv_w + (long)i*3*CDIM*CDIM, d_cqkv_b + i*3*CDIM, nullptr, 0,
        nullptr, CDIM, M, CDIM, CDIM, CQh, nullptr, nullptr, nullptr);
    hgemm_k<128,0,3,true,false,false,false,true><<<dim3(2*CDIM/128, M/128), 256, 0, stream>>>(
        MEMBH16, d_cqkv_w + (long)i*3*CDIM*CDIM + (long)CDIM*CDIM,
        d_cqkv_b + i*3*CDIM + CDIM, nullptr, 0,
        nullptr, 2*CDIM, M, 2*CDIM, CDIM, KVh, nullptr, nullptr, nullptr);
    sattn_k<0><<<agrid, 256, 0, stream>>>(CQh, nullptr, CDIM,
        KVh, nullptr, 2*CDIM, KVh+CDIM, nullptr, 2*CDIM,
        AH16, nullptr, CDIM);
    hgemm_k<64,0,3,true,true,false,false,false><<<dim3(CDIM/128, M/64), 256, 0, stream>>>(
        AH16, d_co_w + (long)i*CDIM*CDIM, d_co_b + i*CDIM, Xb, CDIM,
        T2, CDIM, M, CDIM, CDIM, nullptr, nullptr, nullptr, nullptr);
    ln_k<2><<<M/4, 256, 0, stream>>>(T2, d_ln2w + i*CDIM, d_ln2b + i*CDIM, Xb, XH16, nullptr);
    hgemm_k<64,0,3,true,false,true,false,true><<<dim3(CDIM/128, M/64), 256, 0, stream>>>(
        XH16, d_f1w + (long)i*CDIM*CDIM, d_f1b + i*CDIM, nullptr, 0,
        nullptr, CDIM, M, CDIM, CDIM, FH16, nullptr, nullptr, nullptr);
    hgemm_k<64,0,3,true,true,false,false,false><<<dim3(CDIM/128, M/64), 256, 0, stream>>>(
        FH16, d_f2w + (long)i*CDIM*CDIM, d_f2b + i*CDIM, Xb, CDIM,
        T2, CDIM, M, CDIM, CDIM, nullptr, nullptr, nullptr, nullptr);
    ln_k<2><<<M/4, 256, 0, stream>>>(T2, d_ln3w + i*CDIM, d_ln3b + i*CDIM, Xb, XH16, nullptr);
  }
  tpose_k<<<tgrid, tblk, 0, stream>>>(Xb, o_quant);
}

// Round 15
// 2722.000 us; speedup vs baseline: 4.6053x; 1.1860x over previous
//
#include <hip/hip_runtime.h>
#include <math.h>

#define S_LEN 1024
#define NB 8
#define CDIM 512
#define KCB 4096
#define DH 64
#define NLAYER 6
#define NTOK (S_LEN*NB)
#define TOKC ((long)NTOK*CDIM)

typedef __attribute__((ext_vector_type(8))) _Float16 f16x8;
typedef __attribute__((ext_vector_type(4))) _Float16 f16x4;
typedef __attribute__((ext_vector_type(2))) _Float16 f16x2;
typedef __attribute__((ext_vector_type(4))) float f32x4;

// ---------------------------------------------------------------------------
// MFMA GEMM: C[M,N] = A[M,K] @ W[N,K]^T (+bias/res/relu).
// TM in {64,128}; N-tile 128. BK=64, mfma_f32_16x16x32_f16, XOR-swizzled LDS.
// SPLIT=1: hi/lo split-fp16, 3 MFMAs/pair (~fp32 accuracy).
// F16IN: 0 = A,W fp32 (convert in-kernel); 1 = A,W fp16; 2 = A,W split fp16
// hi/lo (Avl/Wvl, SPLIT=1); 3 = A fp16, W fp32-converted (SPLIT=0).
// E16: epilogue writes fp16 hi (Ch16) (+lo Cl16 if SPLIT); also fp32 C if C!=0.
// OREMAP: output row (s*NB+b) -> (b*S_LEN+s).
// NOTE: A and C must NOT alias (blocks of one dispatch race).
// ---------------------------------------------------------------------------
template<int TM, int SPLIT, int F16IN, bool BIAS, bool RES, bool RELU, bool OREMAP, bool E16>
__global__ __launch_bounds__(256)
void hgemm_k(const void* __restrict__ Av, const void* __restrict__ Wv,
             const float* __restrict__ bias, const float* __restrict__ Rsrc, int ldr,
             float* __restrict__ C, int ldc, int M, int N, int K,
             _Float16* __restrict__ Ch16, _Float16* __restrict__ Cl16,
             const void* __restrict__ Avl, const void* __restrict__ Wvl)
{
  constexpr int MI = TM / 32;
  constexpr int ATPR = 256 / TM;
  constexpr int ACOL = 64 / ATPR;
  constexpr bool AF16 = (F16IN >= 1);
  constexpr bool WF16 = (F16IN == 1 || F16IN == 2);
  __shared__ __align__(16) _Float16 Ah[TM*64];
  __shared__ __align__(16) _Float16 Bh[128*64];
  __shared__ __align__(16) _Float16 Al[SPLIT ? TM*64 : 8];
  __shared__ __align__(16) _Float16 Bl[SPLIT ? 128*64 : 8];
  const int t = threadIdx.x;
  const int m0 = blockIdx.y * TM, n0 = blockIdx.x * 128;

  const int arow = t / ATPR, apart = t % ATPR;
  const int brow = t >> 1, bpart = t & 1;

  const float*    Af  = (const float*)Av;
  const _Float16* Axh = (const _Float16*)Av;
  const _Float16* Axl = (const _Float16*)Avl;
  const float*    Wf  = (const float*)Wv;
  const _Float16* Wxh = (const _Float16*)Wv;
  const _Float16* Wxl = (const _Float16*)Wvl;
  const long aoff = (long)(m0 + arow) * K + apart * ACOL;
  const long boff = (long)(n0 + brow) * K + bpart * 32;

  const int lane = t & 63, wave = t >> 6;
  const int wm = wave >> 1, wn = wave & 1;
  const int lr = lane & 15, lk = lane >> 4;

  f32x4 acc[MI][4];
#pragma unroll
  for (int mi = 0; mi < MI; ++mi)
#pragma unroll
    for (int ni = 0; ni < 4; ++ni)
#pragma unroll
      for (int e = 0; e < 4; ++e) acc[mi][ni][e] = 0.f;

  float4 a4[ACOL/4], b4[8];
  f16x8  a16[ACOL/8], b16[4];
  f16x8  a16l[F16IN==2 ? ACOL/8 : 1], b16l[F16IN==2 ? 4 : 1];
  if (AF16) {
#pragma unroll
    for (int g = 0; g < ACOL/8; ++g) a16[g] = *(const f16x8*)(Axh + aoff + g*8);
    if (F16IN == 2) {
#pragma unroll
      for (int g = 0; g < ACOL/8; ++g) a16l[g] = *(const f16x8*)(Axl + aoff + g*8);
    }
  } else {
#pragma unroll
    for (int j = 0; j < ACOL/4; ++j) a4[j] = *(const float4*)(Af + aoff + j*4);
  }
  if (WF16) {
#pragma unroll
    for (int g = 0; g < 4; ++g) b16[g] = *(const f16x8*)(Wxh + boff + g*8);
    if (F16IN == 2) {
#pragma unroll
      for (int g = 0; g < 4; ++g) b16l[g] = *(const f16x8*)(Wxl + boff + g*8);
    }
  } else {
#pragma unroll
    for (int j = 0; j < 8; ++j) b4[j] = *(const float4*)(Wf + boff + j*4);
  }

  for (int k0 = 0; k0 < K; k0 += 64) {
    __syncthreads();
    if (AF16) {
#pragma unroll
      for (int g = 0; g < ACOL/8; ++g) {
        const int sw = (apart*ACOL*2 + g*16) ^ ((arow & 7) << 4);
        *(f16x8*)((char*)Ah + arow*128 + sw) = a16[g];
        if (F16IN == 2) *(f16x8*)((char*)Al + arow*128 + sw) = a16l[g];
      }
    } else {
      const float* af = (const float*)a4;
#pragma unroll
      for (int g = 0; g < ACOL/8; ++g) {
        f16x8 h, l;
#pragma unroll
        for (int j = 0; j < 8; ++j) {
          float xv = af[g*8+j];
          _Float16 hh = (_Float16)xv;
          h[j] = hh;
          if (SPLIT) l[j] = (_Float16)(xv - (float)hh);
        }
        const int sw = (apart*ACOL*2 + g*16) ^ ((arow & 7) << 4);
        *(f16x8*)((char*)Ah + arow*128 + sw) = h;
        if (SPLIT) *(f16x8*)((char*)Al + arow*128 + sw) = l;
      }
    }
    if (WF16) {
#pragma unroll
      for (int g = 0; g < 4; ++g) {
        const int sw = (bpart*64 + g*16) ^ ((brow & 7) << 4);
        *(f16x8*)((char*)Bh + brow*128 + sw) = b16[g];
        if (F16IN == 2) *(f16x8*)((char*)Bl + brow*128 + sw) = b16l[g];
      }
    } else {
      const float* bf = (const float*)b4;
#pragma unroll
      for (int g = 0; g < 4; ++g) {
        f16x8 h, l;
#pragma unroll
        for (int j = 0; j < 8; ++j) {
          float xv = bf[g*8+j];
          _Float16 hh = (_Float16)xv;
          h[j] = hh;
          if (SPLIT) l[j] = (_Float16)(xv - (float)hh);
        }
        const int sw = (bpart*64 + g*16) ^ ((brow & 7) << 4);
        *(f16x8*)((char*)Bh + brow*128 + sw) = h;
        if (SPLIT) *(f16x8*)((char*)Bl + brow*128 + sw) = l;
      }
    }
    __syncthreads();
    if (k0 + 64 < K) {
      if (AF16) {
#pragma unroll
        for (int g = 0; g < ACOL/8; ++g) a16[g] = *(const f16x8*)(Axh + aoff + k0 + 64 + g*8);
        if (F16IN == 2) {
#pragma unroll
          for (int g = 0; g < ACOL/8; ++g) a16l[g] = *(const f16x8*)(Axl + aoff + k0 + 64 + g*8);
        }
      } else {
#pragma unroll
        for (int j = 0; j < ACOL/4; ++j) a4[j] = *(const float4*)(Af + aoff + k0 + 64 + j*4);
      }
      if (WF16) {
#pragma unroll
        for (int g = 0; g < 4; ++g) b16[g] = *(const f16x8*)(Wxh + boff + k0 + 64 + g*8);
        if (F16IN == 2) {
#pragma unroll
          for (int g = 0; g < 4; ++g) b16l[g] = *(const f16x8*)(Wxl + boff + k0 + 64 + g*8);
        }
      } else {
#pragma unroll
        for (int j = 0; j < 8; ++j) b4[j] = *(const float4*)(Wf + boff + k0 + 64 + j*4);
      }
    }
#pragma unroll
    for (int kk = 0; kk < 2; ++kk) {
      f16x8 afh[MI], bfh[4], afl[MI], bfl[4];
#pragma unroll
      for (int mi = 0; mi < MI; ++mi) {
        const int r = wm*(TM/2) + mi*16 + lr;
        const int bo = (lk*16 + kk*64) ^ ((r & 7) << 4);
        afh[mi] = *(const f16x8*)((const char*)Ah + r*128 + bo);
        if (SPLIT) afl[mi] = *(const f16x8*)((const char*)Al + r*128 + bo);
      }
#pragma unroll
      for (int ni = 0; ni < 4; ++ni) {
        const int r = wn*64 + ni*16 + lr;
        const int bo = (lk*16 + kk*64) ^ ((r & 7) << 4);
        bfh[ni] = *(const f16x8*)((const char*)Bh + r*128 + bo);
        if (SPLIT) bfl[ni] = *(const f16x8*)((const char*)Bl + r*128 + bo);
      }
#pragma unroll
      for (int mi = 0; mi < MI; ++mi)
#pragma unroll
        for (int ni = 0; ni < 4; ++ni) {
          acc[mi][ni] = __builtin_amdgcn_mfma_f32_16x16x32_f16(afh[mi], bfh[ni], acc[mi][ni], 0, 0, 0);
          if (SPLIT) {
            acc[mi][ni] = __builtin_amdgcn_mfma_f32_16x16x32_f16(afh[mi], bfl[ni], acc[mi][ni], 0, 0, 0);
            acc[mi][ni] = __builtin_amdgcn_mfma_f32_16x16x32_f16(afl[mi], bfh[ni], acc[mi][ni], 0, 0, 0);
          }
        }
    }
  }

  float bvv[4];
  if (BIAS) {
#pragma unroll
    for (int ni = 0; ni < 4; ++ni) bvv[ni] = bias[n0 + wn*64 + ni*16 + lr];
  }
#pragma unroll
  for (int mi = 0; mi < MI; ++mi)
#pragma unroll
  for (int i = 0; i < 4; ++i) {
    const int rm = m0 + wm*(TM/2) + mi*16 + lk*4 + i;
    long orow = rm;
    if (OREMAP) orow = (long)(rm & (NB-1)) * S_LEN + (rm >> 3);
#pragma unroll
    for (int ni = 0; ni < 4; ++ni) {
      const int col = n0 + wn*64 + ni*16 + lr;
      float v = acc[mi][ni][i];
      if (BIAS) v += bvv[ni];
      if (RES)  v += Rsrc[(long)rm*ldr + col];
      if (RELU) v = fmaxf(v, 0.f);
      if (E16) {
        _Float16 hv = (_Float16)v;
        Ch16[(long)rm*ldc + col] = hv;
        if (SPLIT) Cl16[(long)rm*ldc + col] = (_Float16)(v - (float)hv);
        if (C != nullptr) C[orow*(long)ldc + col] = v;
      } else {
        C[orow*(long)ldc + col] = v;
      }
    }
  }
}

// ---------------------------------------------------------------------------
// Swapped-operand flash attention (validated, rounds 12-14).
// S^T = mfma(K,Q): lane owns q = qb*16+lr with 16 key-scores local; softmax is
// local ops + 2 shfl; P converts in-register to the B-fragment of
// mfma_f32_16x16x16_f16 -> NO P LDS round-trip. PV: O^T[d][q], A = V^T (b64
// LDS reads). SPLIT=1 (encoder): hi/lo split operands, 3 MFMAs/pair, split
// hi/lo output. SPLIT=0 (decoder): plain fp16, hi-only output.
// Grid: (bh, s0-tile) — same-KV blocks share an XCD.
// ---------------------------------------------------------------------------
template<int SPLIT>
__global__ __launch_bounds__(256)
void sattn_k(const _Float16* __restrict__ Qh, const _Float16* __restrict__ Ql, int ldq,
             const _Float16* __restrict__ Kh, const _Float16* __restrict__ Kl, int ldk,
             const _Float16* __restrict__ Vh, const _Float16* __restrict__ Vl, int ldv,
             _Float16* __restrict__ Oh, _Float16* __restrict__ Ol, int ldo)
{
  __shared__ __align__(16) char Kb[8192];
  __shared__ __align__(16) char Vb[8192];
  __shared__ __align__(16) char Klo[SPLIT ? 8192 : 16];
  __shared__ __align__(16) char Vlo[SPLIT ? 8192 : 16];

  const int t = threadIdx.x;
  const int b = blockIdx.x >> 3, hd = blockIdx.x & 7;
  const int s0 = blockIdx.y * 128;
  const int qoff = hd * DH;
  const int wave = t >> 6, lane = t & 63;
  const int lr = lane & 15, lk = lane >> 4;
  const int krow = t >> 2, kqd = t & 3;
  const int vtp = t & 31, vdc = t >> 5;

  f16x8 qa[2][2], qal[2][2];
#pragma unroll
  for (int qb = 0; qb < 2; ++qb)
#pragma unroll
    for (int kk = 0; kk < 2; ++kk) {
      const int q = s0 + wave*32 + qb*16 + lr;
      const long base = ((long)q*NB + b)*ldq + qoff + kk*32 + lk*8;
      f16x8 v = *(const f16x8*)(Qh + base);
#pragma unroll
      for (int e = 0; e < 8; ++e) v[e] = v[e] * (_Float16)0.125f;
      qa[qb][kk] = v;
      if (SPLIT) {
        f16x8 w = *(const f16x8*)(Ql + base);
#pragma unroll
        for (int e = 0; e < 8; ++e) w[e] = w[e] * (_Float16)0.125f;
        qal[qb][kk] = w;
      }
    }

  float m_run[2] = {-INFINITY, -INFINITY};
  float l_run[2] = {0.f, 0.f};
  f32x4 oaccT[4][2];
#pragma unroll
  for (int nd = 0; nd < 4; ++nd)
#pragma unroll
    for (int qb = 0; qb < 2; ++qb)
#pragma unroll
      for (int e = 0; e < 4; ++e) oaccT[nd][qb][e] = 0.f;

  f16x8 kr0, kr1, krl0, krl1, vr0, vr1, vrl0, vrl1;
  {
    const long kb = ((long)krow*NB + b)*ldk + qoff + kqd*16;
    kr0 = *(const f16x8*)(Kh + kb);
    kr1 = *(const f16x8*)(Kh + kb + 8);
    if (SPLIT) { krl0 = *(const f16x8*)(Kl + kb); krl1 = *(const f16x8*)(Kl + kb + 8); }
    const long vb = ((long)(2*vtp)*NB + b)*ldv + qoff + vdc*8;
    vr0 = *(const f16x8*)(Vh + vb);
    vr1 = *(const f16x8*)(Vh + vb + (long)NB*ldv);
    if (SPLIT) { vrl0 = *(const f16x8*)(Vl + vb); vrl1 = *(const f16x8*)(Vl + vb + (long)NB*ldv); }
  }

  for (int t0 = 0; t0 < S_LEN; t0 += 64) {
    __syncthreads();
    {
      const int sw0 = (kqd*32) ^ ((krow & 7) << 4);
      const int sw1 = (kqd*32 + 16) ^ ((krow & 7) << 4);
      *(f16x8*)(Kb + krow*128 + sw0) = kr0;
      *(f16x8*)(Kb + krow*128 + sw1) = kr1;
      if (SPLIT) {
        *(f16x8*)(Klo + krow*128 + sw0) = krl0;
        *(f16x8*)(Klo + krow*128 + sw1) = krl1;
      }
#pragma unroll
      for (int j = 0; j < 8; ++j) {
        const int dd = vdc*8 + j;
        const int off = dd*128 + ((vtp*4) ^ ((dd & 7) << 4));
        f16x2 hv = {vr0[j], vr1[j]};
        *(f16x2*)(Vb + off) = hv;
        if (SPLIT) {
          f16x2 lv = {vrl0[j], vrl1[j]};
          *(f16x2*)(Vlo + off) = lv;
        }
      }
    }
    if (t0 + 64 < S_LEN) {
      const long kb = ((long)(t0 + 64 + krow)*NB + b)*ldk + qoff + kqd*16;
      kr0 = *(const f16x8*)(Kh + kb);
      kr1 = *(const f16x8*)(Kh + kb + 8);
      if (SPLIT) { krl0 = *(const f16x8*)(Kl + kb); krl1 = *(const f16x8*)(Kl + kb + 8); }
      const long vb = ((long)(t0 + 64 + 2*vtp)*NB + b)*ldv + qoff + vdc*8;
      vr0 = *(const f16x8*)(Vh + vb);
      vr1 = *(const f16x8*)(Vh + vb + (long)NB*ldv);
      if (SPLIT) { vrl0 = *(const f16x8*)(Vl + vb); vrl1 = *(const f16x8*)(Vl + vb + (long)NB*ldv); }
    }
    __syncthreads();

    // ---- S^T[key][q] = mfma(K, Q) (+ split cross terms) ----
    f32x4 st[4][2];
#pragma unroll
    for (int ki = 0; ki < 4; ++ki)
#pragma unroll
      for (int qb = 0; qb < 2; ++qb)
#pragma unroll
        for (int e = 0; e < 4; ++e) st[ki][qb][e] = 0.f;
#pragma unroll
    for (int kk = 0; kk < 2; ++kk) {
      f16x8 kb[4], kbl[4];
#pragma unroll
      for (int ki = 0; ki < 4; ++ki) {
        const int r = ki*16 + lr;
        const int bo = (lk*16 + kk*64) ^ ((r & 7) << 4);
        kb[ki] = *(const f16x8*)(Kb + r*128 + bo);
        if (SPLIT) kbl[ki] = *(const f16x8*)(Klo + r*128 + bo);
      }
#pragma unroll
      for (int ki = 0; ki < 4; ++ki)
#pragma unroll
        for (int qb = 0; qb < 2; ++qb) {
          st[ki][qb] = __builtin_amdgcn_mfma_f32_16x16x32_f16(kb[ki], qa[qb][kk], st[ki][qb], 0, 0, 0);
          if (SPLIT) {
            st[ki][qb] = __builtin_amdgcn_mfma_f32_16x16x32_f16(kb[ki], qal[qb][kk], st[ki][qb], 0, 0, 0);
            st[ki][qb] = __builtin_amdgcn_mfma_f32_16x16x32_f16(kbl[ki], qa[qb][kk], st[ki][qb], 0, 0, 0);
          }
        }
    }

    // ---- online softmax: lane owns q = qb*16+lr; 16 keys local + 2 shfl ----
    f16x4 pbh[4][2], pbl[4][2];
#pragma unroll
    for (int qb = 0; qb < 2; ++qb) {
      float rm = st[0][qb][0];
#pragma unroll
      for (int ki = 0; ki < 4; ++ki)
#pragma unroll
        for (int e = 0; e < 4; ++e) rm = fmaxf(rm, st[ki][qb][e]);
      rm = fmaxf(rm, __shfl_xor(rm, 16));
      rm = fmaxf(rm, __shfl_xor(rm, 32));
      const float mnew = fmaxf(m_run[qb], rm);
      const float corr = __expf(m_run[qb] - mnew);
      m_run[qb] = mnew;
      float ls = 0.f;
#pragma unroll
      for (int ki = 0; ki < 4; ++ki) {
        f16x4 ph, pl;
#pragma unroll
        for (int e = 0; e < 4; ++e) {
          float p = __expf(st[ki][qb][e] - mnew);
          ls += p;
          _Float16 h = (_Float16)p;
          ph[e] = h;
          if (SPLIT) pl[e] = (_Float16)(p - (float)h);
        }
        pbh[ki][qb] = ph;
        if (SPLIT) pbl[ki][qb] = pl;
      }
      ls += __shfl_xor(ls, 16);
      ls += __shfl_xor(ls, 32);
      l_run[qb] = l_run[qb]*corr + ls;
#pragma unroll
      for (int nd = 0; nd < 4; ++nd)
#pragma unroll
        for (int e = 0; e < 4; ++e) oaccT[nd][qb][e] *= corr;
    }

    // ---- O^T[d][q] += mfma16(V^T, P^T) — P never touches LDS ----
#pragma unroll
    for (int ki = 0; ki < 4; ++ki) {
      f16x4 avh[4], avl[4];
#pragma unroll
      for (int nd = 0; nd < 4; ++nd) {
        const int row = nd*16 + lr;
        const int bo = (ki*32 + lk*8) ^ ((row & 7) << 4);
        avh[nd] = *(const f16x4*)(Vb + row*128 + bo);
        if (SPLIT) avl[nd] = *(const f16x4*)(Vlo + row*128 + bo);
      }
#pragma unroll
      for (int nd = 0; nd < 4; ++nd)
#pragma unroll
        for (int qb = 0; qb < 2; ++qb) {
          oaccT[nd][qb] = __builtin_amdgcn_mfma_f32_16x16x16f16(avh[nd], pbh[ki][qb], oaccT[nd][qb], 0, 0, 0);
          if (SPLIT) {
            oaccT[nd][qb] = __builtin_amdgcn_mfma_f32_16x16x16f16(avh[nd], pbl[ki][qb], oaccT[nd][qb], 0, 0, 0);
            oaccT[nd][qb] = __builtin_amdgcn_mfma_f32_16x16x16f16(avl[nd], pbh[ki][qb], oaccT[nd][qb], 0, 0, 0);
          }
        }
    }
  }

  // ---- epilogue: O[q][d], packed b64 stores; SPLIT also writes lo ----
#pragma unroll
  for (int qb = 0; qb < 2; ++qb) {
    const float inv = 1.0f / l_run[qb];
    const int q = s0 + wave*32 + qb*16 + lr;
    const long base = ((long)q * NB + b) * ldo + qoff;
#pragma unroll
    for (int nd = 0; nd < 4; ++nd) {
      f16x4 o, ol;
#pragma unroll
      for (int e = 0; e < 4; ++e) {
        float v = oaccT[nd][qb][e] * inv;
        _Float16 h = (_Float16)v;
        o[e] = h;
        if (SPLIT) ol[e] = (_Float16)(v - (float)h);
      }
      *(f16x4*)(Oh + base + nd*16 + lk*4) = o;
      if (SPLIT) *(f16x4*)(Ol + base + nd*16 + lk*4) = ol;
    }
  }
}

// ---------------------------------------------------------------------------
// LayerNorm over c=512, one wave per row.
// ES: 0 = fp32 only; 1 = fp32 + split fp16 hi/lo; 2 = fp32 + fp16 hi.
// ---------------------------------------------------------------------------
template<int ES>
__global__ __launch_bounds__(256)
void ln_k(const float* __restrict__ X, const float* __restrict__ g,
          const float* __restrict__ bb, float* __restrict__ Y,
          _Float16* __restrict__ Yh, _Float16* __restrict__ Yl)
{
  const int t = threadIdx.x;
  const int lane = t & 63;
  const long row = (long)blockIdx.x * 4 + (t >> 6);
  const float* xr = X + row * CDIM;
  float4 v0 = *(const float4*)(xr + lane*4);
  float4 v1 = *(const float4*)(xr + 256 + lane*4);
  float s = v0.x+v0.y+v0.z+v0.w + v1.x+v1.y+v1.z+v1.w;
#pragma unroll
  for (int off = 1; off < 64; off <<= 1) s += __shfl_xor(s, off);
  const float mean = s * (1.0f/512.0f);
  float d[8] = {v0.x-mean, v0.y-mean, v0.z-mean, v0.w-mean,
                v1.x-mean, v1.y-mean, v1.z-mean, v1.w-mean};
  float sq = d[0]*d[0]+d[1]*d[1]+d[2]*d[2]+d[3]*d[3]
           + d[4]*d[4]+d[5]*d[5]+d[6]*d[6]+d[7]*d[7];
#pragma unroll
  for (int off = 1; off < 64; off <<= 1) sq += __shfl_xor(sq, off);
  const float inv = 1.0f / sqrtf(sq * (1.0f/512.0f) + 1e-5f);
  float4 g0 = *(const float4*)(g + lane*4);
  float4 g1 = *(const float4*)(g + 256 + lane*4);
  float4 b0 = *(const float4*)(bb + lane*4);
  float4 b1 = *(const float4*)(bb + 256 + lane*4);
  float o[8];
  o[0] = d[0]*inv*g0.x + b0.x; o[1] = d[1]*inv*g0.y + b0.y;
  o[2] = d[2]*inv*g0.z + b0.z; o[3] = d[3]*inv*g0.w + b0.w;
  o[4] = d[4]*inv*g1.x + b1.x; o[5] = d[5]*inv*g1.y + b1.y;
  o[6] = d[6]*inv*g1.z + b1.z; o[7] = d[7]*inv*g1.w + b1.w;
  *(float4*)(Y + row*CDIM + lane*4) = *(float4*)&o[0];
  *(float4*)(Y + row*CDIM + 256 + lane*4) = *(float4*)&o[4];
  if (ES) {
    f16x4 h0, h1, l0, l1;
#pragma unroll
    for (int j = 0; j < 4; ++j) {
      _Float16 h = (_Float16)o[j];     h0[j] = h;
      _Float16 k = (_Float16)o[4+j];   h1[j] = k;
      if (ES == 1) { l0[j] = (_Float16)(o[j] - (float)h); l1[j] = (_Float16)(o[4+j] - (float)k); }
    }
    *(f16x4*)(Yh + row*CDIM + lane*4) = h0;
    *(f16x4*)(Yh + row*CDIM + 256 + lane*4) = h1;
    if (ES == 1) {
      *(f16x4*)(Yl + row*CDIM + lane*4) = l0;
      *(f16x4*)(Yl + row*CDIM + 256 + lane*4) = l1;
    }
  }
}

// ---------------------------------------------------------------------------
// Pack x (N,C,H,W) -> enc_flat (S,n,c); posisted fp32 + split fp16 hi/lo.
// ---------------------------------------------------------------------------
__global__ void pack_pe_k(const float* __restrict__ x, float* __restrict__ encf,
                          float* __restrict__ posd,
                          _Float16* __restrict__ posh, _Float16* __restrict__ posl)
{
  __shared__ float tl[32][33];
  const int b = blockIdx.z;
  const int s0 = blockIdx.x*32, c0 = blockIdx.y*32;
#pragma unroll
  for (int i = 0; i < 4; ++i) {
    int ci = threadIdx.y + i*8;
    tl[ci][threadIdx.x] = x[((long)b*CDIM + c0+ci)*S_LEN + s0 + threadIdx.x];
  }
  __syncthreads();
#pragma unroll
  for (int i = 0; i < 4; ++i) {
    int si = threadIdx.y + i*8;
    int s = s0 + si;
    int ch = c0 + threadIdx.x;
    float val = tl[threadIdx.x][si];
    long o = ((long)s*NB + b)*CDIM + ch;
    encf[o] = val;
    int pos = (ch < 256) ? (s & 31) : (s >> 5);
    int j = (ch & 255) >> 1;
    float dv = expf((float)(2*j) * (-9.210340371976184f / 256.0f));
    float ang = (float)pos * dv;
    float pe = (ch & 1) ? cosf(ang) : sinf(ang);
    float pv = val + pe;
    posd[o] = pv;
    _Float16 h = (_Float16)pv;
    posh[o] = h;
    posl[o] = (_Float16)(pv - (float)h);
  }
}

// (S,n,c) token-major -> (n,c,S) output layout
__global__ void tpose_k(const float* __restrict__ in, float* __restrict__ out)
{
  __shared__ float tl[32][33];
  const int b = blockIdx.z;
  const int s0 = blockIdx.x*32, c0 = blockIdx.y*32;
#pragma unroll
  for (int i = 0; i < 4; ++i) {
    int si = threadIdx.y + i*8;
    tl[si][threadIdx.x] = in[((long)(s0+si)*NB + b)*CDIM + c0 + threadIdx.x];
  }
  __syncthreads();
#pragma unroll
  for (int i = 0; i < 4; ++i) {
    int ci = threadIdx.y + i*8;
    out[((long)b*CDIM + c0+ci)*S_LEN + s0 + threadIdx.x] = tl[threadIdx.x][ci];
  }
}

// cb_w (c,K) -> transposed split-fp16 codebook [K][c] hi/lo
__global__ void cbt16_k(const float* __restrict__ cb,
                        _Float16* __restrict__ outh, _Float16* __restrict__ outl)
{
  __shared__ float tl[32][33];
  const int k0 = blockIdx.x*32, c0 = blockIdx.y*32;
#pragma unroll
  for (int i = 0; i < 4; ++i) {
    int ci = threadIdx.y + i*8;
    tl[ci][threadIdx.x] = cb[(long)(c0+ci)*KCB + k0 + threadIdx.x];
  }
  __syncthreads();
#pragma unroll
  for (int i = 0; i < 4; ++i) {
    int ki = threadIdx.y + i*8;
    float v = tl[threadIdx.x][ki];
    _Float16 h = (_Float16)v;
    outh[(long)(k0+ki)*CDIM + c0 + threadIdx.x] = h;
    outl[(long)(k0+ki)*CDIM + c0 + threadIdx.x] = (_Float16)(v - (float)h);
  }
}

// fp32 -> fp16 elementwise, 8 per thread
__global__ __launch_bounds__(256)
void conv16_k(const float* __restrict__ in, _Float16* __restrict__ out)
{
  const long i = ((long)blockIdx.x * 256 + threadIdx.x) * 8;
  float4 v0 = *(const float4*)(in + i);
  float4 v1 = *(const float4*)(in + i + 4);
  f16x8 h;
  h[0]=(_Float16)v0.x; h[1]=(_Float16)v0.y; h[2]=(_Float16)v0.z; h[3]=(_Float16)v0.w;
  h[4]=(_Float16)v1.x; h[5]=(_Float16)v1.y; h[6]=(_Float16)v1.z; h[7]=(_Float16)v1.w;
  *(f16x8*)(out + i) = h;
}

// fp32 -> split fp16 hi/lo, 8 per thread
__global__ __launch_bounds__(256)
void convsplit_k(const float* __restrict__ in, _Float16* __restrict__ oh,
                 _Float16* __restrict__ ol)
{
  const long i = ((long)blockIdx.x * 256 + threadIdx.x) * 8;
  float4 v0 = *(const float4*)(in + i);
  float4 v1 = *(const float4*)(in + i + 4);
  float vv[8] = {v0.x,v0.y,v0.z,v0.w,v1.x,v1.y,v1.z,v1.w};
  f16x8 h, l;
#pragma unroll
  for (int j = 0; j < 8; ++j) {
    _Float16 hh = (_Float16)vv[j];
    h[j] = hh;
    l[j] = (_Float16)(vv[j] - (float)hh);
  }
  *(f16x8*)(oh + i) = h;
  *(f16x8*)(ol + i) = l;
}

// Per-token row of logits: argmax (np first-occurrence) + write P (fp16)
__global__ __launch_bounds__(256)
void simstats_k(const float* __restrict__ logits, _Float16* __restrict__ Pbuf,
                int* __restrict__ codes_tok, float* __restrict__ codes_out)
{
  const long phys = blockIdx.x;
  const float* rowp = logits + phys * KCB;
  const int t = threadIdx.x;
  float vals[16];
#pragma unroll
  for (int rep = 0; rep < 4; ++rep) {
    float4 v = *(const float4*)(rowp + rep*1024 + t*4);
    vals[rep*4+0]=v.x; vals[rep*4+1]=v.y; vals[rep*4+2]=v.z; vals[rep*4+3]=v.w;
  }
  float mv = -INFINITY; int mi = 0;
#pragma unroll
  for (int rep = 0; rep < 4; ++rep)
#pragma unroll
    for (int j = 0; j < 4; ++j) {
      float xv = vals[rep*4+j];
      int ix = rep*1024 + t*4 + j;
      if (xv > mv) { mv = xv; mi = ix; }
    }
  const int lane = t & 63, wid = t >> 6;
#pragma unroll
  for (int off = 1; off < 64; off <<= 1) {
    float ov = __shfl_xor(mv, off);
    int   oi = __shfl_xor(mi, off);
    if (ov > mv || (ov == mv && oi < mi)) { mv = ov; mi = oi; }
  }
  __shared__ float smax[4]; __shared__ int sidx[4]; __shared__ float ssum[4];
  __shared__ float fm; __shared__ int fi; __shared__ float sinv;
  if (lane == 0) { smax[wid] = mv; sidx[wid] = mi; }
  __syncthreads();
  if (t == 0) {
    float bm = smax[0]; int bi = sidx[0];
    for (int wq = 1; wq < 4; ++wq)
      if (smax[wq] > bm || (smax[wq] == bm && sidx[wq] < bi)) { bm = smax[wq]; bi = sidx[wq]; }
    fm = bm; fi = bi;
  }
  __syncthreads();
  const float Mx = fm;
  float se = 0.f;
#pragma unroll
  for (int q = 0; q < 16; ++q) se += __expf(vals[q] - Mx);
#pragma unroll
  for (int off = 1; off < 64; off <<= 1) se += __shfl_xor(se, off);
  if (lane == 0) ssum[wid] = se;
  __syncthreads();
  const int b = (int)(phys >> 10), s = (int)(phys & 1023);
  if (t == 0) {
    float tot = ssum[0]+ssum[1]+ssum[2]+ssum[3];
    sinv = 1.0f / tot;
    codes_tok[s*NB + b] = fi;
    codes_out[phys] = (float)fi;
  }
  __syncthreads();
  const float inv = sinv;
  _Float16* prow = Pbuf + ((long)s*NB + b) * KCB;
#pragma unroll
  for (int rep = 0; rep < 4; ++rep) {
    f16x4 pv;
#pragma unroll
    for (int j = 0; j < 4; ++j) pv[j] = (_Float16)(__expf(vals[rep*4+j] - Mx) * inv);
    *(f16x4*)(prow + rep*1024 + t*4) = pv;
  }
}

// quant = (hard - soft) + soft; emit hard fp32 and quant fp32 + fp16-hi.
__global__ __launch_bounds__(128)
void quant_k(const float* __restrict__ soft, const int* __restrict__ codes_tok,
             const _Float16* __restrict__ cbh, const _Float16* __restrict__ cbl,
             float* __restrict__ quant, float* __restrict__ hardb,
             _Float16* __restrict__ qh16)
{
  const int r = blockIdx.x;
  const int code = codes_tok[r];
  const int c = threadIdx.x * 4;
  f16x4 hh = *(const f16x4*)(cbh + (long)code*CDIM + c);
  f16x4 hl = *(const f16x4*)(cbl + (long)code*CDIM + c);
  float4 sf = *(const float4*)(soft + (long)r*CDIM + c);
  float4 h, q;
  h.x = (float)hh[0] + (float)hl[0]; h.y = (float)hh[1] + (float)hl[1];
  h.z = (float)hh[2] + (float)hl[2]; h.w = (float)hh[3] + (float)hl[3];
  q.x = (h.x - sf.x) + sf.x; q.y = (h.y - sf.y) + sf.y;
  q.z = (h.z - sf.z) + sf.z; q.w = (h.w - sf.w) + sf.w;
  *(float4*)(quant + (long)r*CDIM + c) = q;
  *(float4*)(hardb + (long)r*CDIM + c) = h;
  f16x4 qh = {(_Float16)q.x, (_Float16)q.y, (_Float16)q.z, (_Float16)q.w};
  *(f16x4*)(qh16 + (long)r*CDIM + c) = qh;
}

// Detect the storage format of the bool mask buffer.
__global__ void maskdetect_k(const void* __restrict__ mask, int* __restrict__ flag)
{
  const unsigned int* wds = (const unsigned int*)mask;
  int t = threadIdx.x;
  int okI = 1, okF = 1, okL = 1;
  for (int i = t; i < 2048; i += 256) {
    unsigned int u = wds[i];
    if (u > 1u) okI = 0;
    if (u != 0u && u != 0x3F800000u) okF = 0;
    if ((i & 1) ? (u != 0u) : (u > 1u)) okL = 0;
  }
  __shared__ int sI, sF, sL;
  if (t == 0) { sI = 1; sF = 1; sL = 1; }
  __syncthreads();
  if (!okI) atomicAnd(&sI, 0);
  if (!okF) atomicAnd(&sF, 0);
  if (!okL) atomicAnd(&sL, 0);
  __syncthreads();
  if (t == 0) {
    int f;
    if (sI && sL) f = 3;
    else if (sI)  f = 1;
    else if (sF)  f = 2;
    else          f = 0;
    *flag = f;
  }
}

// mixed = mask ? enc_flat : post; fp32 + fp16-hi outputs
__global__ __launch_bounds__(256)
void mixed_k(const float* __restrict__ encf, const float* __restrict__ post,
             const void* __restrict__ mask, const int* __restrict__ flag,
             float* __restrict__ outx, _Float16* __restrict__ outh)
{
  long gid = (long)blockIdx.x * blockDim.x + threadIdx.x;
  int r = (int)(gid >> 7);
  int c = (int)(gid & 127) * 4;
  int f = *flag;
  bool mv;
  if (f == 0)      mv = ((const unsigned char*)mask)[r] != 0;
  else if (f == 1) mv = ((const int*)mask)[r] != 0;
  else if (f == 3) mv = ((const long long*)mask)[r] != 0;
  else             mv = ((const float*)mask)[r] != 0.0f;
  const float* src = mv ? encf : post;
  float4 v = *(const float4*)(src + (long)r*CDIM + c);
  *(float4*)(outx + (long)r*CDIM + c) = v;
  f16x4 h = {(_Float16)v.x, (_Float16)v.y, (_Float16)v.z, (_Float16)v.w};
  *(f16x4*)(outh + (long)r*CDIM + c) = h;
}

extern "C" void kernel_launch(void* const* d_in, const int* in_sizes, int n_in,
                              void* d_out, int out_size, void* d_ws, size_t ws_size,
                              hipStream_t stream)
{
  const float* x       = (const float*)d_in[0];
  const float* pre_w   = (const float*)d_in[1];
  const float* pre_b   = (const float*)d_in[2];
  const float* post_w  = (const float*)d_in[3];
  const float* post_b  = (const float*)d_in[4];
  const float* cb_w    = (const float*)d_in[5];
  const float* e_qkv_w = (const float*)d_in[6];
  const float* e_qkv_b = (const float*)d_in[7];
  const float* e_o_w   = (const float*)d_in[8];
  const float* e_o_b   = (const float*)d_in[9];
  const float* e_ln1_w = (const float*)d_in[10];
  const float* e_ln1_b = (const float*)d_in[11];
  const float* e_ln2_w = (const float*)d_in[12];
  const float* e_ln2_b = (const float*)d_in[13];
  const float* e_f1_w  = (const float*)d_in[14];
  const float* e_f1_b  = (const float*)d_in[15];
  const float* e_f2_w  = (const float*)d_in[16];
  const float* e_f2_b  = (const float*)d_in[17];
  const float* d_sqkv_w= (const float*)d_in[18];
  const float* d_sqkv_b= (const float*)d_in[19];
  const float* d_so_w  = (const float*)d_in[20];
  const float* d_so_b  = (const float*)d_in[21];
  const float* d_cqkv_w= (const float*)d_in[22];
  const float* d_cqkv_b= (const float*)d_in[23];
  const float* d_co_w  = (const float*)d_in[24];
  const float* d_co_b  = (const float*)d_in[25];
  const float* d_ln1w  = (const float*)d_in[26];
  const float* d_ln1b  = (const float*)d_in[27];
  const float* d_ln2w  = (const float*)d_in[28];
  const float* d_ln2b  = (const float*)d_in[29];
  const float* d_ln3w  = (const float*)d_in[30];
  const float* d_ln3b  = (const float*)d_in[31];
  const float* d_f1w   = (const float*)d_in[32];
  const float* d_f1b   = (const float*)d_in[33];
  const float* d_f2w   = (const float*)d_in[34];
  const float* d_f2b   = (const float*)d_in[35];
  const void*  mask    = d_in[36];

  float* out = (float*)d_out;
  float* o_quant  = out;
  float* o_high   = out + 4194304;
  float* o_softs  = out + 8388608;
  float* o_hards  = out + 12582912;
  float* o_codes  = out + 16777216;
  float* o_logits = out + 16785408;

  float* ws    = (float*)d_ws;
  float* ENC   = ws;
  float* Xb    = ws + TOKC;
  float* T1    = ws + 2*TOKC;
  float* T2    = ws + 3*TOKC;
  float* QKV   = ws + 4*TOKC;
  float* MEMB  = ws + 7*TOKC;
  float* CBREG = ws + 8*TOKC;
  int*   CODES = (int*)(CBREG + (long)KCB*CDIM);
  int*   FLAG  = CODES + NTOK;
  float* HARDB = QKV;
  float* QUANT = QKV + TOKC;
  _Float16* PBUF = (_Float16*)QKV;
  _Float16* CBH  = (_Float16*)T1;
  _Float16* QKVh = (_Float16*)QKV;
  _Float16* QKVl = QKVh + (long)NTOK*3*CDIM;
  _Float16* CQh  = (_Float16*)QKV;
  _Float16* KVh  = (_Float16*)(QKV + TOKC);
  _Float16* CBT16h = (_Float16*)CBREG;
  _Float16* CBT16l = CBT16h + (long)KCB*CDIM;
  _Float16* PREH = (_Float16*)T2;
  _Float16* PREL = PREH + TOKC;
  _Float16* AH16   = (_Float16*)ENC;
  _Float16* FH16   = AH16 + TOKC;
  _Float16* XH16   = ((_Float16*)QKV) + 4*TOKC;
  _Float16* MEMBH16= XH16 + TOKC;
  _Float16* QH16   = ((_Float16*)T1) + TOKC;

  const long WQSZ = (long)6*3*CDIM*CDIM;   // 4,718,592 elems
  const long WSSZ = (long)6*CDIM*CDIM;     // 1,572,864 elems
  _Float16* SCR  = (_Float16*)o_logits;
  _Float16* WQH = SCR;            _Float16* WQL = WQH + WQSZ;
  _Float16* WOH = WQL + WQSZ;     _Float16* WOL = WOH + WSSZ;
  _Float16* WF1H= WOL + WSSZ;     _Float16* WF1L= WF1H + WSSZ;
  _Float16* WF2H= WF1L + WSSZ;    _Float16* WF2L= WF2H + WSSZ;
  _Float16* WPH = WF2L + WSSZ;    _Float16* WPL = WPH + (long)CDIM*CDIM;
  _Float16* XH  = WPL + (long)CDIM*CDIM;  _Float16* XL  = XH + TOKC;
  _Float16* AH  = XL + TOKC;      _Float16* AL  = AH + TOKC;
  _Float16* L1H = AL + TOKC;      _Float16* L1L = L1H + TOKC;
  _Float16* H1H = L1L + TOKC;     _Float16* H1L = H1H + TOKC;

  // ---- decoder fp16 weights (converted once; regions dead by decoder time) --
  _Float16* DWSQ = (_Float16*)MEMB;          // 9 MiB of MEMB's 16 (dead after mixed_k)
  _Float16* DWCQ = (_Float16*)T1;            // 9 MiB of T1's 16 (dead after post GEMM)
  _Float16* DWF1 = DWCQ + WQSZ;              // T1 [9,12) MiB
  _Float16* DWF2 = DWF1 + WSSZ;              // T1 [12,15) MiB
  _Float16* DWSO = (_Float16*)CBREG;         // CBREG [0,3) MiB (dead after quant_k)
  _Float16* DWCO = DWSO + WSSZ;              // CBREG [3,6) MiB

  const size_t NEED = (size_t)(8*TOKC + (long)KCB*CDIM + 2*NTOK + NTOK + 16) * 4;
  if (ws_size < NEED) return;

  const int M = NTOK;
  dim3 tgrid(S_LEN/32, CDIM/32, NB), tblk(32, 8);
  dim3 agrid(NB*8, S_LEN/128);

  pack_pe_k<<<tgrid, tblk, 0, stream>>>(x, ENC, Xb, XH, XL);
  cbt16_k<<<dim3(KCB/32, CDIM/32), tblk, 0, stream>>>(cb_w, CBT16h, CBT16l);
  maskdetect_k<<<1, 256, 0, stream>>>(mask, FLAG);
  convsplit_k<<<(int)(WQSZ/2048), 256, 0, stream>>>(e_qkv_w, WQH, WQL);
  convsplit_k<<<(int)(WSSZ/2048), 256, 0, stream>>>(e_o_w,  WOH,  WOL);
  convsplit_k<<<(int)(WSSZ/2048), 256, 0, stream>>>(e_f1_w, WF1H, WF1L);
  convsplit_k<<<(int)(WSSZ/2048), 256, 0, stream>>>(e_f2_w, WF2H, WF2L);
  convsplit_k<<<(int)(((long)CDIM*CDIM)/2048), 256, 0, stream>>>(pre_w, WPH, WPL);

  // -------- encoder (split-fp16 MFMA, swapped-operand attention) --------
  for (int i = 0; i < NLAYER; ++i) {
    hgemm_k<128,1,2,true,false,false,false,true><<<dim3(3*CDIM/128, M/128), 256, 0, stream>>>(
        XH, WQH + (long)i*3*CDIM*CDIM, e_qkv_b + i*3*CDIM, nullptr, 0,
        nullptr, 3*CDIM, M, 3*CDIM, CDIM, QKVh, QKVl, XL, WQL + (long)i*3*CDIM*CDIM);
    sattn_k<1><<<agrid, 256, 0, stream>>>(QKVh, QKVl, 3*CDIM,
        QKVh+CDIM, QKVl+CDIM, 3*CDIM, QKVh+2*CDIM, QKVl+2*CDIM, 3*CDIM,
        AH, AL, CDIM);
    hgemm_k<64,1,2,true,true,false,false,false><<<dim3(CDIM/128, M/64), 256, 0, stream>>>(
        AH, WOH + (long)i*CDIM*CDIM, e_o_b + i*CDIM, Xb, CDIM,
        T2, CDIM, M, CDIM, CDIM, nullptr, nullptr, AL, WOL + (long)i*CDIM*CDIM);
    ln_k<1><<<M/4, 256, 0, stream>>>(T2, e_ln1_w + i*CDIM, e_ln1_b + i*CDIM, T1, L1H, L1L);
    hgemm_k<64,1,2,true,false,true,false,true><<<dim3(CDIM/128, M/64), 256, 0, stream>>>(
        L1H, WF1H + (long)i*CDIM*CDIM, e_f1_b + i*CDIM, nullptr, 0,
        nullptr, CDIM, M, CDIM, CDIM, H1H, H1L, L1L, WF1L + (long)i*CDIM*CDIM);
    hgemm_k<64,1,2,true,true,false,false,false><<<dim3(CDIM/128, M/64), 256, 0, stream>>>(
        H1H, WF2H + (long)i*CDIM*CDIM, e_f2_b + i*CDIM, T1, CDIM,
        T2, CDIM, M, CDIM, CDIM, nullptr, nullptr, H1L, WF2L + (long)i*CDIM*CDIM);
    ln_k<1><<<M/4, 256, 0, stream>>>(T2, e_ln2_w + i*CDIM, e_ln2_b + i*CDIM, Xb, XH, XL);
  }

  // -------- codebook / quantizer --------
  hgemm_k<64,1,2,true,false,false,false,true><<<dim3(CDIM/128, M/64), 256, 0, stream>>>(
      XH, WPH, pre_b, nullptr, 0, T1, CDIM, M, CDIM, CDIM, PREH, PREL, XL, WPL);
  tpose_k<<<tgrid, tblk, 0, stream>>>(T1, o_high);
  hgemm_k<128,1,2,false,false,false,true,false><<<dim3(KCB/128, M/128), 256, 0, stream>>>(
      PREH, CBT16h, nullptr, nullptr, 0, o_logits, KCB, M, KCB, CDIM,
      nullptr, nullptr, PREL, CBT16l);
  conv16_k<<<(CDIM*(long)KCB)/(256*8), 256, 0, stream>>>(cb_w, CBH);
  simstats_k<<<NTOK, 256, 0, stream>>>(o_logits, PBUF, CODES, o_codes);
  hgemm_k<64,0,1,false,false,false,false,false><<<dim3(CDIM/128, M/64), 256, 0, stream>>>(
      PBUF, CBH, nullptr, nullptr, 0, T2, CDIM, M, CDIM, KCB,
      nullptr, nullptr, nullptr, nullptr);                                   // soft
  tpose_k<<<tgrid, tblk, 0, stream>>>(T2, o_softs);
  quant_k<<<NTOK, 128, 0, stream>>>(T2, CODES, CBT16h, CBT16l, QUANT, HARDB, QH16);
  tpose_k<<<tgrid, tblk, 0, stream>>>(HARDB, o_hards);
  // CBREG dead from here: convert decoder so/co weights into it
  conv16_k<<<(int)(WSSZ/2048), 256, 0, stream>>>(d_so_w, DWSO);
  conv16_k<<<(int)(WSSZ/2048), 256, 0, stream>>>(d_co_w, DWCO);
  // post GEMM: fp32 MEMB + fp16 MEMBH16 in one pass (E16 fused)
  hgemm_k<64,0,3,true,false,false,false,true><<<dim3(CDIM/128, M/64), 256, 0, stream>>>(
      QH16, post_w, post_b, nullptr, 0, MEMB, CDIM, M, CDIM, CDIM,
      MEMBH16, nullptr, nullptr, nullptr);
  // T1 fully dead from here (CBH after soft, QH16 after post): cqkv/f1/f2
  conv16_k<<<(int)(WQSZ/2048), 256, 0, stream>>>(d_cqkv_w, DWCQ);
  conv16_k<<<(int)(WSSZ/2048), 256, 0, stream>>>(d_f1w, DWF1);
  conv16_k<<<(int)(WSSZ/2048), 256, 0, stream>>>(d_f2w, DWF2);
  mixed_k<<<4096, 256, 0, stream>>>(ENC, MEMB, mask, FLAG, Xb, XH16);
  // MEMB fp32 dead from here: sqkv weights
  conv16_k<<<(int)(WQSZ/2048), 256, 0, stream>>>(d_sqkv_w, DWSQ);

  // -------- decoder (f16 MFMA, producer-converted weights + activations) ----
  for (int i = 0; i < NLAYER; ++i) {
    hgemm_k<128,0,1,true,false,false,false,true><<<dim3(3*CDIM/128, M/128), 256, 0, stream>>>(
        XH16, DWSQ + (long)i*3*CDIM*CDIM, d_sqkv_b + i*3*CDIM, nullptr, 0,
        nullptr, 3*CDIM, M, 3*CDIM, CDIM, QKVh, nullptr, nullptr, nullptr);
    sattn_k<0><<<agrid, 256, 0, stream>>>(QKVh, nullptr, 3*CDIM,
        QKVh+CDIM, nullptr, 3*CDIM, QKVh+2*CDIM, nullptr, 3*CDIM,
        AH16, nullptr, CDIM);
    hgemm_k<64,0,1,true,true,false,false,false><<<dim3(CDIM/128, M/64), 256, 0, stream>>>(
        AH16, DWSO + (long)i*CDIM*CDIM, d_so_b + i*CDIM, Xb, CDIM,
        T2, CDIM, M, CDIM, CDIM, nullptr, nullptr, nullptr, nullptr);
    ln_k<2><<<M/4, 256, 0, stream>>>(T2, d_ln1w + i*CDIM, d_ln1b + i*CDIM, Xb, XH16, nullptr);
    hgemm_k<64,0,1,true,false,false,false,true><<<dim3(CDIM/128, M/64), 256, 0, stream>>>(
        XH16, DWCQ + (long)i*3*CDIM*CDIM, d_cqkv_b + i*3*CDIM, nullptr, 0,
        nullptr, CDIM, M, CDIM, CDIM, CQh, nullptr, nullptr, nullptr);
    hgemm_k<128,0,1,true,false,false,false,true><<<dim3(2*CDIM/128, M/128), 256, 0, stream>>>(
        MEMBH16, DWCQ + (long)i*3*CDIM*CDIM + (long)CDIM*CDIM,
        d_cqkv_b + i*3*CDIM + CDIM, nullptr, 0,
        nullptr, 2*CDIM, M, 2*CDIM, CDIM, KVh, nullptr, nullptr, nullptr);
    sattn_k<0><<<agrid, 256, 0, stream>>>(CQh, nullptr, CDIM,
        KVh, nullptr, 2*CDIM, KVh+CDIM, nullptr, 2*CDIM,
        AH16, nullptr, CDIM);
    hgemm_k<64,0,1,true,true,false,false,false><<<dim3(CDIM/128, M/64), 256, 0, stream>>>(
        AH16, DWCO + (long)i*CDIM*CDIM, d_co_b + i*CDIM, Xb, CDIM,
        T2, CDIM, M, CDIM, CDIM, nullptr, nullptr, nullptr, nullptr);
    ln_k<2><<<M/4, 256, 0, stream>>>(T2, d_ln2w + i*CDIM, d_ln2b + i*CDIM, Xb, XH16, nullptr);
    hgemm_k<64,0,1,true,false,true,false,true><<<dim3(CDIM/128, M/64), 256, 0, stream>>>(
        XH16, DWF1 + (long)i*CDIM*CDIM, d_f1b + i*CDIM, nullptr, 0,
        nullptr, CDIM, M, CDIM, CDIM, FH16, nullptr, nullptr, nullptr);
    hgemm_k<64,0,1,true,true,false,false,false><<<dim3(CDIM/128, M/64), 256, 0, stream>>>(
        FH16, DWF2 + (long)i*CDIM*CDIM, d_f2b + i*CDIM, Xb, CDIM,
        T2, CDIM, M, CDIM, CDIM, nullptr, nullptr, nullptr, nullptr);
    ln_k<2><<<M/4, 256, 0, stream>>>(T2, d_ln3w + i*CDIM, d_ln3b + i*CDIM, Xb, XH16, nullptr);
  }
  tpose_k<<<tgrid, tblk, 0, stream>>>(Xb, o_quant);
}

// Round 16
// 2704.356 us; speedup vs baseline: 4.6354x; 1.0065x over previous
//
#include <hip/hip_runtime.h>
#include <math.h>

#define S_LEN 1024
#define NB 8
#define CDIM 512
#define KCB 4096
#define DH 64
#define NLAYER 6
#define NTOK (S_LEN*NB)
#define TOKC ((long)NTOK*CDIM)

typedef __attribute__((ext_vector_type(8))) _Float16 f16x8;
typedef __attribute__((ext_vector_type(4))) _Float16 f16x4;
typedef __attribute__((ext_vector_type(2))) _Float16 f16x2;
typedef __attribute__((ext_vector_type(4))) float f32x4;

// ---------------------------------------------------------------------------
// MFMA GEMM: C[M,N] = A[M,K] @ W[N,K]^T (+bias/res/relu).
// TM in {64,128}; N-tile 128. BK=64, mfma_f32_16x16x32_f16, XOR-swizzled LDS.
// SPLIT=1: hi/lo split-fp16, 3 MFMAs/pair (~fp32 accuracy).
// F16IN: 0 = A,W fp32 (convert in-kernel); 1 = A,W fp16; 2 = A,W split fp16
// hi/lo (Avl/Wvl, SPLIT=1); 3 = A fp16, W fp32-converted (SPLIT=0).
// E16: epilogue writes fp16 hi (Ch16) (+lo Cl16 if SPLIT); also fp32 C if C!=0.
// OREMAP: output row (s*NB+b) -> (b*S_LEN+s).
// NOTE: A and C must NOT alias (blocks of one dispatch race).
// ---------------------------------------------------------------------------
template<int TM, int SPLIT, int F16IN, bool BIAS, bool RES, bool RELU, bool OREMAP, bool E16>
__global__ __launch_bounds__(256)
void hgemm_k(const void* __restrict__ Av, const void* __restrict__ Wv,
             const float* __restrict__ bias, const float* __restrict__ Rsrc, int ldr,
             float* __restrict__ C, int ldc, int M, int N, int K,
             _Float16* __restrict__ Ch16, _Float16* __restrict__ Cl16,
             const void* __restrict__ Avl, const void* __restrict__ Wvl)
{
  constexpr int MI = TM / 32;
  constexpr int ATPR = 256 / TM;
  constexpr int ACOL = 64 / ATPR;
  constexpr bool AF16 = (F16IN >= 1);
  constexpr bool WF16 = (F16IN == 1 || F16IN == 2);
  __shared__ __align__(16) _Float16 Ah[TM*64];
  __shared__ __align__(16) _Float16 Bh[128*64];
  __shared__ __align__(16) _Float16 Al[SPLIT ? TM*64 : 8];
  __shared__ __align__(16) _Float16 Bl[SPLIT ? 128*64 : 8];
  const int t = threadIdx.x;
  const int m0 = blockIdx.y * TM, n0 = blockIdx.x * 128;

  const int arow = t / ATPR, apart = t % ATPR;
  const int brow = t >> 1, bpart = t & 1;

  const float*    Af  = (const float*)Av;
  const _Float16* Axh = (const _Float16*)Av;
  const _Float16* Axl = (const _Float16*)Avl;
  const float*    Wf  = (const float*)Wv;
  const _Float16* Wxh = (const _Float16*)Wv;
  const _Float16* Wxl = (const _Float16*)Wvl;
  const long aoff = (long)(m0 + arow) * K + apart * ACOL;
  const long boff = (long)(n0 + brow) * K + bpart * 32;

  const int lane = t & 63, wave = t >> 6;
  const int wm = wave >> 1, wn = wave & 1;
  const int lr = lane & 15, lk = lane >> 4;

  f32x4 acc[MI][4];
#pragma unroll
  for (int mi = 0; mi < MI; ++mi)
#pragma unroll
    for (int ni = 0; ni < 4; ++ni)
#pragma unroll
      for (int e = 0; e < 4; ++e) acc[mi][ni][e] = 0.f;

  float4 a4[ACOL/4], b4[8];
  f16x8  a16[ACOL/8], b16[4];
  f16x8  a16l[F16IN==2 ? ACOL/8 : 1], b16l[F16IN==2 ? 4 : 1];
  if (AF16) {
#pragma unroll
    for (int g = 0; g < ACOL/8; ++g) a16[g] = *(const f16x8*)(Axh + aoff + g*8);
    if (F16IN == 2) {
#pragma unroll
      for (int g = 0; g < ACOL/8; ++g) a16l[g] = *(const f16x8*)(Axl + aoff + g*8);
    }
  } else {
#pragma unroll
    for (int j = 0; j < ACOL/4; ++j) a4[j] = *(const float4*)(Af + aoff + j*4);
  }
  if (WF16) {
#pragma unroll
    for (int g = 0; g < 4; ++g) b16[g] = *(const f16x8*)(Wxh + boff + g*8);
    if (F16IN == 2) {
#pragma unroll
      for (int g = 0; g < 4; ++g) b16l[g] = *(const f16x8*)(Wxl + boff + g*8);
    }
  } else {
#pragma unroll
    for (int j = 0; j < 8; ++j) b4[j] = *(const float4*)(Wf + boff + j*4);
  }

  for (int k0 = 0; k0 < K; k0 += 64) {
    __syncthreads();
    if (AF16) {
#pragma unroll
      for (int g = 0; g < ACOL/8; ++g) {
        const int sw = (apart*ACOL*2 + g*16) ^ ((arow & 7) << 4);
        *(f16x8*)((char*)Ah + arow*128 + sw) = a16[g];
        if (F16IN == 2) *(f16x8*)((char*)Al + arow*128 + sw) = a16l[g];
      }
    } else {
      const float* af = (const float*)a4;
#pragma unroll
      for (int g = 0; g < ACOL/8; ++g) {
        f16x8 h, l;
#pragma unroll
        for (int j = 0; j < 8; ++j) {
          float xv = af[g*8+j];
          _Float16 hh = (_Float16)xv;
          h[j] = hh;
          if (SPLIT) l[j] = (_Float16)(xv - (float)hh);
        }
        const int sw = (apart*ACOL*2 + g*16) ^ ((arow & 7) << 4);
        *(f16x8*)((char*)Ah + arow*128 + sw) = h;
        if (SPLIT) *(f16x8*)((char*)Al + arow*128 + sw) = l;
      }
    }
    if (WF16) {
#pragma unroll
      for (int g = 0; g < 4; ++g) {
        const int sw = (bpart*64 + g*16) ^ ((brow & 7) << 4);
        *(f16x8*)((char*)Bh + brow*128 + sw) = b16[g];
        if (F16IN == 2) *(f16x8*)((char*)Bl + brow*128 + sw) = b16l[g];
      }
    } else {
      const float* bf = (const float*)b4;
#pragma unroll
      for (int g = 0; g < 4; ++g) {
        f16x8 h, l;
#pragma unroll
        for (int j = 0; j < 8; ++j) {
          float xv = bf[g*8+j];
          _Float16 hh = (_Float16)xv;
          h[j] = hh;
          if (SPLIT) l[j] = (_Float16)(xv - (float)hh);
        }
        const int sw = (bpart*64 + g*16) ^ ((brow & 7) << 4);
        *(f16x8*)((char*)Bh + brow*128 + sw) = h;
        if (SPLIT) *(f16x8*)((char*)Bl + brow*128 + sw) = l;
      }
    }
    __syncthreads();
    if (k0 + 64 < K) {
      if (AF16) {
#pragma unroll
        for (int g = 0; g < ACOL/8; ++g) a16[g] = *(const f16x8*)(Axh + aoff + k0 + 64 + g*8);
        if (F16IN == 2) {
#pragma unroll
          for (int g = 0; g < ACOL/8; ++g) a16l[g] = *(const f16x8*)(Axl + aoff + k0 + 64 + g*8);
        }
      } else {
#pragma unroll
        for (int j = 0; j < ACOL/4; ++j) a4[j] = *(const float4*)(Af + aoff + k0 + 64 + j*4);
      }
      if (WF16) {
#pragma unroll
        for (int g = 0; g < 4; ++g) b16[g] = *(const f16x8*)(Wxh + boff + k0 + 64 + g*8);
        if (F16IN == 2) {
#pragma unroll
          for (int g = 0; g < 4; ++g) b16l[g] = *(const f16x8*)(Wxl + boff + k0 + 64 + g*8);
        }
      } else {
#pragma unroll
        for (int j = 0; j < 8; ++j) b4[j] = *(const float4*)(Wf + boff + k0 + 64 + j*4);
      }
    }
#pragma unroll
    for (int kk = 0; kk < 2; ++kk) {
      f16x8 afh[MI], bfh[4], afl[MI], bfl[4];
#pragma unroll
      for (int mi = 0; mi < MI; ++mi) {
        const int r = wm*(TM/2) + mi*16 + lr;
        const int bo = (lk*16 + kk*64) ^ ((r & 7) << 4);
        afh[mi] = *(const f16x8*)((const char*)Ah + r*128 + bo);
        if (SPLIT) afl[mi] = *(const f16x8*)((const char*)Al + r*128 + bo);
      }
#pragma unroll
      for (int ni = 0; ni < 4; ++ni) {
        const int r = wn*64 + ni*16 + lr;
        const int bo = (lk*16 + kk*64) ^ ((r & 7) << 4);
        bfh[ni] = *(const f16x8*)((const char*)Bh + r*128 + bo);
        if (SPLIT) bfl[ni] = *(const f16x8*)((const char*)Bl + r*128 + bo);
      }
#pragma unroll
      for (int mi = 0; mi < MI; ++mi)
#pragma unroll
        for (int ni = 0; ni < 4; ++ni) {
          acc[mi][ni] = __builtin_amdgcn_mfma_f32_16x16x32_f16(afh[mi], bfh[ni], acc[mi][ni], 0, 0, 0);
          if (SPLIT) {
            acc[mi][ni] = __builtin_amdgcn_mfma_f32_16x16x32_f16(afh[mi], bfl[ni], acc[mi][ni], 0, 0, 0);
            acc[mi][ni] = __builtin_amdgcn_mfma_f32_16x16x32_f16(afl[mi], bfh[ni], acc[mi][ni], 0, 0, 0);
          }
        }
    }
  }

  float bvv[4];
  if (BIAS) {
#pragma unroll
    for (int ni = 0; ni < 4; ++ni) bvv[ni] = bias[n0 + wn*64 + ni*16 + lr];
  }
#pragma unroll
  for (int mi = 0; mi < MI; ++mi)
#pragma unroll
  for (int i = 0; i < 4; ++i) {
    const int rm = m0 + wm*(TM/2) + mi*16 + lk*4 + i;
    long orow = rm;
    if (OREMAP) orow = (long)(rm & (NB-1)) * S_LEN + (rm >> 3);
#pragma unroll
    for (int ni = 0; ni < 4; ++ni) {
      const int col = n0 + wn*64 + ni*16 + lr;
      float v = acc[mi][ni][i];
      if (BIAS) v += bvv[ni];
      if (RES)  v += Rsrc[(long)rm*ldr + col];
      if (RELU) v = fmaxf(v, 0.f);
      if (E16) {
        _Float16 hv = (_Float16)v;
        Ch16[(long)rm*ldc + col] = hv;
        if (SPLIT) Cl16[(long)rm*ldc + col] = (_Float16)(v - (float)hv);
        if (C != nullptr) C[orow*(long)ldc + col] = v;
      } else {
        C[orow*(long)ldc + col] = v;
      }
    }
  }
}

// ---------------------------------------------------------------------------
// Swapped-operand flash attention, KV tile 64 (validated r12-14). ENCODER.
// SPLIT=1: hi/lo split operands, 3 MFMAs/pair, split hi/lo output.
// ---------------------------------------------------------------------------
template<int SPLIT>
__global__ __launch_bounds__(256)
void sattn_k(const _Float16* __restrict__ Qh, const _Float16* __restrict__ Ql, int ldq,
             const _Float16* __restrict__ Kh, const _Float16* __restrict__ Kl, int ldk,
             const _Float16* __restrict__ Vh, const _Float16* __restrict__ Vl, int ldv,
             _Float16* __restrict__ Oh, _Float16* __restrict__ Ol, int ldo)
{
  __shared__ __align__(16) char Kb[8192];
  __shared__ __align__(16) char Vb[8192];
  __shared__ __align__(16) char Klo[SPLIT ? 8192 : 16];
  __shared__ __align__(16) char Vlo[SPLIT ? 8192 : 16];

  const int t = threadIdx.x;
  const int b = blockIdx.x >> 3, hd = blockIdx.x & 7;
  const int s0 = blockIdx.y * 128;
  const int qoff = hd * DH;
  const int wave = t >> 6, lane = t & 63;
  const int lr = lane & 15, lk = lane >> 4;
  const int krow = t >> 2, kqd = t & 3;
  const int vtp = t & 31, vdc = t >> 5;

  f16x8 qa[2][2], qal[2][2];
#pragma unroll
  for (int qb = 0; qb < 2; ++qb)
#pragma unroll
    for (int kk = 0; kk < 2; ++kk) {
      const int q = s0 + wave*32 + qb*16 + lr;
      const long base = ((long)q*NB + b)*ldq + qoff + kk*32 + lk*8;
      f16x8 v = *(const f16x8*)(Qh + base);
#pragma unroll
      for (int e = 0; e < 8; ++e) v[e] = v[e] * (_Float16)0.125f;
      qa[qb][kk] = v;
      if (SPLIT) {
        f16x8 w = *(const f16x8*)(Ql + base);
#pragma unroll
        for (int e = 0; e < 8; ++e) w[e] = w[e] * (_Float16)0.125f;
        qal[qb][kk] = w;
      }
    }

  float m_run[2] = {-INFINITY, -INFINITY};
  float l_run[2] = {0.f, 0.f};
  f32x4 oaccT[4][2];
#pragma unroll
  for (int nd = 0; nd < 4; ++nd)
#pragma unroll
    for (int qb = 0; qb < 2; ++qb)
#pragma unroll
      for (int e = 0; e < 4; ++e) oaccT[nd][qb][e] = 0.f;

  f16x8 kr0, kr1, krl0, krl1, vr0, vr1, vrl0, vrl1;
  {
    const long kb = ((long)krow*NB + b)*ldk + qoff + kqd*16;
    kr0 = *(const f16x8*)(Kh + kb);
    kr1 = *(const f16x8*)(Kh + kb + 8);
    if (SPLIT) { krl0 = *(const f16x8*)(Kl + kb); krl1 = *(const f16x8*)(Kl + kb + 8); }
    const long vb = ((long)(2*vtp)*NB + b)*ldv + qoff + vdc*8;
    vr0 = *(const f16x8*)(Vh + vb);
    vr1 = *(const f16x8*)(Vh + vb + (long)NB*ldv);
    if (SPLIT) { vrl0 = *(const f16x8*)(Vl + vb); vrl1 = *(const f16x8*)(Vl + vb + (long)NB*ldv); }
  }

  for (int t0 = 0; t0 < S_LEN; t0 += 64) {
    __syncthreads();
    {
      const int sw0 = (kqd*32) ^ ((krow & 7) << 4);
      const int sw1 = (kqd*32 + 16) ^ ((krow & 7) << 4);
      *(f16x8*)(Kb + krow*128 + sw0) = kr0;
      *(f16x8*)(Kb + krow*128 + sw1) = kr1;
      if (SPLIT) {
        *(f16x8*)(Klo + krow*128 + sw0) = krl0;
        *(f16x8*)(Klo + krow*128 + sw1) = krl1;
      }
#pragma unroll
      for (int j = 0; j < 8; ++j) {
        const int dd = vdc*8 + j;
        const int off = dd*128 + ((vtp*4) ^ ((dd & 7) << 4));
        f16x2 hv = {vr0[j], vr1[j]};
        *(f16x2*)(Vb + off) = hv;
        if (SPLIT) {
          f16x2 lv = {vrl0[j], vrl1[j]};
          *(f16x2*)(Vlo + off) = lv;
        }
      }
    }
    if (t0 + 64 < S_LEN) {
      const long kb = ((long)(t0 + 64 + krow)*NB + b)*ldk + qoff + kqd*16;
      kr0 = *(const f16x8*)(Kh + kb);
      kr1 = *(const f16x8*)(Kh + kb + 8);
      if (SPLIT) { krl0 = *(const f16x8*)(Kl + kb); krl1 = *(const f16x8*)(Kl + kb + 8); }
      const long vb = ((long)(t0 + 64 + 2*vtp)*NB + b)*ldv + qoff + vdc*8;
      vr0 = *(const f16x8*)(Vh + vb);
      vr1 = *(const f16x8*)(Vh + vb + (long)NB*ldv);
      if (SPLIT) { vrl0 = *(const f16x8*)(Vl + vb); vrl1 = *(const f16x8*)(Vl + vb + (long)NB*ldv); }
    }
    __syncthreads();

    f32x4 st[4][2];
#pragma unroll
    for (int ki = 0; ki < 4; ++ki)
#pragma unroll
      for (int qb = 0; qb < 2; ++qb)
#pragma unroll
        for (int e = 0; e < 4; ++e) st[ki][qb][e] = 0.f;
#pragma unroll
    for (int kk = 0; kk < 2; ++kk) {
      f16x8 kb[4], kbl[4];
#pragma unroll
      for (int ki = 0; ki < 4; ++ki) {
        const int r = ki*16 + lr;
        const int bo = (lk*16 + kk*64) ^ ((r & 7) << 4);
        kb[ki] = *(const f16x8*)(Kb + r*128 + bo);
        if (SPLIT) kbl[ki] = *(const f16x8*)(Klo + r*128 + bo);
      }
#pragma unroll
      for (int ki = 0; ki < 4; ++ki)
#pragma unroll
        for (int qb = 0; qb < 2; ++qb) {
          st[ki][qb] = __builtin_amdgcn_mfma_f32_16x16x32_f16(kb[ki], qa[qb][kk], st[ki][qb], 0, 0, 0);
          if (SPLIT) {
            st[ki][qb] = __builtin_amdgcn_mfma_f32_16x16x32_f16(kb[ki], qal[qb][kk], st[ki][qb], 0, 0, 0);
            st[ki][qb] = __builtin_amdgcn_mfma_f32_16x16x32_f16(kbl[ki], qa[qb][kk], st[ki][qb], 0, 0, 0);
          }
        }
    }

    f16x4 pbh[4][2], pbl[4][2];
#pragma unroll
    for (int qb = 0; qb < 2; ++qb) {
      float rm = st[0][qb][0];
#pragma unroll
      for (int ki = 0; ki < 4; ++ki)
#pragma unroll
        for (int e = 0; e < 4; ++e) rm = fmaxf(rm, st[ki][qb][e]);
      rm = fmaxf(rm, __shfl_xor(rm, 16));
      rm = fmaxf(rm, __shfl_xor(rm, 32));
      const float mnew = fmaxf(m_run[qb], rm);
      const float corr = __expf(m_run[qb] - mnew);
      m_run[qb] = mnew;
      float ls = 0.f;
#pragma unroll
      for (int ki = 0; ki < 4; ++ki) {
        f16x4 ph, pl;
#pragma unroll
        for (int e = 0; e < 4; ++e) {
          float p = __expf(st[ki][qb][e] - mnew);
          ls += p;
          _Float16 h = (_Float16)p;
          ph[e] = h;
          if (SPLIT) pl[e] = (_Float16)(p - (float)h);
        }
        pbh[ki][qb] = ph;
        if (SPLIT) pbl[ki][qb] = pl;
      }
      ls += __shfl_xor(ls, 16);
      ls += __shfl_xor(ls, 32);
      l_run[qb] = l_run[qb]*corr + ls;
#pragma unroll
      for (int nd = 0; nd < 4; ++nd)
#pragma unroll
        for (int e = 0; e < 4; ++e) oaccT[nd][qb][e] *= corr;
    }

#pragma unroll
    for (int ki = 0; ki < 4; ++ki) {
      f16x4 avh[4], avl[4];
#pragma unroll
      for (int nd = 0; nd < 4; ++nd) {
        const int row = nd*16 + lr;
        const int bo = (ki*32 + lk*8) ^ ((row & 7) << 4);
        avh[nd] = *(const f16x4*)(Vb + row*128 + bo);
        if (SPLIT) avl[nd] = *(const f16x4*)(Vlo + row*128 + bo);
      }
#pragma unroll
      for (int nd = 0; nd < 4; ++nd)
#pragma unroll
        for (int qb = 0; qb < 2; ++qb) {
          oaccT[nd][qb] = __builtin_amdgcn_mfma_f32_16x16x16f16(avh[nd], pbh[ki][qb], oaccT[nd][qb], 0, 0, 0);
          if (SPLIT) {
            oaccT[nd][qb] = __builtin_amdgcn_mfma_f32_16x16x16f16(avh[nd], pbl[ki][qb], oaccT[nd][qb], 0, 0, 0);
            oaccT[nd][qb] = __builtin_amdgcn_mfma_f32_16x16x16f16(avl[nd], pbh[ki][qb], oaccT[nd][qb], 0, 0, 0);
          }
        }
    }
  }

#pragma unroll
  for (int qb = 0; qb < 2; ++qb) {
    const float inv = 1.0f / l_run[qb];
    const int q = s0 + wave*32 + qb*16 + lr;
    const long base = ((long)q * NB + b) * ldo + qoff;
#pragma unroll
    for (int nd = 0; nd < 4; ++nd) {
      f16x4 o, ol;
#pragma unroll
      for (int e = 0; e < 4; ++e) {
        float v = oaccT[nd][qb][e] * inv;
        _Float16 h = (_Float16)v;
        o[e] = h;
        if (SPLIT) ol[e] = (_Float16)(v - (float)h);
      }
      *(f16x4*)(Oh + base + nd*16 + lk*4) = o;
      if (SPLIT) *(f16x4*)(Ol + base + nd*16 + lk*4) = ol;
    }
  }
}

// ---------------------------------------------------------------------------
// DECODER attention: swapped-operand, plain fp16, KV tile 128 (half the
// barriers of the 64-key version; same validated fragment layouts extended).
// K in LDS: [128 rows][128 B]; V^T: [64 d-rows][256 B]. Same XOR maps.
// ---------------------------------------------------------------------------
__global__ __launch_bounds__(256)
void sattn128_k(const _Float16* __restrict__ Qh, int ldq,
                const _Float16* __restrict__ Kh, int ldk,
                const _Float16* __restrict__ Vh, int ldv,
                _Float16* __restrict__ Oh, int ldo)
{
  __shared__ __align__(16) char Kb[16384];
  __shared__ __align__(16) char Vb[16384];

  const int t = threadIdx.x;
  const int b = blockIdx.x >> 3, hd = blockIdx.x & 7;
  const int s0 = blockIdx.y * 128;
  const int qoff = hd * DH;
  const int wave = t >> 6, lane = t & 63;
  const int lr = lane & 15, lk = lane >> 4;
  const int krow = t >> 1, kpart = t & 1;     // K stage: 128 rows, 2 thr/row
  const int vtp = t & 63, vdc = t >> 6;       // V stage: keys 2vtp,+1; d-chunk 16

  f16x8 qa[2][2];
#pragma unroll
  for (int qb = 0; qb < 2; ++qb)
#pragma unroll
    for (int kk = 0; kk < 2; ++kk) {
      const int q = s0 + wave*32 + qb*16 + lr;
      const long base = ((long)q*NB + b)*ldq + qoff + kk*32 + lk*8;
      f16x8 v = *(const f16x8*)(Qh + base);
#pragma unroll
      for (int e = 0; e < 8; ++e) v[e] = v[e] * (_Float16)0.125f;
      qa[qb][kk] = v;
    }

  float m_run[2] = {-INFINITY, -INFINITY};
  float l_run[2] = {0.f, 0.f};
  f32x4 oaccT[4][2];
#pragma unroll
  for (int nd = 0; nd < 4; ++nd)
#pragma unroll
    for (int qb = 0; qb < 2; ++qb)
#pragma unroll
      for (int e = 0; e < 4; ++e) oaccT[nd][qb][e] = 0.f;

  f16x8 kr[4], vrA[2], vrB[2];
  {
    const long kb = ((long)krow*NB + b)*ldk + qoff + kpart*32;
#pragma unroll
    for (int g = 0; g < 4; ++g) kr[g] = *(const f16x8*)(Kh + kb + g*8);
    const long vb = ((long)(2*vtp)*NB + b)*ldv + qoff + vdc*16;
    vrA[0] = *(const f16x8*)(Vh + vb);
    vrA[1] = *(const f16x8*)(Vh + vb + 8);
    vrB[0] = *(const f16x8*)(Vh + vb + (long)NB*ldv);
    vrB[1] = *(const f16x8*)(Vh + vb + (long)NB*ldv + 8);
  }

  for (int t0 = 0; t0 < S_LEN; t0 += 128) {
    __syncthreads();
    {
#pragma unroll
      for (int g = 0; g < 4; ++g) {
        const int sw = (kpart*64 + g*16) ^ ((krow & 7) << 4);
        *(f16x8*)(Kb + krow*128 + sw) = kr[g];
      }
#pragma unroll
      for (int h = 0; h < 2; ++h)
#pragma unroll
        for (int j = 0; j < 8; ++j) {
          const int dd = vdc*16 + h*8 + j;
          const int off = dd*256 + ((vtp*4) ^ ((dd & 7) << 4));
          f16x2 hv = {vrA[h][j], vrB[h][j]};
          *(f16x2*)(Vb + off) = hv;
        }
    }
    if (t0 + 128 < S_LEN) {
      const long kb = ((long)(t0 + 128 + krow)*NB + b)*ldk + qoff + kpart*32;
#pragma unroll
      for (int g = 0; g < 4; ++g) kr[g] = *(const f16x8*)(Kh + kb + g*8);
      const long vb = ((long)(t0 + 128 + 2*vtp)*NB + b)*ldv + qoff + vdc*16;
      vrA[0] = *(const f16x8*)(Vh + vb);
      vrA[1] = *(const f16x8*)(Vh + vb + 8);
      vrB[0] = *(const f16x8*)(Vh + vb + (long)NB*ldv);
      vrB[1] = *(const f16x8*)(Vh + vb + (long)NB*ldv + 8);
    }
    __syncthreads();

    // ---- S^T[key][q] = mfma(K, Q), 8 key sub-tiles ----
    f32x4 st[8][2];
#pragma unroll
    for (int ki = 0; ki < 8; ++ki)
#pragma unroll
      for (int qb = 0; qb < 2; ++qb)
#pragma unroll
        for (int e = 0; e < 4; ++e) st[ki][qb][e] = 0.f;
#pragma unroll
    for (int kk = 0; kk < 2; ++kk) {
#pragma unroll
      for (int ki = 0; ki < 8; ++ki) {
        const int r = ki*16 + lr;
        const int bo = (lk*16 + kk*64) ^ ((r & 7) << 4);
        f16x8 kbv = *(const f16x8*)(Kb + r*128 + bo);
#pragma unroll
        for (int qb = 0; qb < 2; ++qb)
          st[ki][qb] = __builtin_amdgcn_mfma_f32_16x16x32_f16(kbv, qa[qb][kk], st[ki][qb], 0, 0, 0);
      }
    }

    // ---- online softmax: lane owns q; 32 key scores local + 2 shfl ----
    f16x4 pbh[8][2];
#pragma unroll
    for (int qb = 0; qb < 2; ++qb) {
      float rm = st[0][qb][0];
#pragma unroll
      for (int ki = 0; ki < 8; ++ki)
#pragma unroll
        for (int e = 0; e < 4; ++e) rm = fmaxf(rm, st[ki][qb][e]);
      rm = fmaxf(rm, __shfl_xor(rm, 16));
      rm = fmaxf(rm, __shfl_xor(rm, 32));
      const float mnew = fmaxf(m_run[qb], rm);
      const float corr = __expf(m_run[qb] - mnew);
      m_run[qb] = mnew;
      float ls = 0.f;
#pragma unroll
      for (int ki = 0; ki < 8; ++ki) {
        f16x4 ph;
#pragma unroll
        for (int e = 0; e < 4; ++e) {
          float p = __expf(st[ki][qb][e] - mnew);
          ls += p;
          ph[e] = (_Float16)p;
        }
        pbh[ki][qb] = ph;
      }
      ls += __shfl_xor(ls, 16);
      ls += __shfl_xor(ls, 32);
      l_run[qb] = l_run[qb]*corr + ls;
#pragma unroll
      for (int nd = 0; nd < 4; ++nd)
#pragma unroll
        for (int e = 0; e < 4; ++e) oaccT[nd][qb][e] *= corr;
    }

    // ---- O^T[d][q] += mfma16(V^T, P^T) ----
#pragma unroll
    for (int ki = 0; ki < 8; ++ki) {
#pragma unroll
      for (int nd = 0; nd < 4; ++nd) {
        const int row = nd*16 + lr;
        const int bo = (ki*32 + lk*8) ^ ((row & 7) << 4);
        f16x4 av = *(const f16x4*)(Vb + row*256 + bo);
#pragma unroll
        for (int qb = 0; qb < 2; ++qb)
          oaccT[nd][qb] = __builtin_amdgcn_mfma_f32_16x16x16f16(av, pbh[ki][qb], oaccT[nd][qb], 0, 0, 0);
      }
    }
  }

#pragma unroll
  for (int qb = 0; qb < 2; ++qb) {
    const float inv = 1.0f / l_run[qb];
    const int q = s0 + wave*32 + qb*16 + lr;
    const long base = ((long)q * NB + b) * ldo + qoff;
#pragma unroll
    for (int nd = 0; nd < 4; ++nd) {
      f16x4 o;
#pragma unroll
      for (int e = 0; e < 4; ++e) o[e] = (_Float16)(oaccT[nd][qb][e] * inv);
      *(f16x4*)(Oh + base + nd*16 + lk*4) = o;
    }
  }
}

// ---------------------------------------------------------------------------
// LayerNorm over c=512, one wave per row.
// ES: 0 = fp32 only; 1 = fp32 + split fp16 hi/lo; 2 = fp32 + fp16 hi.
// ---------------------------------------------------------------------------
template<int ES>
__global__ __launch_bounds__(256)
void ln_k(const float* __restrict__ X, const float* __restrict__ g,
          const float* __restrict__ bb, float* __restrict__ Y,
          _Float16* __restrict__ Yh, _Float16* __restrict__ Yl)
{
  const int t = threadIdx.x;
  const int lane = t & 63;
  const long row = (long)blockIdx.x * 4 + (t >> 6);
  const float* xr = X + row * CDIM;
  float4 v0 = *(const float4*)(xr + lane*4);
  float4 v1 = *(const float4*)(xr + 256 + lane*4);
  float s = v0.x+v0.y+v0.z+v0.w + v1.x+v1.y+v1.z+v1.w;
#pragma unroll
  for (int off = 1; off < 64; off <<= 1) s += __shfl_xor(s, off);
  const float mean = s * (1.0f/512.0f);
  float d[8] = {v0.x-mean, v0.y-mean, v0.z-mean, v0.w-mean,
                v1.x-mean, v1.y-mean, v1.z-mean, v1.w-mean};
  float sq = d[0]*d[0]+d[1]*d[1]+d[2]*d[2]+d[3]*d[3]
           + d[4]*d[4]+d[5]*d[5]+d[6]*d[6]+d[7]*d[7];
#pragma unroll
  for (int off = 1; off < 64; off <<= 1) sq += __shfl_xor(sq, off);
  const float inv = 1.0f / sqrtf(sq * (1.0f/512.0f) + 1e-5f);
  float4 g0 = *(const float4*)(g + lane*4);
  float4 g1 = *(const float4*)(g + 256 + lane*4);
  float4 b0 = *(const float4*)(bb + lane*4);
  float4 b1 = *(const float4*)(bb + 256 + lane*4);
  float o[8];
  o[0] = d[0]*inv*g0.x + b0.x; o[1] = d[1]*inv*g0.y + b0.y;
  o[2] = d[2]*inv*g0.z + b0.z; o[3] = d[3]*inv*g0.w + b0.w;
  o[4] = d[4]*inv*g1.x + b1.x; o[5] = d[5]*inv*g1.y + b1.y;
  o[6] = d[6]*inv*g1.z + b1.z; o[7] = d[7]*inv*g1.w + b1.w;
  *(float4*)(Y + row*CDIM + lane*4) = *(float4*)&o[0];
  *(float4*)(Y + row*CDIM + 256 + lane*4) = *(float4*)&o[4];
  if (ES) {
    f16x4 h0, h1, l0, l1;
#pragma unroll
    for (int j = 0; j < 4; ++j) {
      _Float16 h = (_Float16)o[j];     h0[j] = h;
      _Float16 k = (_Float16)o[4+j];   h1[j] = k;
      if (ES == 1) { l0[j] = (_Float16)(o[j] - (float)h); l1[j] = (_Float16)(o[4+j] - (float)k); }
    }
    *(f16x4*)(Yh + row*CDIM + lane*4) = h0;
    *(f16x4*)(Yh + row*CDIM + 256 + lane*4) = h1;
    if (ES == 1) {
      *(f16x4*)(Yl + row*CDIM + lane*4) = l0;
      *(f16x4*)(Yl + row*CDIM + 256 + lane*4) = l1;
    }
  }
}

// ---------------------------------------------------------------------------
// Pack x (N,C,H,W) -> enc_flat (S,n,c); posisted fp32 + split fp16 hi/lo.
// ---------------------------------------------------------------------------
__global__ void pack_pe_k(const float* __restrict__ x, float* __restrict__ encf,
                          float* __restrict__ posd,
                          _Float16* __restrict__ posh, _Float16* __restrict__ posl)
{
  __shared__ float tl[32][33];
  const int b = blockIdx.z;
  const int s0 = blockIdx.x*32, c0 = blockIdx.y*32;
#pragma unroll
  for (int i = 0; i < 4; ++i) {
    int ci = threadIdx.y + i*8;
    tl[ci][threadIdx.x] = x[((long)b*CDIM + c0+ci)*S_LEN + s0 + threadIdx.x];
  }
  __syncthreads();
#pragma unroll
  for (int i = 0; i < 4; ++i) {
    int si = threadIdx.y + i*8;
    int s = s0 + si;
    int ch = c0 + threadIdx.x;
    float val = tl[threadIdx.x][si];
    long o = ((long)s*NB + b)*CDIM + ch;
    encf[o] = val;
    int pos = (ch < 256) ? (s & 31) : (s >> 5);
    int j = (ch & 255) >> 1;
    float dv = expf((float)(2*j) * (-9.210340371976184f / 256.0f));
    float ang = (float)pos * dv;
    float pe = (ch & 1) ? cosf(ang) : sinf(ang);
    float pv = val + pe;
    posd[o] = pv;
    _Float16 h = (_Float16)pv;
    posh[o] = h;
    posl[o] = (_Float16)(pv - (float)h);
  }
}

// (S,n,c) token-major -> (n,c,S) output layout
__global__ void tpose_k(const float* __restrict__ in, float* __restrict__ out)
{
  __shared__ float tl[32][33];
  const int b = blockIdx.z;
  const int s0 = blockIdx.x*32, c0 = blockIdx.y*32;
#pragma unroll
  for (int i = 0; i < 4; ++i) {
    int si = threadIdx.y + i*8;
    tl[si][threadIdx.x] = in[((long)(s0+si)*NB + b)*CDIM + c0 + threadIdx.x];
  }
  __syncthreads();
#pragma unroll
  for (int i = 0; i < 4; ++i) {
    int ci = threadIdx.y + i*8;
    out[((long)b*CDIM + c0+ci)*S_LEN + s0 + threadIdx.x] = tl[threadIdx.x][ci];
  }
}

// cb_w (c,K) -> transposed split-fp16 codebook [K][c] hi/lo
__global__ void cbt16_k(const float* __restrict__ cb,
                        _Float16* __restrict__ outh, _Float16* __restrict__ outl)
{
  __shared__ float tl[32][33];
  const int k0 = blockIdx.x*32, c0 = blockIdx.y*32;
#pragma unroll
  for (int i = 0; i < 4; ++i) {
    int ci = threadIdx.y + i*8;
    tl[ci][threadIdx.x] = cb[(long)(c0+ci)*KCB + k0 + threadIdx.x];
  }
  __syncthreads();
#pragma unroll
  for (int i = 0; i < 4; ++i) {
    int ki = threadIdx.y + i*8;
    float v = tl[threadIdx.x][ki];
    _Float16 h = (_Float16)v;
    outh[(long)(k0+ki)*CDIM + c0 + threadIdx.x] = h;
    outl[(long)(k0+ki)*CDIM + c0 + threadIdx.x] = (_Float16)(v - (float)h);
  }
}

// fp32 -> fp16 elementwise, 8 per thread
__global__ __launch_bounds__(256)
void conv16_k(const float* __restrict__ in, _Float16* __restrict__ out)
{
  const long i = ((long)blockIdx.x * 256 + threadIdx.x) * 8;
  float4 v0 = *(const float4*)(in + i);
  float4 v1 = *(const float4*)(in + i + 4);
  f16x8 h;
  h[0]=(_Float16)v0.x; h[1]=(_Float16)v0.y; h[2]=(_Float16)v0.z; h[3]=(_Float16)v0.w;
  h[4]=(_Float16)v1.x; h[5]=(_Float16)v1.y; h[6]=(_Float16)v1.z; h[7]=(_Float16)v1.w;
  *(f16x8*)(out + i) = h;
}

// fp32 -> split fp16 hi/lo, 8 per thread
__global__ __launch_bounds__(256)
void convsplit_k(const float* __restrict__ in, _Float16* __restrict__ oh,
                 _Float16* __restrict__ ol)
{
  const long i = ((long)blockIdx.x * 256 + threadIdx.x) * 8;
  float4 v0 = *(const float4*)(in + i);
  float4 v1 = *(const float4*)(in + i + 4);
  float vv[8] = {v0.x,v0.y,v0.z,v0.w,v1.x,v1.y,v1.z,v1.w};
  f16x8 h, l;
#pragma unroll
  for (int j = 0; j < 8; ++j) {
    _Float16 hh = (_Float16)vv[j];
    h[j] = hh;
    l[j] = (_Float16)(vv[j] - (float)hh);
  }
  *(f16x8*)(oh + i) = h;
  *(f16x8*)(ol + i) = l;
}

// Per-token row of logits: argmax (np first-occurrence) + write P (fp16)
__global__ __launch_bounds__(256)
void simstats_k(const float* __restrict__ logits, _Float16* __restrict__ Pbuf,
                int* __restrict__ codes_tok, float* __restrict__ codes_out)
{
  const long phys = blockIdx.x;
  const float* rowp = logits + phys * KCB;
  const int t = threadIdx.x;
  float vals[16];
#pragma unroll
  for (int rep = 0; rep < 4; ++rep) {
    float4 v = *(const float4*)(rowp + rep*1024 + t*4);
    vals[rep*4+0]=v.x; vals[rep*4+1]=v.y; vals[rep*4+2]=v.z; vals[rep*4+3]=v.w;
  }
  float mv = -INFINITY; int mi = 0;
#pragma unroll
  for (int rep = 0; rep < 4; ++rep)
#pragma unroll
    for (int j = 0; j < 4; ++j) {
      float xv = vals[rep*4+j];
      int ix = rep*1024 + t*4 + j;
      if (xv > mv) { mv = xv; mi = ix; }
    }
  const int lane = t & 63, wid = t >> 6;
#pragma unroll
  for (int off = 1; off < 64; off <<= 1) {
    float ov = __shfl_xor(mv, off);
    int   oi = __shfl_xor(mi, off);
    if (ov > mv || (ov == mv && oi < mi)) { mv = ov; mi = oi; }
  }
  __shared__ float smax[4]; __shared__ int sidx[4]; __shared__ float ssum[4];
  __shared__ float fm; __shared__ int fi; __shared__ float sinv;
  if (lane == 0) { smax[wid] = mv; sidx[wid] = mi; }
  __syncthreads();
  if (t == 0) {
    float bm = smax[0]; int bi = sidx[0];
    for (int wq = 1; wq < 4; ++wq)
      if (smax[wq] > bm || (smax[wq] == bm && sidx[wq] < bi)) { bm = smax[wq]; bi = sidx[wq]; }
    fm = bm; fi = bi;
  }
  __syncthreads();
  const float Mx = fm;
  float se = 0.f;
#pragma unroll
  for (int q = 0; q < 16; ++q) se += __expf(vals[q] - Mx);
#pragma unroll
  for (int off = 1; off < 64; off <<= 1) se += __shfl_xor(se, off);
  if (lane == 0) ssum[wid] = se;
  __syncthreads();
  const int b = (int)(phys >> 10), s = (int)(phys & 1023);
  if (t == 0) {
    float tot = ssum[0]+ssum[1]+ssum[2]+ssum[3];
    sinv = 1.0f / tot;
    codes_tok[s*NB + b] = fi;
    codes_out[phys] = (float)fi;
  }
  __syncthreads();
  const float inv = sinv;
  _Float16* prow = Pbuf + ((long)s*NB + b) * KCB;
#pragma unroll
  for (int rep = 0; rep < 4; ++rep) {
    f16x4 pv;
#pragma unroll
    for (int j = 0; j < 4; ++j) pv[j] = (_Float16)(__expf(vals[rep*4+j] - Mx) * inv);
    *(f16x4*)(prow + rep*1024 + t*4) = pv;
  }
}

// quant = (hard - soft) + soft; emit hard fp32 and quant fp32 + fp16-hi.
__global__ __launch_bounds__(128)
void quant_k(const float* __restrict__ soft, const int* __restrict__ codes_tok,
             const _Float16* __restrict__ cbh, const _Float16* __restrict__ cbl,
             float* __restrict__ quant, float* __restrict__ hardb,
             _Float16* __restrict__ qh16)
{
  const int r = blockIdx.x;
  const int code = codes_tok[r];
  const int c = threadIdx.x * 4;
  f16x4 hh = *(const f16x4*)(cbh + (long)code*CDIM + c);
  f16x4 hl = *(const f16x4*)(cbl + (long)code*CDIM + c);
  float4 sf = *(const float4*)(soft + (long)r*CDIM + c);
  float4 h, q;
  h.x = (float)hh[0] + (float)hl[0]; h.y = (float)hh[1] + (float)hl[1];
  h.z = (float)hh[2] + (float)hl[2]; h.w = (float)hh[3] + (float)hl[3];
  q.x = (h.x - sf.x) + sf.x; q.y = (h.y - sf.y) + sf.y;
  q.z = (h.z - sf.z) + sf.z; q.w = (h.w - sf.w) + sf.w;
  *(float4*)(quant + (long)r*CDIM + c) = q;
  *(float4*)(hardb + (long)r*CDIM + c) = h;
  f16x4 qh = {(_Float16)q.x, (_Float16)q.y, (_Float16)q.z, (_Float16)q.w};
  *(f16x4*)(qh16 + (long)r*CDIM + c) = qh;
}

// Detect the storage format of the bool mask buffer.
__global__ void maskdetect_k(const void* __restrict__ mask, int* __restrict__ flag)
{
  const unsigned int* wds = (const unsigned int*)mask;
  int t = threadIdx.x;
  int okI = 1, okF = 1, okL = 1;
  for (int i = t; i < 2048; i += 256) {
    unsigned int u = wds[i];
    if (u > 1u) okI = 0;
    if (u != 0u && u != 0x3F800000u) okF = 0;
    if ((i & 1) ? (u != 0u) : (u > 1u)) okL = 0;
  }
  __shared__ int sI, sF, sL;
  if (t == 0) { sI = 1; sF = 1; sL = 1; }
  __syncthreads();
  if (!okI) atomicAnd(&sI, 0);
  if (!okF) atomicAnd(&sF, 0);
  if (!okL) atomicAnd(&sL, 0);
  __syncthreads();
  if (t == 0) {
    int f;
    if (sI && sL) f = 3;
    else if (sI)  f = 1;
    else if (sF)  f = 2;
    else          f = 0;
    *flag = f;
  }
}

// mixed = mask ? enc_flat : post; fp32 + fp16-hi outputs
__global__ __launch_bounds__(256)
void mixed_k(const float* __restrict__ encf, const float* __restrict__ post,
             const void* __restrict__ mask, const int* __restrict__ flag,
             float* __restrict__ outx, _Float16* __restrict__ outh)
{
  long gid = (long)blockIdx.x * blockDim.x + threadIdx.x;
  int r = (int)(gid >> 7);
  int c = (int)(gid & 127) * 4;
  int f = *flag;
  bool mv;
  if (f == 0)      mv = ((const unsigned char*)mask)[r] != 0;
  else if (f == 1) mv = ((const int*)mask)[r] != 0;
  else if (f == 3) mv = ((const long long*)mask)[r] != 0;
  else             mv = ((const float*)mask)[r] != 0.0f;
  const float* src = mv ? encf : post;
  float4 v = *(const float4*)(src + (long)r*CDIM + c);
  *(float4*)(outx + (long)r*CDIM + c) = v;
  f16x4 h = {(_Float16)v.x, (_Float16)v.y, (_Float16)v.z, (_Float16)v.w};
  *(f16x4*)(outh + (long)r*CDIM + c) = h;
}

extern "C" void kernel_launch(void* const* d_in, const int* in_sizes, int n_in,
                              void* d_out, int out_size, void* d_ws, size_t ws_size,
                              hipStream_t stream)
{
  const float* x       = (const float*)d_in[0];
  const float* pre_w   = (const float*)d_in[1];
  const float* pre_b   = (const float*)d_in[2];
  const float* post_w  = (const float*)d_in[3];
  const float* post_b  = (const float*)d_in[4];
  const float* cb_w    = (const float*)d_in[5];
  const float* e_qkv_w = (const float*)d_in[6];
  const float* e_qkv_b = (const float*)d_in[7];
  const float* e_o_w   = (const float*)d_in[8];
  const float* e_o_b   = (const float*)d_in[9];
  const float* e_ln1_w = (const float*)d_in[10];
  const float* e_ln1_b = (const float*)d_in[11];
  const float* e_ln2_w = (const float*)d_in[12];
  const float* e_ln2_b = (const float*)d_in[13];
  const float* e_f1_w  = (const float*)d_in[14];
  const float* e_f1_b  = (const float*)d_in[15];
  const float* e_f2_w  = (const float*)d_in[16];
  const float* e_f2_b  = (const float*)d_in[17];
  const float* d_sqkv_w= (const float*)d_in[18];
  const float* d_sqkv_b= (const float*)d_in[19];
  const float* d_so_w  = (const float*)d_in[20];
  const float* d_so_b  = (const float*)d_in[21];
  const float* d_cqkv_w= (const float*)d_in[22];
  const float* d_cqkv_b= (const float*)d_in[23];
  const float* d_co_w  = (const float*)d_in[24];
  const float* d_co_b  = (const float*)d_in[25];
  const float* d_ln1w  = (const float*)d_in[26];
  const float* d_ln1b  = (const float*)d_in[27];
  const float* d_ln2w  = (const float*)d_in[28];
  const float* d_ln2b  = (const float*)d_in[29];
  const float* d_ln3w  = (const float*)d_in[30];
  const float* d_ln3b  = (const float*)d_in[31];
  const float* d_f1w   = (const float*)d_in[32];
  const float* d_f1b   = (const float*)d_in[33];
  const float* d_f2w   = (const float*)d_in[34];
  const float* d_f2b   = (const float*)d_in[35];
  const void*  mask    = d_in[36];

  float* out = (float*)d_out;
  float* o_quant  = out;
  float* o_high   = out + 4194304;
  float* o_softs  = out + 8388608;
  float* o_hards  = out + 12582912;
  float* o_codes  = out + 16777216;
  float* o_logits = out + 16785408;

  float* ws    = (float*)d_ws;
  float* ENC   = ws;
  float* Xb    = ws + TOKC;
  float* T1    = ws + 2*TOKC;
  float* T2    = ws + 3*TOKC;
  float* QKV   = ws + 4*TOKC;
  float* MEMB  = ws + 7*TOKC;
  float* CBREG = ws + 8*TOKC;
  int*   CODES = (int*)(CBREG + (long)KCB*CDIM);
  int*   FLAG  = CODES + NTOK;
  float* HARDB = QKV;
  float* QUANT = QKV + TOKC;
  _Float16* PBUF = (_Float16*)QKV;
  _Float16* CBH  = (_Float16*)T1;
  _Float16* QKVh = (_Float16*)QKV;
  _Float16* QKVl = QKVh + (long)NTOK*3*CDIM;
  _Float16* CQh  = (_Float16*)QKV;
  _Float16* KVh  = (_Float16*)(QKV + TOKC);
  _Float16* CBT16h = (_Float16*)CBREG;
  _Float16* CBT16l = CBT16h + (long)KCB*CDIM;
  _Float16* PREH = (_Float16*)T2;
  _Float16* PREL = PREH + TOKC;
  _Float16* AH16   = (_Float16*)ENC;
  _Float16* FH16   = AH16 + TOKC;
  _Float16* XH16   = ((_Float16*)QKV) + 4*TOKC;
  _Float16* MEMBH16= XH16 + TOKC;
  _Float16* QH16   = ((_Float16*)T1) + TOKC;

  const long WQSZ = (long)6*3*CDIM*CDIM;   // 4,718,592 elems
  const long WSSZ = (long)6*CDIM*CDIM;     // 1,572,864 elems
  _Float16* SCR  = (_Float16*)o_logits;
  _Float16* WQH = SCR;            _Float16* WQL = WQH + WQSZ;
  _Float16* WOH = WQL + WQSZ;     _Float16* WOL = WOH + WSSZ;
  _Float16* WF1H= WOL + WSSZ;     _Float16* WF1L= WF1H + WSSZ;
  _Float16* WF2H= WF1L + WSSZ;    _Float16* WF2L= WF2H + WSSZ;
  _Float16* WPH = WF2L + WSSZ;    _Float16* WPL = WPH + (long)CDIM*CDIM;
  _Float16* XH  = WPL + (long)CDIM*CDIM;  _Float16* XL  = XH + TOKC;
  _Float16* AH  = XL + TOKC;      _Float16* AL  = AH + TOKC;
  _Float16* L1H = AL + TOKC;      _Float16* L1L = L1H + TOKC;
  _Float16* H1H = L1L + TOKC;     _Float16* H1L = H1H + TOKC;

  // ---- decoder fp16 weights (converted once; regions dead by decoder time) --
  _Float16* DWSQ = (_Float16*)MEMB;
  _Float16* DWCQ = (_Float16*)T1;
  _Float16* DWF1 = DWCQ + WQSZ;
  _Float16* DWF2 = DWF1 + WSSZ;
  _Float16* DWSO = (_Float16*)CBREG;
  _Float16* DWCO = DWSO + WSSZ;

  const size_t NEED = (size_t)(8*TOKC + (long)KCB*CDIM + 2*NTOK + NTOK + 16) * 4;
  if (ws_size < NEED) return;

  const int M = NTOK;
  dim3 tgrid(S_LEN/32, CDIM/32, NB), tblk(32, 8);
  dim3 agrid(NB*8, S_LEN/128);

  pack_pe_k<<<tgrid, tblk, 0, stream>>>(x, ENC, Xb, XH, XL);
  cbt16_k<<<dim3(KCB/32, CDIM/32), tblk, 0, stream>>>(cb_w, CBT16h, CBT16l);
  maskdetect_k<<<1, 256, 0, stream>>>(mask, FLAG);
  convsplit_k<<<(int)(WQSZ/2048), 256, 0, stream>>>(e_qkv_w, WQH, WQL);
  convsplit_k<<<(int)(WSSZ/2048), 256, 0, stream>>>(e_o_w,  WOH,  WOL);
  convsplit_k<<<(int)(WSSZ/2048), 256, 0, stream>>>(e_f1_w, WF1H, WF1L);
  convsplit_k<<<(int)(WSSZ/2048), 256, 0, stream>>>(e_f2_w, WF2H, WF2L);
  convsplit_k<<<(int)(((long)CDIM*CDIM)/2048), 256, 0, stream>>>(pre_w, WPH, WPL);

  // -------- encoder (split-fp16 MFMA, swapped-operand attention) --------
  for (int i = 0; i < NLAYER; ++i) {
    hgemm_k<128,1,2,true,false,false,false,true><<<dim3(3*CDIM/128, M/128), 256, 0, stream>>>(
        XH, WQH + (long)i*3*CDIM*CDIM, e_qkv_b + i*3*CDIM, nullptr, 0,
        nullptr, 3*CDIM, M, 3*CDIM, CDIM, QKVh, QKVl, XL, WQL + (long)i*3*CDIM*CDIM);
    sattn_k<1><<<agrid, 256, 0, stream>>>(QKVh, QKVl, 3*CDIM,
        QKVh+CDIM, QKVl+CDIM, 3*CDIM, QKVh+2*CDIM, QKVl+2*CDIM, 3*CDIM,
        AH, AL, CDIM);
    hgemm_k<64,1,2,true,true,false,false,false><<<dim3(CDIM/128, M/64), 256, 0, stream>>>(
        AH, WOH + (long)i*CDIM*CDIM, e_o_b + i*CDIM, Xb, CDIM,
        T2, CDIM, M, CDIM, CDIM, nullptr, nullptr, AL, WOL + (long)i*CDIM*CDIM);
    ln_k<1><<<M/4, 256, 0, stream>>>(T2, e_ln1_w + i*CDIM, e_ln1_b + i*CDIM, T1, L1H, L1L);
    hgemm_k<64,1,2,true,false,true,false,true><<<dim3(CDIM/128, M/64), 256, 0, stream>>>(
        L1H, WF1H + (long)i*CDIM*CDIM, e_f1_b + i*CDIM, nullptr, 0,
        nullptr, CDIM, M, CDIM, CDIM, H1H, H1L, L1L, WF1L + (long)i*CDIM*CDIM);
    hgemm_k<64,1,2,true,true,false,false,false><<<dim3(CDIM/128, M/64), 256, 0, stream>>>(
        H1H, WF2H + (long)i*CDIM*CDIM, e_f2_b + i*CDIM, T1, CDIM,
        T2, CDIM, M, CDIM, CDIM, nullptr, nullptr, H1L, WF2L + (long)i*CDIM*CDIM);
    ln_k<1><<<M/4, 256, 0, stream>>>(T2, e_ln2_w + i*CDIM, e_ln2_b + i*CDIM, Xb, XH, XL);
  }

  // -------- codebook / quantizer --------
  hgemm_k<64,1,2,true,false,false,false,true><<<dim3(CDIM/128, M/64), 256, 0, stream>>>(
      XH, WPH, pre_b, nullptr, 0, T1, CDIM, M, CDIM, CDIM, PREH, PREL, XL, WPL);
  tpose_k<<<tgrid, tblk, 0, stream>>>(T1, o_high);
  hgemm_k<128,1,2,false,false,false,true,false><<<dim3(KCB/128, M/128), 256, 0, stream>>>(
      PREH, CBT16h, nullptr, nullptr, 0, o_logits, KCB, M, KCB, CDIM,
      nullptr, nullptr, PREL, CBT16l);
  conv16_k<<<(CDIM*(long)KCB)/(256*8), 256, 0, stream>>>(cb_w, CBH);
  simstats_k<<<NTOK, 256, 0, stream>>>(o_logits, PBUF, CODES, o_codes);
  hgemm_k<64,0,1,false,false,false,false,false><<<dim3(CDIM/128, M/64), 256, 0, stream>>>(
      PBUF, CBH, nullptr, nullptr, 0, T2, CDIM, M, CDIM, KCB,
      nullptr, nullptr, nullptr, nullptr);                                   // soft
  tpose_k<<<tgrid, tblk, 0, stream>>>(T2, o_softs);
  quant_k<<<NTOK, 128, 0, stream>>>(T2, CODES, CBT16h, CBT16l, QUANT, HARDB, QH16);
  tpose_k<<<tgrid, tblk, 0, stream>>>(HARDB, o_hards);
  conv16_k<<<(int)(WSSZ/2048), 256, 0, stream>>>(d_so_w, DWSO);
  conv16_k<<<(int)(WSSZ/2048), 256, 0, stream>>>(d_co_w, DWCO);
  hgemm_k<64,0,3,true,false,false,false,true><<<dim3(CDIM/128, M/64), 256, 0, stream>>>(
      QH16, post_w, post_b, nullptr, 0, MEMB, CDIM, M, CDIM, CDIM,
      MEMBH16, nullptr, nullptr, nullptr);
  conv16_k<<<(int)(WQSZ/2048), 256, 0, stream>>>(d_cqkv_w, DWCQ);
  conv16_k<<<(int)(WSSZ/2048), 256, 0, stream>>>(d_f1w, DWF1);
  conv16_k<<<(int)(WSSZ/2048), 256, 0, stream>>>(d_f2w, DWF2);
  mixed_k<<<4096, 256, 0, stream>>>(ENC, MEMB, mask, FLAG, Xb, XH16);
  conv16_k<<<(int)(WQSZ/2048), 256, 0, stream>>>(d_sqkv_w, DWSQ);

  // -------- decoder (f16 MFMA, KV-128 swapped-operand attention) --------
  for (int i = 0; i < NLAYER; ++i) {
    hgemm_k<128,0,1,true,false,false,false,true><<<dim3(3*CDIM/128, M/128), 256, 0, stream>>>(
        XH16, DWSQ + (long)i*3*CDIM*CDIM, d_sqkv_b + i*3*CDIM, nullptr, 0,
        nullptr, 3*CDIM, M, 3*CDIM, CDIM, QKVh, nullptr, nullptr, nullptr);
    sattn128_k<<<agrid, 256, 0, stream>>>(QKVh, 3*CDIM,
        QKVh+CDIM, 3*CDIM, QKVh+2*CDIM, 3*CDIM, AH16, CDIM);
    hgemm_k<64,0,1,true,true,false,false,false><<<dim3(CDIM/128, M/64), 256, 0, stream>>>(
        AH16, DWSO + (long)i*CDIM*CDIM, d_so_b + i*CDIM, Xb, CDIM,
        T2, CDIM, M, CDIM, CDIM, nullptr, nullptr, nullptr, nullptr);
    ln_k<2><<<M/4, 256, 0, stream>>>(T2, d_ln1w + i*CDIM, d_ln1b + i*CDIM, Xb, XH16, nullptr);
    hgemm_k<64,0,1,true,false,false,false,true><<<dim3(CDIM/128, M/64), 256, 0, stream>>>(
        XH16, DWCQ + (long)i*3*CDIM*CDIM, d_cqkv_b + i*3*CDIM, nullptr, 0,
        nullptr, CDIM, M, CDIM, CDIM, CQh, nullptr, nullptr, nullptr);
    hgemm_k<128,0,1,true,false,false,false,true><<<dim3(2*CDIM/128, M/128), 256, 0, stream>>>(
        MEMBH16, DWCQ + (long)i*3*CDIM*CDIM + (long)CDIM*CDIM,
        d_cqkv_b + i*3*CDIM + CDIM, nullptr, 0,
        nullptr, 2*CDIM, M, 2*CDIM, CDIM, KVh, nullptr, nullptr, nullptr);
    sattn128_k<<<agrid, 256, 0, stream>>>(CQh, CDIM,
        KVh, 2*CDIM, KVh+CDIM, 2*CDIM, AH16, CDIM);
    hgemm_k<64,0,1,true,true,false,false,false><<<dim3(CDIM/128, M/64), 256, 0, stream>>>(
        AH16, DWCO + (long)i*CDIM*CDIM, d_co_b + i*CDIM, Xb, CDIM,
        T2, CDIM, M, CDIM, CDIM, nullptr, nullptr, nullptr, nullptr);
    ln_k<2><<<M/4, 256, 0, stream>>>(T2, d_ln2w + i*CDIM, d_ln2b + i*CDIM, Xb, XH16, nullptr);
    hgemm_k<64,0,1,true,false,true,false,true><<<dim3(CDIM/128, M/64), 256, 0, stream>>>(
        XH16, DWF1 + (long)i*CDIM*CDIM, d_f1b + i*CDIM, nullptr, 0,
        nullptr, CDIM, M, CDIM, CDIM, FH16, nullptr, nullptr, nullptr);
    hgemm_k<64,0,1,true,true,false,false,false><<<dim3(CDIM/128, M/64), 256, 0, stream>>>(
        FH16, DWF2 + (long)i*CDIM*CDIM, d_f2b + i*CDIM, Xb, CDIM,
        T2, CDIM, M, CDIM, CDIM, nullptr, nullptr, nullptr, nullptr);
    ln_k<2><<<M/4, 256, 0, stream>>>(T2, d_ln3w + i*CDIM, d_ln3b + i*CDIM, Xb, XH16, nullptr);
  }
  tpose_k<<<tgrid, tblk, 0, stream>>>(Xb, o_quant);
}

// Round 17
// 2613.448 us; speedup vs baseline: 4.7966x; 1.0348x over previous
//
#include <hip/hip_runtime.h>
#include <math.h>

#define S_LEN 1024
#define NB 8
#define CDIM 512
#define KCB 4096
#define DH 64
#define NLAYER 6
#define NTOK (S_LEN*NB)
#define TOKC ((long)NTOK*CDIM)

typedef __attribute__((ext_vector_type(8))) _Float16 f16x8;
typedef __attribute__((ext_vector_type(4))) _Float16 f16x4;
typedef __attribute__((ext_vector_type(2))) _Float16 f16x2;
typedef __attribute__((ext_vector_type(4))) float f32x4;

// ---------------------------------------------------------------------------
// MFMA GEMM: C[M,N] = A[M,K] @ W[N,K]^T (+bias/residual/relu).
// TM in {64,128}; N-tile 128. BK=64, mfma_f32_16x16x32_f16, XOR-swizzled LDS.
// SPLIT=1: hi/lo split-fp16, 3 MFMAs/pair (~fp32 accuracy).
// F16IN: 0 = A,W fp32; 1 = A,W fp16; 2 = A,W split fp16 hi/lo; 3 = A fp16,
// W fp32-converted.
// RESM: 0 none; 1 fp32 Rsrc; 2 fp16-hi Rh16; 3 fp16 hi+lo (Rh16+Rl16) —
// hi+lo reconstruction error ~2^-22 rel (same class as split-MFMA inputs).
// E16: epilogue writes fp16 hi (Ch16) (+lo Cl16 if SPLIT); fp32 C if C!=0.
// OREMAP: output row (s*NB+b) -> (b*S_LEN+s).
// NOTE: A and C must NOT alias (blocks of one dispatch race).
// ---------------------------------------------------------------------------
template<int TM, int SPLIT, int F16IN, bool BIAS, int RESM, bool RELU, bool OREMAP, bool E16>
__global__ __launch_bounds__(256)
void hgemm_k(const void* __restrict__ Av, const void* __restrict__ Wv,
             const float* __restrict__ bias, const float* __restrict__ Rsrc, int ldr,
             float* __restrict__ C, int ldc, int M, int N, int K,
             _Float16* __restrict__ Ch16, _Float16* __restrict__ Cl16,
             const void* __restrict__ Avl, const void* __restrict__ Wvl,
             const _Float16* __restrict__ Rh16, const _Float16* __restrict__ Rl16)
{
  constexpr int MI = TM / 32;
  constexpr int ATPR = 256 / TM;
  constexpr int ACOL = 64 / ATPR;
  constexpr bool AF16 = (F16IN >= 1);
  constexpr bool WF16 = (F16IN == 1 || F16IN == 2);
  __shared__ __align__(16) _Float16 Ah[TM*64];
  __shared__ __align__(16) _Float16 Bh[128*64];
  __shared__ __align__(16) _Float16 Al[SPLIT ? TM*64 : 8];
  __shared__ __align__(16) _Float16 Bl[SPLIT ? 128*64 : 8];
  const int t = threadIdx.x;
  const int m0 = blockIdx.y * TM, n0 = blockIdx.x * 128;

  const int arow = t / ATPR, apart = t % ATPR;
  const int brow = t >> 1, bpart = t & 1;

  const float*    Af  = (const float*)Av;
  const _Float16* Axh = (const _Float16*)Av;
  const _Float16* Axl = (const _Float16*)Avl;
  const float*    Wf  = (const float*)Wv;
  const _Float16* Wxh = (const _Float16*)Wv;
  const _Float16* Wxl = (const _Float16*)Wvl;
  const long aoff = (long)(m0 + arow) * K + apart * ACOL;
  const long boff = (long)(n0 + brow) * K + bpart * 32;

  const int lane = t & 63, wave = t >> 6;
  const int wm = wave >> 1, wn = wave & 1;
  const int lr = lane & 15, lk = lane >> 4;

  f32x4 acc[MI][4];
#pragma unroll
  for (int mi = 0; mi < MI; ++mi)
#pragma unroll
    for (int ni = 0; ni < 4; ++ni)
#pragma unroll
      for (int e = 0; e < 4; ++e) acc[mi][ni][e] = 0.f;

  float4 a4[ACOL/4], b4[8];
  f16x8  a16[ACOL/8], b16[4];
  f16x8  a16l[F16IN==2 ? ACOL/8 : 1], b16l[F16IN==2 ? 4 : 1];
  if (AF16) {
#pragma unroll
    for (int g = 0; g < ACOL/8; ++g) a16[g] = *(const f16x8*)(Axh + aoff + g*8);
    if (F16IN == 2) {
#pragma unroll
      for (int g = 0; g < ACOL/8; ++g) a16l[g] = *(const f16x8*)(Axl + aoff + g*8);
    }
  } else {
#pragma unroll
    for (int j = 0; j < ACOL/4; ++j) a4[j] = *(const float4*)(Af + aoff + j*4);
  }
  if (WF16) {
#pragma unroll
    for (int g = 0; g < 4; ++g) b16[g] = *(const f16x8*)(Wxh + boff + g*8);
    if (F16IN == 2) {
#pragma unroll
      for (int g = 0; g < 4; ++g) b16l[g] = *(const f16x8*)(Wxl + boff + g*8);
    }
  } else {
#pragma unroll
    for (int j = 0; j < 8; ++j) b4[j] = *(const float4*)(Wf + boff + j*4);
  }

  for (int k0 = 0; k0 < K; k0 += 64) {
    __syncthreads();
    if (AF16) {
#pragma unroll
      for (int g = 0; g < ACOL/8; ++g) {
        const int sw = (apart*ACOL*2 + g*16) ^ ((arow & 7) << 4);
        *(f16x8*)((char*)Ah + arow*128 + sw) = a16[g];
        if (F16IN == 2) *(f16x8*)((char*)Al + arow*128 + sw) = a16l[g];
      }
    } else {
      const float* af = (const float*)a4;
#pragma unroll
      for (int g = 0; g < ACOL/8; ++g) {
        f16x8 h, l;
#pragma unroll
        for (int j = 0; j < 8; ++j) {
          float xv = af[g*8+j];
          _Float16 hh = (_Float16)xv;
          h[j] = hh;
          if (SPLIT) l[j] = (_Float16)(xv - (float)hh);
        }
        const int sw = (apart*ACOL*2 + g*16) ^ ((arow & 7) << 4);
        *(f16x8*)((char*)Ah + arow*128 + sw) = h;
        if (SPLIT) *(f16x8*)((char*)Al + arow*128 + sw) = l;
      }
    }
    if (WF16) {
#pragma unroll
      for (int g = 0; g < 4; ++g) {
        const int sw = (bpart*64 + g*16) ^ ((brow & 7) << 4);
        *(f16x8*)((char*)Bh + brow*128 + sw) = b16[g];
        if (F16IN == 2) *(f16x8*)((char*)Bl + brow*128 + sw) = b16l[g];
      }
    } else {
      const float* bf = (const float*)b4;
#pragma unroll
      for (int g = 0; g < 4; ++g) {
        f16x8 h, l;
#pragma unroll
        for (int j = 0; j < 8; ++j) {
          float xv = bf[g*8+j];
          _Float16 hh = (_Float16)xv;
          h[j] = hh;
          if (SPLIT) l[j] = (_Float16)(xv - (float)hh);
        }
        const int sw = (bpart*64 + g*16) ^ ((brow & 7) << 4);
        *(f16x8*)((char*)Bh + brow*128 + sw) = h;
        if (SPLIT) *(f16x8*)((char*)Bl + brow*128 + sw) = l;
      }
    }
    __syncthreads();
    if (k0 + 64 < K) {
      if (AF16) {
#pragma unroll
        for (int g = 0; g < ACOL/8; ++g) a16[g] = *(const f16x8*)(Axh + aoff + k0 + 64 + g*8);
        if (F16IN == 2) {
#pragma unroll
          for (int g = 0; g < ACOL/8; ++g) a16l[g] = *(const f16x8*)(Axl + aoff + k0 + 64 + g*8);
        }
      } else {
#pragma unroll
        for (int j = 0; j < ACOL/4; ++j) a4[j] = *(const float4*)(Af + aoff + k0 + 64 + j*4);
      }
      if (WF16) {
#pragma unroll
        for (int g = 0; g < 4; ++g) b16[g] = *(const f16x8*)(Wxh + boff + k0 + 64 + g*8);
        if (F16IN == 2) {
#pragma unroll
          for (int g = 0; g < 4; ++g) b16l[g] = *(const f16x8*)(Wxl + boff + k0 + 64 + g*8);
        }
      } else {
#pragma unroll
        for (int j = 0; j < 8; ++j) b4[j] = *(const float4*)(Wf + boff + k0 + 64 + j*4);
      }
    }
#pragma unroll
    for (int kk = 0; kk < 2; ++kk) {
      f16x8 afh[MI], bfh[4], afl[MI], bfl[4];
#pragma unroll
      for (int mi = 0; mi < MI; ++mi) {
        const int r = wm*(TM/2) + mi*16 + lr;
        const int bo = (lk*16 + kk*64) ^ ((r & 7) << 4);
        afh[mi] = *(const f16x8*)((const char*)Ah + r*128 + bo);
        if (SPLIT) afl[mi] = *(const f16x8*)((const char*)Al + r*128 + bo);
      }
#pragma unroll
      for (int ni = 0; ni < 4; ++ni) {
        const int r = wn*64 + ni*16 + lr;
        const int bo = (lk*16 + kk*64) ^ ((r & 7) << 4);
        bfh[ni] = *(const f16x8*)((const char*)Bh + r*128 + bo);
        if (SPLIT) bfl[ni] = *(const f16x8*)((const char*)Bl + r*128 + bo);
      }
#pragma unroll
      for (int mi = 0; mi < MI; ++mi)
#pragma unroll
        for (int ni = 0; ni < 4; ++ni) {
          acc[mi][ni] = __builtin_amdgcn_mfma_f32_16x16x32_f16(afh[mi], bfh[ni], acc[mi][ni], 0, 0, 0);
          if (SPLIT) {
            acc[mi][ni] = __builtin_amdgcn_mfma_f32_16x16x32_f16(afh[mi], bfl[ni], acc[mi][ni], 0, 0, 0);
            acc[mi][ni] = __builtin_amdgcn_mfma_f32_16x16x32_f16(afl[mi], bfh[ni], acc[mi][ni], 0, 0, 0);
          }
        }
    }
  }

  float bvv[4];
  if (BIAS) {
#pragma unroll
    for (int ni = 0; ni < 4; ++ni) bvv[ni] = bias[n0 + wn*64 + ni*16 + lr];
  }
#pragma unroll
  for (int mi = 0; mi < MI; ++mi)
#pragma unroll
  for (int i = 0; i < 4; ++i) {
    const int rm = m0 + wm*(TM/2) + mi*16 + lk*4 + i;
    long orow = rm;
    if (OREMAP) orow = (long)(rm & (NB-1)) * S_LEN + (rm >> 3);
#pragma unroll
    for (int ni = 0; ni < 4; ++ni) {
      const int col = n0 + wn*64 + ni*16 + lr;
      float v = acc[mi][ni][i];
      if (BIAS) v += bvv[ni];
      if (RESM == 1) v += Rsrc[(long)rm*ldr + col];
      else if (RESM == 2) v += (float)Rh16[(long)rm*ldr + col];
      else if (RESM == 3) v += (float)Rh16[(long)rm*ldr + col] + (float)Rl16[(long)rm*ldr + col];
      if (RELU) v = fmaxf(v, 0.f);
      if (E16) {
        _Float16 hv = (_Float16)v;
        Ch16[(long)rm*ldc + col] = hv;
        if (SPLIT) Cl16[(long)rm*ldc + col] = (_Float16)(v - (float)hv);
        if (C != nullptr) C[orow*(long)ldc + col] = v;
      } else {
        C[orow*(long)ldc + col] = v;
      }
    }
  }
}

// ---------------------------------------------------------------------------
// Swapped-operand flash attention, KV tile 64 (validated r12-14). ENCODER.
// SPLIT=1: hi/lo split operands, 3 MFMAs/pair, split hi/lo output.
// ---------------------------------------------------------------------------
template<int SPLIT>
__global__ __launch_bounds__(256)
void sattn_k(const _Float16* __restrict__ Qh, const _Float16* __restrict__ Ql, int ldq,
             const _Float16* __restrict__ Kh, const _Float16* __restrict__ Kl, int ldk,
             const _Float16* __restrict__ Vh, const _Float16* __restrict__ Vl, int ldv,
             _Float16* __restrict__ Oh, _Float16* __restrict__ Ol, int ldo)
{
  __shared__ __align__(16) char Kb[8192];
  __shared__ __align__(16) char Vb[8192];
  __shared__ __align__(16) char Klo[SPLIT ? 8192 : 16];
  __shared__ __align__(16) char Vlo[SPLIT ? 8192 : 16];

  const int t = threadIdx.x;
  const int b = blockIdx.x >> 3, hd = blockIdx.x & 7;
  const int s0 = blockIdx.y * 128;
  const int qoff = hd * DH;
  const int wave = t >> 6, lane = t & 63;
  const int lr = lane & 15, lk = lane >> 4;
  const int krow = t >> 2, kqd = t & 3;
  const int vtp = t & 31, vdc = t >> 5;

  f16x8 qa[2][2], qal[2][2];
#pragma unroll
  for (int qb = 0; qb < 2; ++qb)
#pragma unroll
    for (int kk = 0; kk < 2; ++kk) {
      const int q = s0 + wave*32 + qb*16 + lr;
      const long base = ((long)q*NB + b)*ldq + qoff + kk*32 + lk*8;
      f16x8 v = *(const f16x8*)(Qh + base);
#pragma unroll
      for (int e = 0; e < 8; ++e) v[e] = v[e] * (_Float16)0.125f;
      qa[qb][kk] = v;
      if (SPLIT) {
        f16x8 w = *(const f16x8*)(Ql + base);
#pragma unroll
        for (int e = 0; e < 8; ++e) w[e] = w[e] * (_Float16)0.125f;
        qal[qb][kk] = w;
      }
    }

  float m_run[2] = {-INFINITY, -INFINITY};
  float l_run[2] = {0.f, 0.f};
  f32x4 oaccT[4][2];
#pragma unroll
  for (int nd = 0; nd < 4; ++nd)
#pragma unroll
    for (int qb = 0; qb < 2; ++qb)
#pragma unroll
      for (int e = 0; e < 4; ++e) oaccT[nd][qb][e] = 0.f;

  f16x8 kr0, kr1, krl0, krl1, vr0, vr1, vrl0, vrl1;
  {
    const long kb = ((long)krow*NB + b)*ldk + qoff + kqd*16;
    kr0 = *(const f16x8*)(Kh + kb);
    kr1 = *(const f16x8*)(Kh + kb + 8);
    if (SPLIT) { krl0 = *(const f16x8*)(Kl + kb); krl1 = *(const f16x8*)(Kl + kb + 8); }
    const long vb = ((long)(2*vtp)*NB + b)*ldv + qoff + vdc*8;
    vr0 = *(const f16x8*)(Vh + vb);
    vr1 = *(const f16x8*)(Vh + vb + (long)NB*ldv);
    if (SPLIT) { vrl0 = *(const f16x8*)(Vl + vb); vrl1 = *(const f16x8*)(Vl + vb + (long)NB*ldv); }
  }

  for (int t0 = 0; t0 < S_LEN; t0 += 64) {
    __syncthreads();
    {
      const int sw0 = (kqd*32) ^ ((krow & 7) << 4);
      const int sw1 = (kqd*32 + 16) ^ ((krow & 7) << 4);
      *(f16x8*)(Kb + krow*128 + sw0) = kr0;
      *(f16x8*)(Kb + krow*128 + sw1) = kr1;
      if (SPLIT) {
        *(f16x8*)(Klo + krow*128 + sw0) = krl0;
        *(f16x8*)(Klo + krow*128 + sw1) = krl1;
      }
#pragma unroll
      for (int j = 0; j < 8; ++j) {
        const int dd = vdc*8 + j;
        const int off = dd*128 + ((vtp*4) ^ ((dd & 7) << 4));
        f16x2 hv = {vr0[j], vr1[j]};
        *(f16x2*)(Vb + off) = hv;
        if (SPLIT) {
          f16x2 lv = {vrl0[j], vrl1[j]};
          *(f16x2*)(Vlo + off) = lv;
        }
      }
    }
    if (t0 + 64 < S_LEN) {
      const long kb = ((long)(t0 + 64 + krow)*NB + b)*ldk + qoff + kqd*16;
      kr0 = *(const f16x8*)(Kh + kb);
      kr1 = *(const f16x8*)(Kh + kb + 8);
      if (SPLIT) { krl0 = *(const f16x8*)(Kl + kb); krl1 = *(const f16x8*)(Kl + kb + 8); }
      const long vb = ((long)(t0 + 64 + 2*vtp)*NB + b)*ldv + qoff + vdc*8;
      vr0 = *(const f16x8*)(Vh + vb);
      vr1 = *(const f16x8*)(Vh + vb + (long)NB*ldv);
      if (SPLIT) { vrl0 = *(const f16x8*)(Vl + vb); vrl1 = *(const f16x8*)(Vl + vb + (long)NB*ldv); }
    }
    __syncthreads();

    f32x4 st[4][2];
#pragma unroll
    for (int ki = 0; ki < 4; ++ki)
#pragma unroll
      for (int qb = 0; qb < 2; ++qb)
#pragma unroll
        for (int e = 0; e < 4; ++e) st[ki][qb][e] = 0.f;
#pragma unroll
    for (int kk = 0; kk < 2; ++kk) {
      f16x8 kb[4], kbl[4];
#pragma unroll
      for (int ki = 0; ki < 4; ++ki) {
        const int r = ki*16 + lr;
        const int bo = (lk*16 + kk*64) ^ ((r & 7) << 4);
        kb[ki] = *(const f16x8*)(Kb + r*128 + bo);
        if (SPLIT) kbl[ki] = *(const f16x8*)(Klo + r*128 + bo);
      }
#pragma unroll
      for (int ki = 0; ki < 4; ++ki)
#pragma unroll
        for (int qb = 0; qb < 2; ++qb) {
          st[ki][qb] = __builtin_amdgcn_mfma_f32_16x16x32_f16(kb[ki], qa[qb][kk], st[ki][qb], 0, 0, 0);
          if (SPLIT) {
            st[ki][qb] = __builtin_amdgcn_mfma_f32_16x16x32_f16(kb[ki], qal[qb][kk], st[ki][qb], 0, 0, 0);
            st[ki][qb] = __builtin_amdgcn_mfma_f32_16x16x32_f16(kbl[ki], qa[qb][kk], st[ki][qb], 0, 0, 0);
          }
        }
    }

    f16x4 pbh[4][2], pbl[4][2];
#pragma unroll
    for (int qb = 0; qb < 2; ++qb) {
      float rm = st[0][qb][0];
#pragma unroll
      for (int ki = 0; ki < 4; ++ki)
#pragma unroll
        for (int e = 0; e < 4; ++e) rm = fmaxf(rm, st[ki][qb][e]);
      rm = fmaxf(rm, __shfl_xor(rm, 16));
      rm = fmaxf(rm, __shfl_xor(rm, 32));
      const float mnew = fmaxf(m_run[qb], rm);
      const float corr = __expf(m_run[qb] - mnew);
      m_run[qb] = mnew;
      float ls = 0.f;
#pragma unroll
      for (int ki = 0; ki < 4; ++ki) {
        f16x4 ph, pl;
#pragma unroll
        for (int e = 0; e < 4; ++e) {
          float p = __expf(st[ki][qb][e] - mnew);
          ls += p;
          _Float16 h = (_Float16)p;
          ph[e] = h;
          if (SPLIT) pl[e] = (_Float16)(p - (float)h);
        }
        pbh[ki][qb] = ph;
        if (SPLIT) pbl[ki][qb] = pl;
      }
      ls += __shfl_xor(ls, 16);
      ls += __shfl_xor(ls, 32);
      l_run[qb] = l_run[qb]*corr + ls;
#pragma unroll
      for (int nd = 0; nd < 4; ++nd)
#pragma unroll
        for (int e = 0; e < 4; ++e) oaccT[nd][qb][e] *= corr;
    }

#pragma unroll
    for (int ki = 0; ki < 4; ++ki) {
      f16x4 avh[4], avl[4];
#pragma unroll
      for (int nd = 0; nd < 4; ++nd) {
        const int row = nd*16 + lr;
        const int bo = (ki*32 + lk*8) ^ ((row & 7) << 4);
        avh[nd] = *(const f16x4*)(Vb + row*128 + bo);
        if (SPLIT) avl[nd] = *(const f16x4*)(Vlo + row*128 + bo);
      }
#pragma unroll
      for (int nd = 0; nd < 4; ++nd)
#pragma unroll
        for (int qb = 0; qb < 2; ++qb) {
          oaccT[nd][qb] = __builtin_amdgcn_mfma_f32_16x16x16f16(avh[nd], pbh[ki][qb], oaccT[nd][qb], 0, 0, 0);
          if (SPLIT) {
            oaccT[nd][qb] = __builtin_amdgcn_mfma_f32_16x16x16f16(avh[nd], pbl[ki][qb], oaccT[nd][qb], 0, 0, 0);
            oaccT[nd][qb] = __builtin_amdgcn_mfma_f32_16x16x16f16(avl[nd], pbh[ki][qb], oaccT[nd][qb], 0, 0, 0);
          }
        }
    }
  }

#pragma unroll
  for (int qb = 0; qb < 2; ++qb) {
    const float inv = 1.0f / l_run[qb];
    const int q = s0 + wave*32 + qb*16 + lr;
    const long base = ((long)q * NB + b) * ldo + qoff;
#pragma unroll
    for (int nd = 0; nd < 4; ++nd) {
      f16x4 o, ol;
#pragma unroll
      for (int e = 0; e < 4; ++e) {
        float v = oaccT[nd][qb][e] * inv;
        _Float16 h = (_Float16)v;
        o[e] = h;
        if (SPLIT) ol[e] = (_Float16)(v - (float)h);
      }
      *(f16x4*)(Oh + base + nd*16 + lk*4) = o;
      if (SPLIT) *(f16x4*)(Ol + base + nd*16 + lk*4) = ol;
    }
  }
}

// ---------------------------------------------------------------------------
// DECODER attention: swapped-operand, plain fp16, KV tile 128 (validated r16).
// ---------------------------------------------------------------------------
__global__ __launch_bounds__(256)
void sattn128_k(const _Float16* __restrict__ Qh, int ldq,
                const _Float16* __restrict__ Kh, int ldk,
                const _Float16* __restrict__ Vh, int ldv,
                _Float16* __restrict__ Oh, int ldo)
{
  __shared__ __align__(16) char Kb[16384];
  __shared__ __align__(16) char Vb[16384];

  const int t = threadIdx.x;
  const int b = blockIdx.x >> 3, hd = blockIdx.x & 7;
  const int s0 = blockIdx.y * 128;
  const int qoff = hd * DH;
  const int wave = t >> 6, lane = t & 63;
  const int lr = lane & 15, lk = lane >> 4;
  const int krow = t >> 1, kpart = t & 1;
  const int vtp = t & 63, vdc = t >> 6;

  f16x8 qa[2][2];
#pragma unroll
  for (int qb = 0; qb < 2; ++qb)
#pragma unroll
    for (int kk = 0; kk < 2; ++kk) {
      const int q = s0 + wave*32 + qb*16 + lr;
      const long base = ((long)q*NB + b)*ldq + qoff + kk*32 + lk*8;
      f16x8 v = *(const f16x8*)(Qh + base);
#pragma unroll
      for (int e = 0; e < 8; ++e) v[e] = v[e] * (_Float16)0.125f;
      qa[qb][kk] = v;
    }

  float m_run[2] = {-INFINITY, -INFINITY};
  float l_run[2] = {0.f, 0.f};
  f32x4 oaccT[4][2];
#pragma unroll
  for (int nd = 0; nd < 4; ++nd)
#pragma unroll
    for (int qb = 0; qb < 2; ++qb)
#pragma unroll
      for (int e = 0; e < 4; ++e) oaccT[nd][qb][e] = 0.f;

  f16x8 kr[4], vrA[2], vrB[2];
  {
    const long kb = ((long)krow*NB + b)*ldk + qoff + kpart*32;
#pragma unroll
    for (int g = 0; g < 4; ++g) kr[g] = *(const f16x8*)(Kh + kb + g*8);
    const long vb = ((long)(2*vtp)*NB + b)*ldv + qoff + vdc*16;
    vrA[0] = *(const f16x8*)(Vh + vb);
    vrA[1] = *(const f16x8*)(Vh + vb + 8);
    vrB[0] = *(const f16x8*)(Vh + vb + (long)NB*ldv);
    vrB[1] = *(const f16x8*)(Vh + vb + (long)NB*ldv + 8);
  }

  for (int t0 = 0; t0 < S_LEN; t0 += 128) {
    __syncthreads();
    {
#pragma unroll
      for (int g = 0; g < 4; ++g) {
        const int sw = (kpart*64 + g*16) ^ ((krow & 7) << 4);
        *(f16x8*)(Kb + krow*128 + sw) = kr[g];
      }
#pragma unroll
      for (int h = 0; h < 2; ++h)
#pragma unroll
        for (int j = 0; j < 8; ++j) {
          const int dd = vdc*16 + h*8 + j;
          const int off = dd*256 + ((vtp*4) ^ ((dd & 7) << 4));
          f16x2 hv = {vrA[h][j], vrB[h][j]};
          *(f16x2*)(Vb + off) = hv;
        }
    }
    if (t0 + 128 < S_LEN) {
      const long kb = ((long)(t0 + 128 + krow)*NB + b)*ldk + qoff + kpart*32;
#pragma unroll
      for (int g = 0; g < 4; ++g) kr[g] = *(const f16x8*)(Kh + kb + g*8);
      const long vb = ((long)(t0 + 128 + 2*vtp)*NB + b)*ldv + qoff + vdc*16;
      vrA[0] = *(const f16x8*)(Vh + vb);
      vrA[1] = *(const f16x8*)(Vh + vb + 8);
      vrB[0] = *(const f16x8*)(Vh + vb + (long)NB*ldv);
      vrB[1] = *(const f16x8*)(Vh + vb + (long)NB*ldv + 8);
    }
    __syncthreads();

    f32x4 st[8][2];
#pragma unroll
    for (int ki = 0; ki < 8; ++ki)
#pragma unroll
      for (int qb = 0; qb < 2; ++qb)
#pragma unroll
        for (int e = 0; e < 4; ++e) st[ki][qb][e] = 0.f;
#pragma unroll
    for (int kk = 0; kk < 2; ++kk) {
#pragma unroll
      for (int ki = 0; ki < 8; ++ki) {
        const int r = ki*16 + lr;
        const int bo = (lk*16 + kk*64) ^ ((r & 7) << 4);
        f16x8 kbv = *(const f16x8*)(Kb + r*128 + bo);
#pragma unroll
        for (int qb = 0; qb < 2; ++qb)
          st[ki][qb] = __builtin_amdgcn_mfma_f32_16x16x32_f16(kbv, qa[qb][kk], st[ki][qb], 0, 0, 0);
      }
    }

    f16x4 pbh[8][2];
#pragma unroll
    for (int qb = 0; qb < 2; ++qb) {
      float rm = st[0][qb][0];
#pragma unroll
      for (int ki = 0; ki < 8; ++ki)
#pragma unroll
        for (int e = 0; e < 4; ++e) rm = fmaxf(rm, st[ki][qb][e]);
      rm = fmaxf(rm, __shfl_xor(rm, 16));
      rm = fmaxf(rm, __shfl_xor(rm, 32));
      const float mnew = fmaxf(m_run[qb], rm);
      const float corr = __expf(m_run[qb] - mnew);
      m_run[qb] = mnew;
      float ls = 0.f;
#pragma unroll
      for (int ki = 0; ki < 8; ++ki) {
        f16x4 ph;
#pragma unroll
        for (int e = 0; e < 4; ++e) {
          float p = __expf(st[ki][qb][e] - mnew);
          ls += p;
          ph[e] = (_Float16)p;
        }
        pbh[ki][qb] = ph;
      }
      ls += __shfl_xor(ls, 16);
      ls += __shfl_xor(ls, 32);
      l_run[qb] = l_run[qb]*corr + ls;
#pragma unroll
      for (int nd = 0; nd < 4; ++nd)
#pragma unroll
        for (int e = 0; e < 4; ++e) oaccT[nd][qb][e] *= corr;
    }

#pragma unroll
    for (int ki = 0; ki < 8; ++ki) {
#pragma unroll
      for (int nd = 0; nd < 4; ++nd) {
        const int row = nd*16 + lr;
        const int bo = (ki*32 + lk*8) ^ ((row & 7) << 4);
        f16x4 av = *(const f16x4*)(Vb + row*256 + bo);
#pragma unroll
        for (int qb = 0; qb < 2; ++qb)
          oaccT[nd][qb] = __builtin_amdgcn_mfma_f32_16x16x16f16(av, pbh[ki][qb], oaccT[nd][qb], 0, 0, 0);
      }
    }
  }

#pragma unroll
  for (int qb = 0; qb < 2; ++qb) {
    const float inv = 1.0f / l_run[qb];
    const int q = s0 + wave*32 + qb*16 + lr;
    const long base = ((long)q * NB + b) * ldo + qoff;
#pragma unroll
    for (int nd = 0; nd < 4; ++nd) {
      f16x4 o;
#pragma unroll
      for (int e = 0; e < 4; ++e) o[e] = (_Float16)(oaccT[nd][qb][e] * inv);
      *(f16x4*)(Oh + base + nd*16 + lk*4) = o;
    }
  }
}

// ---------------------------------------------------------------------------
// LayerNorm over c=512, one wave per row.
// ES: 0 fp32; 1 fp32+hi+lo; 2 fp32+hi; 3 hi+lo only; 4 hi only.
// ---------------------------------------------------------------------------
template<int ES>
__global__ __launch_bounds__(256)
void ln_k(const float* __restrict__ X, const float* __restrict__ g,
          const float* __restrict__ bb, float* __restrict__ Y,
          _Float16* __restrict__ Yh, _Float16* __restrict__ Yl)
{
  const int t = threadIdx.x;
  const int lane = t & 63;
  const long row = (long)blockIdx.x * 4 + (t >> 6);
  const float* xr = X + row * CDIM;
  float4 v0 = *(const float4*)(xr + lane*4);
  float4 v1 = *(const float4*)(xr + 256 + lane*4);
  float s = v0.x+v0.y+v0.z+v0.w + v1.x+v1.y+v1.z+v1.w;
#pragma unroll
  for (int off = 1; off < 64; off <<= 1) s += __shfl_xor(s, off);
  const float mean = s * (1.0f/512.0f);
  float d[8] = {v0.x-mean, v0.y-mean, v0.z-mean, v0.w-mean,
                v1.x-mean, v1.y-mean, v1.z-mean, v1.w-mean};
  float sq = d[0]*d[0]+d[1]*d[1]+d[2]*d[2]+d[3]*d[3]
           + d[4]*d[4]+d[5]*d[5]+d[6]*d[6]+d[7]*d[7];
#pragma unroll
  for (int off = 1; off < 64; off <<= 1) sq += __shfl_xor(sq, off);
  const float inv = 1.0f / sqrtf(sq * (1.0f/512.0f) + 1e-5f);
  float4 g0 = *(const float4*)(g + lane*4);
  float4 g1 = *(const float4*)(g + 256 + lane*4);
  float4 b0 = *(const float4*)(bb + lane*4);
  float4 b1 = *(const float4*)(bb + 256 + lane*4);
  float o[8];
  o[0] = d[0]*inv*g0.x + b0.x; o[1] = d[1]*inv*g0.y + b0.y;
  o[2] = d[2]*inv*g0.z + b0.z; o[3] = d[3]*inv*g0.w + b0.w;
  o[4] = d[4]*inv*g1.x + b1.x; o[5] = d[5]*inv*g1.y + b1.y;
  o[6] = d[6]*inv*g1.z + b1.z; o[7] = d[7]*inv*g1.w + b1.w;
  if (ES <= 2) {
    *(float4*)(Y + row*CDIM + lane*4) = *(float4*)&o[0];
    *(float4*)(Y + row*CDIM + 256 + lane*4) = *(float4*)&o[4];
  }
  if (ES >= 1) {
    f16x4 h0, h1, l0, l1;
#pragma unroll
    for (int j = 0; j < 4; ++j) {
      _Float16 h = (_Float16)o[j];     h0[j] = h;
      _Float16 k = (_Float16)o[4+j];   h1[j] = k;
      if (ES == 1 || ES == 3) { l0[j] = (_Float16)(o[j] - (float)h); l1[j] = (_Float16)(o[4+j] - (float)k); }
    }
    *(f16x4*)(Yh + row*CDIM + lane*4) = h0;
    *(f16x4*)(Yh + row*CDIM + 256 + lane*4) = h1;
    if (ES == 1 || ES == 3) {
      *(f16x4*)(Yl + row*CDIM + lane*4) = l0;
      *(f16x4*)(Yl + row*CDIM + 256 + lane*4) = l1;
    }
  }
}

// ---------------------------------------------------------------------------
// Pack x (N,C,H,W) -> enc_flat (S,n,c); posisted as split fp16 hi/lo only.
// ---------------------------------------------------------------------------
__global__ void pack_pe_k(const float* __restrict__ x, float* __restrict__ encf,
                          _Float16* __restrict__ posh, _Float16* __restrict__ posl)
{
  __shared__ float tl[32][33];
  const int b = blockIdx.z;
  const int s0 = blockIdx.x*32, c0 = blockIdx.y*32;
#pragma unroll
  for (int i = 0; i < 4; ++i) {
    int ci = threadIdx.y + i*8;
    tl[ci][threadIdx.x] = x[((long)b*CDIM + c0+ci)*S_LEN + s0 + threadIdx.x];
  }
  __syncthreads();
#pragma unroll
  for (int i = 0; i < 4; ++i) {
    int si = threadIdx.y + i*8;
    int s = s0 + si;
    int ch = c0 + threadIdx.x;
    float val = tl[threadIdx.x][si];
    long o = ((long)s*NB + b)*CDIM + ch;
    encf[o] = val;
    int pos = (ch < 256) ? (s & 31) : (s >> 5);
    int j = (ch & 255) >> 1;
    float dv = expf((float)(2*j) * (-9.210340371976184f / 256.0f));
    float ang = (float)pos * dv;
    float pe = (ch & 1) ? cosf(ang) : sinf(ang);
    float pv = val + pe;
    _Float16 h = (_Float16)pv;
    posh[o] = h;
    posl[o] = (_Float16)(pv - (float)h);
  }
}

// (S,n,c) token-major -> (n,c,S) output layout
__global__ void tpose_k(const float* __restrict__ in, float* __restrict__ out)
{
  __shared__ float tl[32][33];
  const int b = blockIdx.z;
  const int s0 = blockIdx.x*32, c0 = blockIdx.y*32;
#pragma unroll
  for (int i = 0; i < 4; ++i) {
    int si = threadIdx.y + i*8;
    tl[si][threadIdx.x] = in[((long)(s0+si)*NB + b)*CDIM + c0 + threadIdx.x];
  }
  __syncthreads();
#pragma unroll
  for (int i = 0; i < 4; ++i) {
    int ci = threadIdx.y + i*8;
    out[((long)b*CDIM + c0+ci)*S_LEN + s0 + threadIdx.x] = tl[threadIdx.x][ci];
  }
}

// cb_w (c,K) -> transposed split-fp16 codebook [K][c] hi/lo
__global__ void cbt16_k(const float* __restrict__ cb,
                        _Float16* __restrict__ outh, _Float16* __restrict__ outl)
{
  __shared__ float tl[32][33];
  const int k0 = blockIdx.x*32, c0 = blockIdx.y*32;
#pragma unroll
  for (int i = 0; i < 4; ++i) {
    int ci = threadIdx.y + i*8;
    tl[ci][threadIdx.x] = cb[(long)(c0+ci)*KCB + k0 + threadIdx.x];
  }
  __syncthreads();
#pragma unroll
  for (int i = 0; i < 4; ++i) {
    int ki = threadIdx.y + i*8;
    float v = tl[threadIdx.x][ki];
    _Float16 h = (_Float16)v;
    outh[(long)(k0+ki)*CDIM + c0 + threadIdx.x] = h;
    outl[(long)(k0+ki)*CDIM + c0 + threadIdx.x] = (_Float16)(v - (float)h);
  }
}

// fp32 -> fp16 elementwise, 8 per thread
__global__ __launch_bounds__(256)
void conv16_k(const float* __restrict__ in, _Float16* __restrict__ out)
{
  const long i = ((long)blockIdx.x * 256 + threadIdx.x) * 8;
  float4 v0 = *(const float4*)(in + i);
  float4 v1 = *(const float4*)(in + i + 4);
  f16x8 h;
  h[0]=(_Float16)v0.x; h[1]=(_Float16)v0.y; h[2]=(_Float16)v0.z; h[3]=(_Float16)v0.w;
  h[4]=(_Float16)v1.x; h[5]=(_Float16)v1.y; h[6]=(_Float16)v1.z; h[7]=(_Float16)v1.w;
  *(f16x8*)(out + i) = h;
}

// fp32 -> split fp16 hi/lo, 8 per thread
__global__ __launch_bounds__(256)
void convsplit_k(const float* __restrict__ in, _Float16* __restrict__ oh,
                 _Float16* __restrict__ ol)
{
  const long i = ((long)blockIdx.x * 256 + threadIdx.x) * 8;
  float4 v0 = *(const float4*)(in + i);
  float4 v1 = *(const float4*)(in + i + 4);
  float vv[8] = {v0.x,v0.y,v0.z,v0.w,v1.x,v1.y,v1.z,v1.w};
  f16x8 h, l;
#pragma unroll
  for (int j = 0; j < 8; ++j) {
    _Float16 hh = (_Float16)vv[j];
    h[j] = hh;
    l[j] = (_Float16)(vv[j] - (float)hh);
  }
  *(f16x8*)(oh + i) = h;
  *(f16x8*)(ol + i) = l;
}

// Per-token row of logits: argmax (np first-occurrence) + write P (fp16)
__global__ __launch_bounds__(256)
void simstats_k(const float* __restrict__ logits, _Float16* __restrict__ Pbuf,
                int* __restrict__ codes_tok, float* __restrict__ codes_out)
{
  const long phys = blockIdx.x;
  const float* rowp = logits + phys * KCB;
  const int t = threadIdx.x;
  float vals[16];
#pragma unroll
  for (int rep = 0; rep < 4; ++rep) {
    float4 v = *(const float4*)(rowp + rep*1024 + t*4);
    vals[rep*4+0]=v.x; vals[rep*4+1]=v.y; vals[rep*4+2]=v.z; vals[rep*4+3]=v.w;
  }
  float mv = -INFINITY; int mi = 0;
#pragma unroll
  for (int rep = 0; rep < 4; ++rep)
#pragma unroll
    for (int j = 0; j < 4; ++j) {
      float xv = vals[rep*4+j];
      int ix = rep*1024 + t*4 + j;
      if (xv > mv) { mv = xv; mi = ix; }
    }
  const int lane = t & 63, wid = t >> 6;
#pragma unroll
  for (int off = 1; off < 64; off <<= 1) {
    float ov = __shfl_xor(mv, off);
    int   oi = __shfl_xor(mi, off);
    if (ov > mv || (ov == mv && oi < mi)) { mv = ov; mi = oi; }
  }
  __shared__ float smax[4]; __shared__ int sidx[4]; __shared__ float ssum[4];
  __shared__ float fm; __shared__ int fi; __shared__ float sinv;
  if (lane == 0) { smax[wid] = mv; sidx[wid] = mi; }
  __syncthreads();
  if (t == 0) {
    float bm = smax[0]; int bi = sidx[0];
    for (int wq = 1; wq < 4; ++wq)
      if (smax[wq] > bm || (smax[wq] == bm && sidx[wq] < bi)) { bm = smax[wq]; bi = sidx[wq]; }
    fm = bm; fi = bi;
  }
  __syncthreads();
  const float Mx = fm;
  float se = 0.f;
#pragma unroll
  for (int q = 0; q < 16; ++q) se += __expf(vals[q] - Mx);
#pragma unroll
  for (int off = 1; off < 64; off <<= 1) se += __shfl_xor(se, off);
  if (lane == 0) ssum[wid] = se;
  __syncthreads();
  const int b = (int)(phys >> 10), s = (int)(phys & 1023);
  if (t == 0) {
    float tot = ssum[0]+ssum[1]+ssum[2]+ssum[3];
    sinv = 1.0f / tot;
    codes_tok[s*NB + b] = fi;
    codes_out[phys] = (float)fi;
  }
  __syncthreads();
  const float inv = sinv;
  _Float16* prow = Pbuf + ((long)s*NB + b) * KCB;
#pragma unroll
  for (int rep = 0; rep < 4; ++rep) {
    f16x4 pv;
#pragma unroll
    for (int j = 0; j < 4; ++j) pv[j] = (_Float16)(__expf(vals[rep*4+j] - Mx) * inv);
    *(f16x4*)(prow + rep*1024 + t*4) = pv;
  }
}

// quant = (hard - soft) + soft; emit hard fp32 and quant fp32 + fp16-hi.
__global__ __launch_bounds__(128)
void quant_k(const float* __restrict__ soft, const int* __restrict__ codes_tok,
             const _Float16* __restrict__ cbh, const _Float16* __restrict__ cbl,
             float* __restrict__ quant, float* __restrict__ hardb,
             _Float16* __restrict__ qh16)
{
  const int r = blockIdx.x;
  const int code = codes_tok[r];
  const int c = threadIdx.x * 4;
  f16x4 hh = *(const f16x4*)(cbh + (long)code*CDIM + c);
  f16x4 hl = *(const f16x4*)(cbl + (long)code*CDIM + c);
  float4 sf = *(const float4*)(soft + (long)r*CDIM + c);
  float4 h, q;
  h.x = (float)hh[0] + (float)hl[0]; h.y = (float)hh[1] + (float)hl[1];
  h.z = (float)hh[2] + (float)hl[2]; h.w = (float)hh[3] + (float)hl[3];
  q.x = (h.x - sf.x) + sf.x; q.y = (h.y - sf.y) + sf.y;
  q.z = (h.z - sf.z) + sf.z; q.w = (h.w - sf.w) + sf.w;
  *(float4*)(quant + (long)r*CDIM + c) = q;
  *(float4*)(hardb + (long)r*CDIM + c) = h;
  f16x4 qh = {(_Float16)q.x, (_Float16)q.y, (_Float16)q.z, (_Float16)q.w};
  *(f16x4*)(qh16 + (long)r*CDIM + c) = qh;
}

// Detect the storage format of the bool mask buffer.
__global__ void maskdetect_k(const void* __restrict__ mask, int* __restrict__ flag)
{
  const unsigned int* wds = (const unsigned int*)mask;
  int t = threadIdx.x;
  int okI = 1, okF = 1, okL = 1;
  for (int i = t; i < 2048; i += 256) {
    unsigned int u = wds[i];
    if (u > 1u) okI = 0;
    if (u != 0u && u != 0x3F800000u) okF = 0;
    if ((i & 1) ? (u != 0u) : (u > 1u)) okL = 0;
  }
  __shared__ int sI, sF, sL;
  if (t == 0) { sI = 1; sF = 1; sL = 1; }
  __syncthreads();
  if (!okI) atomicAnd(&sI, 0);
  if (!okF) atomicAnd(&sF, 0);
  if (!okL) atomicAnd(&sL, 0);
  __syncthreads();
  if (t == 0) {
    int f;
    if (sI && sL) f = 3;
    else if (sI)  f = 1;
    else if (sF)  f = 2;
    else          f = 0;
    *flag = f;
  }
}

// mixed = mask ? enc_flat : post; fp32 + fp16-hi outputs
__global__ __launch_bounds__(256)
void mixed_k(const float* __restrict__ encf, const float* __restrict__ post,
             const void* __restrict__ mask, const int* __restrict__ flag,
             float* __restrict__ outx, _Float16* __restrict__ outh)
{
  long gid = (long)blockIdx.x * blockDim.x + threadIdx.x;
  int r = (int)(gid >> 7);
  int c = (int)(gid & 127) * 4;
  int f = *flag;
  bool mv;
  if (f == 0)      mv = ((const unsigned char*)mask)[r] != 0;
  else if (f == 1) mv = ((const int*)mask)[r] != 0;
  else if (f == 3) mv = ((const long long*)mask)[r] != 0;
  else             mv = ((const float*)mask)[r] != 0.0f;
  const float* src = mv ? encf : post;
  float4 v = *(const float4*)(src + (long)r*CDIM + c);
  *(float4*)(outx + (long)r*CDIM + c) = v;
  f16x4 h = {(_Float16)v.x, (_Float16)v.y, (_Float16)v.z, (_Float16)v.w};
  *(f16x4*)(outh + (long)r*CDIM + c) = h;
}

extern "C" void kernel_launch(void* const* d_in, const int* in_sizes, int n_in,
                              void* d_out, int out_size, void* d_ws, size_t ws_size,
                              hipStream_t stream)
{
  const float* x       = (const float*)d_in[0];
  const float* pre_w   = (const float*)d_in[1];
  const float* pre_b   = (const float*)d_in[2];
  const float* post_w  = (const float*)d_in[3];
  const float* post_b  = (const float*)d_in[4];
  const float* cb_w    = (const float*)d_in[5];
  const float* e_qkv_w = (const float*)d_in[6];
  const float* e_qkv_b = (const float*)d_in[7];
  const float* e_o_w   = (const float*)d_in[8];
  const float* e_o_b   = (const float*)d_in[9];
  const float* e_ln1_w = (const float*)d_in[10];
  const float* e_ln1_b = (const float*)d_in[11];
  const float* e_ln2_w = (const float*)d_in[12];
  const float* e_ln2_b = (const float*)d_in[13];
  const float* e_f1_w  = (const float*)d_in[14];
  const float* e_f1_b  = (const float*)d_in[15];
  const float* e_f2_w  = (const float*)d_in[16];
  const float* e_f2_b  = (const float*)d_in[17];
  const float* d_sqkv_w= (const float*)d_in[18];
  const float* d_sqkv_b= (const float*)d_in[19];
  const float* d_so_w  = (const float*)d_in[20];
  const float* d_so_b  = (const float*)d_in[21];
  const float* d_cqkv_w= (const float*)d_in[22];
  const float* d_cqkv_b= (const float*)d_in[23];
  const float* d_co_w  = (const float*)d_in[24];
  const float* d_co_b  = (const float*)d_in[25];
  const float* d_ln1w  = (const float*)d_in[26];
  const float* d_ln1b  = (const float*)d_in[27];
  const float* d_ln2w  = (const float*)d_in[28];
  const float* d_ln2b  = (const float*)d_in[29];
  const float* d_ln3w  = (const float*)d_in[30];
  const float* d_ln3b  = (const float*)d_in[31];
  const float* d_f1w   = (const float*)d_in[32];
  const float* d_f1b   = (const float*)d_in[33];
  const float* d_f2w   = (const float*)d_in[34];
  const float* d_f2b   = (const float*)d_in[35];
  const void*  mask    = d_in[36];

  float* out = (float*)d_out;
  float* o_quant  = out;
  float* o_high   = out + 4194304;
  float* o_softs  = out + 8388608;
  float* o_hards  = out + 12582912;
  float* o_codes  = out + 16777216;
  float* o_logits = out + 16785408;

  float* ws    = (float*)d_ws;
  float* ENC   = ws;
  float* Xb    = ws + TOKC;
  float* T1    = ws + 2*TOKC;
  float* T2    = ws + 3*TOKC;
  float* QKV   = ws + 4*TOKC;
  float* MEMB  = ws + 7*TOKC;
  float* CBREG = ws + 8*TOKC;
  int*   CODES = (int*)(CBREG + (long)KCB*CDIM);
  int*   FLAG  = CODES + NTOK;
  float* HARDB = QKV;
  float* QUANT = QKV + TOKC;
  _Float16* PBUF = (_Float16*)QKV;
  _Float16* CBH  = (_Float16*)T1;
  _Float16* QKVh = (_Float16*)QKV;
  _Float16* QKVl = QKVh + (long)NTOK*3*CDIM;
  _Float16* CQh  = (_Float16*)QKV;
  _Float16* KVh  = (_Float16*)(QKV + TOKC);
  _Float16* CBT16h = (_Float16*)CBREG;
  _Float16* CBT16l = CBT16h + (long)KCB*CDIM;
  _Float16* PREH = (_Float16*)T2;
  _Float16* PREL = PREH + TOKC;
  _Float16* AH16   = (_Float16*)ENC;
  _Float16* FH16   = AH16 + TOKC;
  _Float16* XH16   = ((_Float16*)QKV) + 4*TOKC;
  _Float16* MEMBH16= XH16 + TOKC;
  _Float16* QH16   = ((_Float16*)T1) + TOKC;

  const long WQSZ = (long)6*3*CDIM*CDIM;
  const long WSSZ = (long)6*CDIM*CDIM;
  _Float16* SCR  = (_Float16*)o_logits;
  _Float16* WQH = SCR;            _Float16* WQL = WQH + WQSZ;
  _Float16* WOH = WQL + WQSZ;     _Float16* WOL = WOH + WSSZ;
  _Float16* WF1H= WOL + WSSZ;     _Float16* WF1L= WF1H + WSSZ;
  _Float16* WF2H= WF1L + WSSZ;    _Float16* WF2L= WF2H + WSSZ;
  _Float16* WPH = WF2L + WSSZ;    _Float16* WPL = WPH + (long)CDIM*CDIM;
  _Float16* XH  = WPL + (long)CDIM*CDIM;  _Float16* XL  = XH + TOKC;
  _Float16* AH  = XL + TOKC;      _Float16* AL  = AH + TOKC;
  _Float16* L1H = AL + TOKC;      _Float16* L1L = L1H + TOKC;
  _Float16* H1H = L1L + TOKC;     _Float16* H1L = H1H + TOKC;

  _Float16* DWSQ = (_Float16*)MEMB;
  _Float16* DWCQ = (_Float16*)T1;
  _Float16* DWF1 = DWCQ + WQSZ;
  _Float16* DWF2 = DWF1 + WSSZ;
  _Float16* DWSO = (_Float16*)CBREG;
  _Float16* DWCO = DWSO + WSSZ;

  const size_t NEED = (size_t)(8*TOKC + (long)KCB*CDIM + 2*NTOK + NTOK + 16) * 4;
  if (ws_size < NEED) return;

  const int M = NTOK;
  dim3 tgrid(S_LEN/32, CDIM/32, NB), tblk(32, 8);
  dim3 agrid(NB*8, S_LEN/128);

  pack_pe_k<<<tgrid, tblk, 0, stream>>>(x, ENC, XH, XL);
  cbt16_k<<<dim3(KCB/32, CDIM/32), tblk, 0, stream>>>(cb_w, CBT16h, CBT16l);
  maskdetect_k<<<1, 256, 0, stream>>>(mask, FLAG);
  convsplit_k<<<(int)(WQSZ/2048), 256, 0, stream>>>(e_qkv_w, WQH, WQL);
  convsplit_k<<<(int)(WSSZ/2048), 256, 0, stream>>>(e_o_w,  WOH,  WOL);
  convsplit_k<<<(int)(WSSZ/2048), 256, 0, stream>>>(e_f1_w, WF1H, WF1L);
  convsplit_k<<<(int)(WSSZ/2048), 256, 0, stream>>>(e_f2_w, WF2H, WF2L);
  convsplit_k<<<(int)(((long)CDIM*CDIM)/2048), 256, 0, stream>>>(pre_w, WPH, WPL);

  // -------- encoder (split-fp16 MFMA; residuals via hi+lo reconstruction) ----
  for (int i = 0; i < NLAYER; ++i) {
    hgemm_k<128,1,2,true,0,false,false,true><<<dim3(3*CDIM/128, M/128), 256, 0, stream>>>(
        XH, WQH + (long)i*3*CDIM*CDIM, e_qkv_b + i*3*CDIM, nullptr, 0,
        nullptr, 3*CDIM, M, 3*CDIM, CDIM, QKVh, QKVl, XL, WQL + (long)i*3*CDIM*CDIM,
        nullptr, nullptr);
    sattn_k<1><<<agrid, 256, 0, stream>>>(QKVh, QKVl, 3*CDIM,
        QKVh+CDIM, QKVl+CDIM, 3*CDIM, QKVh+2*CDIM, QKVl+2*CDIM, 3*CDIM,
        AH, AL, CDIM);
    hgemm_k<64,1,2,true,3,false,false,false><<<dim3(CDIM/128, M/64), 256, 0, stream>>>(
        AH, WOH + (long)i*CDIM*CDIM, e_o_b + i*CDIM, nullptr, CDIM,
        T2, CDIM, M, CDIM, CDIM, nullptr, nullptr, AL, WOL + (long)i*CDIM*CDIM,
        XH, XL);
    ln_k<3><<<M/4, 256, 0, stream>>>(T2, e_ln1_w + i*CDIM, e_ln1_b + i*CDIM, nullptr, L1H, L1L);
    hgemm_k<64,1,2,true,0,true,false,true><<<dim3(CDIM/128, M/64), 256, 0, stream>>>(
        L1H, WF1H + (long)i*CDIM*CDIM, e_f1_b + i*CDIM, nullptr, 0,
        nullptr, CDIM, M, CDIM, CDIM, H1H, H1L, L1L, WF1L + (long)i*CDIM*CDIM,
        nullptr, nullptr);
    hgemm_k<64,1,2,true,3,false,false,false><<<dim3(CDIM/128, M/64), 256, 0, stream>>>(
        H1H, WF2H + (long)i*CDIM*CDIM, e_f2_b + i*CDIM, nullptr, CDIM,
        T2, CDIM, M, CDIM, CDIM, nullptr, nullptr, H1L, WF2L + (long)i*CDIM*CDIM,
        L1H, L1L);
    ln_k<3><<<M/4, 256, 0, stream>>>(T2, e_ln2_w + i*CDIM, e_ln2_b + i*CDIM, nullptr, XH, XL);
  }

  // -------- codebook / quantizer --------
  hgemm_k<64,1,2,true,0,false,false,true><<<dim3(CDIM/128, M/64), 256, 0, stream>>>(
      XH, WPH, pre_b, nullptr, 0, T1, CDIM, M, CDIM, CDIM, PREH, PREL, XL, WPL,
      nullptr, nullptr);
  tpose_k<<<tgrid, tblk, 0, stream>>>(T1, o_high);
  hgemm_k<128,1,2,false,0,false,true,false><<<dim3(KCB/128, M/128), 256, 0, stream>>>(
      PREH, CBT16h, nullptr, nullptr, 0, o_logits, KCB, M, KCB, CDIM,
      nullptr, nullptr, PREL, CBT16l, nullptr, nullptr);
  conv16_k<<<(CDIM*(long)KCB)/(256*8), 256, 0, stream>>>(cb_w, CBH);
  simstats_k<<<NTOK, 256, 0, stream>>>(o_logits, PBUF, CODES, o_codes);
  hgemm_k<64,0,1,false,0,false,false,false><<<dim3(CDIM/128, M/64), 256, 0, stream>>>(
      PBUF, CBH, nullptr, nullptr, 0, T2, CDIM, M, CDIM, KCB,
      nullptr, nullptr, nullptr, nullptr, nullptr, nullptr);                 // soft
  tpose_k<<<tgrid, tblk, 0, stream>>>(T2, o_softs);
  quant_k<<<NTOK, 128, 0, stream>>>(T2, CODES, CBT16h, CBT16l, QUANT, HARDB, QH16);
  tpose_k<<<tgrid, tblk, 0, stream>>>(HARDB, o_hards);
  conv16_k<<<(int)(WSSZ/2048), 256, 0, stream>>>(d_so_w, DWSO);
  conv16_k<<<(int)(WSSZ/2048), 256, 0, stream>>>(d_co_w, DWCO);
  hgemm_k<64,0,3,true,0,false,false,true><<<dim3(CDIM/128, M/64), 256, 0, stream>>>(
      QH16, post_w, post_b, nullptr, 0, MEMB, CDIM, M, CDIM, CDIM,
      MEMBH16, nullptr, nullptr, nullptr, nullptr, nullptr);                 // post
  conv16_k<<<(int)(WQSZ/2048), 256, 0, stream>>>(d_cqkv_w, DWCQ);
  conv16_k<<<(int)(WSSZ/2048), 256, 0, stream>>>(d_f1w, DWF1);
  conv16_k<<<(int)(WSSZ/2048), 256, 0, stream>>>(d_f2w, DWF2);
  mixed_k<<<4096, 256, 0, stream>>>(ENC, MEMB, mask, FLAG, Xb, XH16);
  conv16_k<<<(int)(WQSZ/2048), 256, 0, stream>>>(d_sqkv_w, DWSQ);

  // -------- decoder (f16 MFMA; residuals via fp16-hi reconstruction) --------
  for (int i = 0; i < NLAYER; ++i) {
    hgemm_k<128,0,1,true,0,false,false,true><<<dim3(3*CDIM/128, M/128), 256, 0, stream>>>(
        XH16, DWSQ + (long)i*3*CDIM*CDIM, d_sqkv_b + i*3*CDIM, nullptr, 0,
        nullptr, 3*CDIM, M, 3*CDIM, CDIM, QKVh, nullptr, nullptr, nullptr,
        nullptr, nullptr);
    sattn128_k<<<agrid, 256, 0, stream>>>(QKVh, 3*CDIM,
        QKVh+CDIM, 3*CDIM, QKVh+2*CDIM, 3*CDIM, AH16, CDIM);
    hgemm_k<64,0,1,true,2,false,false,false><<<dim3(CDIM/128, M/64), 256, 0, stream>>>(
        AH16, DWSO + (long)i*CDIM*CDIM, d_so_b + i*CDIM, nullptr, CDIM,
        T2, CDIM, M, CDIM, CDIM, nullptr, nullptr, nullptr, nullptr,
        XH16, nullptr);
    ln_k<4><<<M/4, 256, 0, stream>>>(T2, d_ln1w + i*CDIM, d_ln1b + i*CDIM, nullptr, XH16, nullptr);
    hgemm_k<64,0,1,true,0,false,false,true><<<dim3(CDIM/128, M/64), 256, 0, stream>>>(
        XH16, DWCQ + (long)i*3*CDIM*CDIM, d_cqkv_b + i*3*CDIM, nullptr, 0,
        nullptr, CDIM, M, CDIM, CDIM, CQh, nullptr, nullptr, nullptr,
        nullptr, nullptr);
    hgemm_k<128,0,1,true,0,false,false,true><<<dim3(2*CDIM/128, M/128), 256, 0, stream>>>(
        MEMBH16, DWCQ + (long)i*3*CDIM*CDIM + (long)CDIM*CDIM,
        d_cqkv_b + i*3*CDIM + CDIM, nullptr, 0,
        nullptr, 2*CDIM, M, 2*CDIM, CDIM, KVh, nullptr, nullptr, nullptr,
        nullptr, nullptr);
    sattn128_k<<<agrid, 256, 0, stream>>>(CQh, CDIM,
        KVh, 2*CDIM, KVh+CDIM, 2*CDIM, AH16, CDIM);
    hgemm_k<64,0,1,true,2,false,false,false><<<dim3(CDIM/128, M/64), 256, 0, stream>>>(
        AH16, DWCO + (long)i*CDIM*CDIM, d_co_b + i*CDIM, nullptr, CDIM,
        T2, CDIM, M, CDIM, CDIM, nullptr, nullptr, nullptr, nullptr,
        XH16, nullptr);
    ln_k<4><<<M/4, 256, 0, stream>>>(T2, d_ln2w + i*CDIM, d_ln2b + i*CDIM, nullptr, XH16, nullptr);
    hgemm_k<64,0,1,true,0,true,false,true><<<dim3(CDIM/128, M/64), 256, 0, stream>>>(
        XH16, DWF1 + (long)i*CDIM*CDIM, d_f1b + i*CDIM, nullptr, 0,
        nullptr, CDIM, M, CDIM, CDIM, FH16, nullptr, nullptr, nullptr,
        nullptr, nullptr);
    hgemm_k<64,0,1,true,2,false,false,false><<<dim3(CDIM/128, M/64), 256, 0, stream>>>(
        FH16, DWF2 + (long)i*CDIM*CDIM, d_f2b + i*CDIM, nullptr, CDIM,
        T2, CDIM, M, CDIM, CDIM, nullptr, nullptr, nullptr, nullptr,
        XH16, nullptr);
    if (i < NLAYER-1) {
      ln_k<4><<<M/4, 256, 0, stream>>>(T2, d_ln3w + i*CDIM, d_ln3b + i*CDIM, nullptr, XH16, nullptr);
    } else {
      ln_k<2><<<M/4, 256, 0, stream>>>(T2, d_ln3w + i*CDIM, d_ln3b + i*CDIM, Xb, XH16, nullptr);
    }
  }
  tpose_k<<<tgrid, tblk, 0, stream>>>(Xb, o_quant);
}